// Round 2
// baseline (35764.948 us; speedup 1.0000x reference)
//
#include <hip/hip_runtime.h>
#include <hip/hip_bf16.h>

#define BB 8
#define TT 2048
#define DD 512
#define NBLK 256   // 32 blocks per batch, 16 rows each
#define RPB 16

typedef unsigned short u16;
typedef unsigned int u32;

__device__ __forceinline__ float bf2f(u32 h) { return __uint_as_float(h << 16); }
__device__ __forceinline__ u16 f2bf(float f) {
    u32 u = __float_as_uint(f);
    u += 0x7fffu + ((u >> 16) & 1u);
    return (u16)(u >> 16);
}
__device__ __forceinline__ float wred64(float v) {
    #pragma unroll
    for (int off = 32; off; off >>= 1) v += __shfl_xor(v, off);
    return v;
}
__device__ __forceinline__ float half_red32(float v) {
    #pragma unroll
    for (int off = 16; off; off >>= 1) v += __shfl_xor(v, off);
    return v;   // sums within each 32-lane half
}
__device__ __forceinline__ void unpack8(uint4 r, float* f) {
    f[0] = bf2f(r.x & 0xffff); f[1] = bf2f(r.x >> 16);
    f[2] = bf2f(r.y & 0xffff); f[3] = bf2f(r.y >> 16);
    f[4] = bf2f(r.z & 0xffff); f[5] = bf2f(r.z >> 16);
    f[6] = bf2f(r.w & 0xffff); f[7] = bf2f(r.w >> 16);
}

// ---------------- projection GEMM (unchanged from round 1) ----------------
template<int IN_BF, int OUT_BF>
__global__ __launch_bounds__(256)
void gemm_xwT(const void* __restrict__ Xin, const float* __restrict__ W,
              const float* __restrict__ bias, void* __restrict__ Cout,
              const int K, const float outscale)
{
    __shared__ float Xs[32][68];
    __shared__ float Ws[32][68];
    const int m0 = blockIdx.x * 64, n0 = blockIdx.y * 64;
    const int tid = threadIdx.x;
    const int tx = tid & 15, ty = tid >> 4;
    float acc[4][4] = {};
    for (int k0 = 0; k0 < K; k0 += 32) {
        #pragma unroll
        for (int h = 0; h < 2; ++h) {
            const int f4 = tid + h * 256;
            const int r = f4 >> 3, c4 = f4 & 7;
            float v0, v1, v2, v3;
            if (IN_BF) {
                const u16* p = (const u16*)Xin + (size_t)(m0 + r) * K + k0 + c4 * 4;
                const uint2 raw = *(const uint2*)p;
                v0 = bf2f(raw.x & 0xffff); v1 = bf2f(raw.x >> 16);
                v2 = bf2f(raw.y & 0xffff); v3 = bf2f(raw.y >> 16);
            } else {
                const float4 raw = *(const float4*)((const float*)Xin + (size_t)(m0 + r) * K + k0 + c4 * 4);
                v0 = raw.x; v1 = raw.y; v2 = raw.z; v3 = raw.w;
            }
            Xs[c4 * 4 + 0][r] = v0; Xs[c4 * 4 + 1][r] = v1;
            Xs[c4 * 4 + 2][r] = v2; Xs[c4 * 4 + 3][r] = v3;
            const float4 wr = *(const float4*)(W + (size_t)(n0 + r) * K + k0 + c4 * 4);
            Ws[c4 * 4 + 0][r] = wr.x; Ws[c4 * 4 + 1][r] = wr.y;
            Ws[c4 * 4 + 2][r] = wr.z; Ws[c4 * 4 + 3][r] = wr.w;
        }
        __syncthreads();
        #pragma unroll
        for (int kk = 0; kk < 32; ++kk) {
            const float4 xa = *(const float4*)&Xs[kk][ty * 4];
            const float4 wb = *(const float4*)&Ws[kk][tx * 4];
            const float xv[4] = {xa.x, xa.y, xa.z, xa.w};
            const float wv[4] = {wb.x, wb.y, wb.z, wb.w};
            #pragma unroll
            for (int i = 0; i < 4; ++i)
                #pragma unroll
                for (int j = 0; j < 4; ++j)
                    acc[i][j] = fmaf(xv[i], wv[j], acc[i][j]);
        }
        __syncthreads();
    }
    #pragma unroll
    for (int i = 0; i < 4; ++i) {
        const int m = m0 + ty * 4 + i;
        #pragma unroll
        for (int j = 0; j < 4; ++j) {
            const int n = n0 + tx * 4 + j;
            const float val = (acc[i][j] + bias[n]) * outscale;
            if (OUT_BF) ((u16*)Cout)[(size_t)m * DD + n] = f2bf(val);
            else        ((float*)Cout)[(size_t)m * DD + n] = val;
        }
    }
}

// s_seq = sqrt(512) * sum(Q*U) ; Vn = V/(||V||+1e-6) in place (one wave per row)
__global__ __launch_bounds__(256)
void prep_kernel(const u16* __restrict__ Qb, const u16* __restrict__ Ub,
                 u16* __restrict__ Vb, float* __restrict__ sseq)
{
    const int lane = threadIdx.x & 63, wid = threadIdx.x >> 6;
    const int row = blockIdx.x * 4 + wid;
    const size_t base = (size_t)row * DD;
    const uint4 qr = *(const uint4*)(Qb + base + lane * 8);
    const uint4 ur = *(const uint4*)(Ub + base + lane * 8);
    const uint4 vr = *(const uint4*)(Vb + base + lane * 8);
    float q[8], u[8], v[8];
    unpack8(qr, q); unpack8(ur, u); unpack8(vr, v);
    float sd = 0.f, nv = 0.f;
    #pragma unroll
    for (int e = 0; e < 8; ++e) { sd = fmaf(q[e], u[e], sd); nv = fmaf(v[e], v[e], nv); }
    #pragma unroll
    for (int off = 32; off; off >>= 1) { sd += __shfl_xor(sd, off); nv += __shfl_xor(nv, off); }
    if (lane == 0) sseq[row] = sd * 22.627416997969522f;
    const float inv = 1.f / (sqrtf(nv) + 1e-6f);
    uint4 o;
    o.x = (u32)f2bf(v[0] * inv) | ((u32)f2bf(v[1] * inv) << 16);
    o.y = (u32)f2bf(v[2] * inv) | ((u32)f2bf(v[3] * inv) << 16);
    o.z = (u32)f2bf(v[4] * inv) | ((u32)f2bf(v[5] * inv) << 16);
    o.w = (u32)f2bf(v[6] * inv) | ((u32)f2bf(v[7] * inv) << 16);
    *(uint4*)(Vb + base + lane * 8) = o;
}

// ---------------- persistent scan kernel ----------------
// 256 blocks (1/CU). Block = (batch b, slab g of 16 rows). A,S rows live in
// registers for the whole scan. Cross-block data (z vector, dot/uu/norm
// partials) goes through agent-scope atomics (MALL-coherent across XCDs),
// synchronized by a sense-reversing grid barrier once per step.
__device__ __forceinline__ void grid_barrier(u32* bar, u32 target) {
    __syncthreads();   // all block stores complete (incl. vmcnt drain) before arrival
    if (threadIdx.x == 0) {
        const u32 prev = __hip_atomic_fetch_add(&bar[0], 1u, __ATOMIC_ACQ_REL, __HIP_MEMORY_SCOPE_AGENT);
        if (prev == NBLK - 1u) {
            __hip_atomic_store(&bar[0], 0u, __ATOMIC_RELAXED, __HIP_MEMORY_SCOPE_AGENT);
            __hip_atomic_store(&bar[32], target, __ATOMIC_RELEASE, __HIP_MEMORY_SCOPE_AGENT);
        } else {
            while (__hip_atomic_load(&bar[32], __ATOMIC_ACQUIRE, __HIP_MEMORY_SCOPE_AGENT) < target) {
                __builtin_amdgcn_s_sleep(1);
            }
        }
    }
    __syncthreads();
}

__global__ __launch_bounds__(256)
void scan_kernel(const u16* __restrict__ Qb, const u16* __restrict__ Ub,
                 const u16* __restrict__ Vnb, const float* __restrict__ sseq,
                 float* __restrict__ zbuf,   // [2][BB][DD]
                 float* __restrict__ part,   // [2][BB][32][4] {dotn, uun, na, ns}
                 u32* __restrict__ bar,
                 u16* __restrict__ Ob)
{
    const int b = blockIdx.x >> 5, g = blockIdx.x & 31;
    const int tid = threadIdx.x, lane = tid & 63, wid = tid >> 6;
    const int row0 = g * RPB + wid * 4;

    __shared__ __align__(16) float zs[DD], us[DD], un[DD], qs[DD], al[DD];
    __shared__ float vsh[RPB];
    __shared__ float bc[8];
    __shared__ float redA[4], redS[4], redD[4], redU[4], redT[4];

    // register-resident state: A = I, S = 0
    float4 Areg[4][2], Sreg[4][2];
    #pragma unroll
    for (int r = 0; r < 4; ++r) {
        const int grow = row0 + r;
        #pragma unroll
        for (int c = 0; c < 2; ++c) {
            const int jb = (c * 64 + lane) * 4;
            float4 a;
            a.x = (jb + 0 == grow) ? 1.f : 0.f;
            a.y = (jb + 1 == grow) ? 1.f : 0.f;
            a.z = (jb + 2 == grow) ? 1.f : 0.f;
            a.w = (jb + 3 == grow) ? 1.f : 0.f;
            Areg[r][c] = a;
            Sreg[r][c] = make_float4(0.f, 0.f, 0.f, 0.f);
        }
    }

    const float4* zs4 = (const float4*)zs;
    const float4* un4 = (const float4*)un;
    const float4* al4 = (const float4*)al;
    const float4* qs4 = (const float4*)qs;

    for (int t = 0; t < TT; ++t) {
        const int cur = t & 1, nxt = cur ^ 1;
        const size_t rowbase = ((size_t)b * TT + t) * DD;
        const int tn = (t + 1 < TT) ? (t + 1) : t;
        const size_t rowbaseN = ((size_t)b * TT + tn) * DD;

        // ---- phase 1: stage shared vectors + cross-block partials ----
        {
            const u32 uraw = *(const u32*)(Ub + rowbase + tid * 2);
            us[tid * 2]     = bf2f(uraw & 0xffff);
            us[tid * 2 + 1] = bf2f(uraw >> 16);
            const u32 qraw = *(const u32*)(Qb + rowbase + tid * 2);
            qs[tid * 2]     = bf2f(qraw & 0xffff);
            qs[tid * 2 + 1] = bf2f(qraw >> 16);
            const u32 nraw = *(const u32*)(Ub + rowbaseN + tid * 2);
            un[tid * 2]     = bf2f(nraw & 0xffff);
            un[tid * 2 + 1] = bf2f(nraw >> 16);
            if (tid < RPB) vsh[tid] = bf2f(Vnb[rowbase + g * RPB + tid]);
            if (t > 0) {
                const size_t zb = (size_t)cur * (BB * DD) + b * DD;
                zs[tid]       = __hip_atomic_load(&zbuf[zb + tid],       __ATOMIC_RELAXED, __HIP_MEMORY_SCOPE_AGENT);
                zs[tid + 256] = __hip_atomic_load(&zbuf[zb + tid + 256], __ATOMIC_RELAXED, __HIP_MEMORY_SCOPE_AGENT);
                if (wid < 2) {
                    const int blk = lane & 31, which = lane >> 5;
                    const float* pp = part + (((size_t)nxt * BB + b) * 32 + blk) * 4 + wid * 2 + which;
                    float pv = __hip_atomic_load(pp, __ATOMIC_RELAXED, __HIP_MEMORY_SCOPE_AGENT);
                    pv = half_red32(pv);
                    if (wid == 0 && lane == 0)  bc[0] = pv;  // sum dotn
                    if (wid == 0 && lane == 32) bc[1] = pv;  // sum uun
                    if (wid == 1 && lane == 0)  bc[2] = pv;  // sum ||A||^2
                    if (wid == 1 && lane == 32) bc[3] = pv;  // sum ||S||^2
                }
            }
        }
        __syncthreads();

        if (t == 0) {
            // z_0 = u_0 ; dot = u.u (computed locally by every block)
            zs[tid] = us[tid]; zs[tid + 256] = us[tid + 256];
            float dp = us[tid] * us[tid] + us[tid + 256] * us[tid + 256];
            dp = wred64(dp);
            if (lane == 0) redT[wid] = dp;
            __syncthreads();
            if (tid == 0) { bc[0] = redT[0] + redT[1] + redT[2] + redT[3]; bc[1] = 0.f; bc[2] = 0.f; bc[3] = 0.f; }
            __syncthreads();
        }

        // ---- uniform per-step scalars ----
        const float pend = (t > 0 && (bc[2] > 1e6f || bc[3] > 1e6f)) ? 1e-5f : 0.f;
        const float dot = bc[0] + pend * bc[1];
        const float dpl = 1.f + dot;
        const bool nn = __builtin_isnan(dpl);
        const float delta = nn ? dpl : fmaxf(dpl, 1e-6f);
        const bool unst = nn || __builtin_isinf(delta) || (fabsf(delta) < 1e-6f);
        const float subc = unst ? 0.f : (1.f / delta);
        const float d12 = (unst ? 1e-6f : 0.f) + ((((t + 1) & 127) == 0) ? 1e-6f : 0.f);
        const float coef = 1.f - subc * dot;   // A_new u = coef*z + d12*u
        const float sv = sseq[(size_t)b * TT + t];
        const float dadd = pend + d12;

        // ---- phase 2: correct z with pending guard, build alpha ----
        #pragma unroll
        for (int h = 0; h < 2; ++h) {
            const int i = tid + h * 256;
            const float z = fmaf(pend, us[i], zs[i]);
            zs[i] = z;
            al[i] = sv * fmaf(coef, z, d12 * us[i]);
        }
        __syncthreads();

        // ---- phase 3a: A update in registers; fuse ||A||^2 and z_next = A u_next ----
        float na = 0.f, ns = 0.f, dotn = 0.f, uun = 0.f;
        #pragma unroll
        for (int r = 0; r < 4; ++r) {
            const int grow = row0 + r;
            const float Cz = subc * zs[grow];
            float znp = 0.f;
            #pragma unroll
            for (int c = 0; c < 2; ++c) {
                const int idx = c * 64 + lane;
                const int jb = idx * 4;
                float4 a = Areg[r][c];
                const float4 zv = zs4[idx];
                const float4 uv = un4[idx];
                a.x = fmaf(-Cz, zv.x, a.x) + ((jb + 0 == grow) ? dadd : 0.f);
                a.y = fmaf(-Cz, zv.y, a.y) + ((jb + 1 == grow) ? dadd : 0.f);
                a.z = fmaf(-Cz, zv.z, a.z) + ((jb + 2 == grow) ? dadd : 0.f);
                a.w = fmaf(-Cz, zv.w, a.w) + ((jb + 3 == grow) ? dadd : 0.f);
                na += a.x * a.x + a.y * a.y + a.z * a.z + a.w * a.w;
                znp += a.x * uv.x + a.y * uv.y + a.z * uv.z + a.w * uv.w;
                Areg[r][c] = a;
            }
            znp = wred64(znp);
            if (lane == 0) {
                __hip_atomic_store(&zbuf[(size_t)nxt * (BB * DD) + b * DD + grow], znp,
                                   __ATOMIC_RELAXED, __HIP_MEMORY_SCOPE_AGENT);
                const float unv = un[grow];
                dotn = fmaf(unv, znp, dotn);
                uun  = fmaf(unv, unv, uun);
            }
        }
        // ---- phase 3b: S update; fuse ||S||^2 and o = S_new q ----
        #pragma unroll
        for (int r = 0; r < 4; ++r) {
            const int grow = row0 + r;
            const float vr = vsh[wid * 4 + r];
            float op = 0.f;
            #pragma unroll
            for (int c = 0; c < 2; ++c) {
                const int idx = c * 64 + lane;
                float4 s = Sreg[r][c];
                const float4 av = al4[idx];
                const float4 qv = qs4[idx];
                s.x = fmaf(vr, av.x, s.x);
                s.y = fmaf(vr, av.y, s.y);
                s.z = fmaf(vr, av.z, s.z);
                s.w = fmaf(vr, av.w, s.w);
                ns += s.x * s.x + s.y * s.y + s.z * s.z + s.w * s.w;
                op += s.x * qv.x + s.y * qv.y + s.z * qv.z + s.w * qv.w;
                Sreg[r][c] = s;
            }
            op = wred64(op);
            if (lane == 0) Ob[rowbase + grow] = f2bf(op);
        }
        // ---- phase 4: block-level reduces + publish partials ----
        na = wred64(na); ns = wred64(ns);
        if (lane == 0) { redA[wid] = na; redS[wid] = ns; redD[wid] = dotn; redU[wid] = uun; }
        __syncthreads();
        if (tid == 0) {
            float* pp = part + (((size_t)cur * BB + b) * 32 + g) * 4;
            __hip_atomic_store(&pp[0], redD[0] + redD[1] + redD[2] + redD[3], __ATOMIC_RELAXED, __HIP_MEMORY_SCOPE_AGENT);
            __hip_atomic_store(&pp[1], redU[0] + redU[1] + redU[2] + redU[3], __ATOMIC_RELAXED, __HIP_MEMORY_SCOPE_AGENT);
            __hip_atomic_store(&pp[2], redA[0] + redA[1] + redA[2] + redA[3], __ATOMIC_RELAXED, __HIP_MEMORY_SCOPE_AGENT);
            __hip_atomic_store(&pp[3], redS[0] + redS[1] + redS[2] + redS[3], __ATOMIC_RELAXED, __HIP_MEMORY_SCOPE_AGENT);
        }
        if (t + 1 < TT) grid_barrier(bar, (u32)(t + 1));
    }
}

extern "C" void kernel_launch(void* const* d_in, const int* in_sizes, int n_in,
                              void* d_out, int out_size, void* d_ws, size_t ws_size,
                              hipStream_t stream)
{
    const float* x  = (const float*)d_in[0];
    const float* Wq = (const float*)d_in[1];
    const float* bq = (const float*)d_in[2];
    const float* Wk = (const float*)d_in[3];
    const float* bk = (const float*)d_in[4];
    const float* Wv = (const float*)d_in[5];
    const float* bv = (const float*)d_in[6];
    const float* Wo = (const float*)d_in[7];
    const float* bo = (const float*)d_in[8];

    char* ws = (char*)d_ws;
    u16* Qb   = (u16*)(ws);                        // 16 MiB
    u16* Ub   = (u16*)(ws + (16u << 20));          // 16 MiB
    u16* Vnb  = (u16*)(ws + (32u << 20));          // 16 MiB
    u16* Ob   = (u16*)(ws + (48u << 20));          // 16 MiB
    float* zbuf = (float*)(ws + (64u << 20));                  // 32 KiB
    float* part = (float*)(ws + (64u << 20) + (64u << 10));    // 8 KiB
    float* sseq = (float*)(ws + (64u << 20) + (128u << 10));   // 64 KiB
    u32*   bar  = (u32*)  (ws + (64u << 20) + (256u << 10));   // 256 B

    hipMemsetAsync(bar, 0, 256, stream);

    dim3 gg(16384 / 64, 512 / 64);
    gemm_xwT<0, 1><<<gg, 256, 0, stream>>>(x, Wq, bq, Qb, 512, 1.f);
    gemm_xwT<0, 1><<<gg, 256, 0, stream>>>(x, Wk, bk, Ub, 512, 0.04419417382415922f);
    gemm_xwT<0, 1><<<gg, 256, 0, stream>>>(x, Wv, bv, Vnb, 512, 1.f);
    prep_kernel<<<4096, 256, 0, stream>>>(Qb, Ub, Vnb, sseq);
    scan_kernel<<<NBLK, 256, 0, stream>>>(Qb, Ub, Vnb, sseq, zbuf, part, bar, Ob);
    gemm_xwT<1, 0><<<gg, 256, 0, stream>>>(Ob, Wo, bo, d_out, 512, 1.f);
}

// Round 3
// 7614.961 us; speedup vs baseline: 4.6967x; 4.6967x over previous
//
#include <hip/hip_runtime.h>
#include <hip/hip_bf16.h>

#define BB 8
#define TT 2048
#define DD 512
#define LL 128
#define NC 16

typedef unsigned short u16;
typedef unsigned int u32;

__device__ __forceinline__ float bf2f(u32 h) { return __uint_as_float(h << 16); }
__device__ __forceinline__ u16 f2bf(float f) {
    u32 u = __float_as_uint(f);
    u += 0x7fffu + ((u >> 16) & 1u);
    return (u16)(u >> 16);
}
__device__ __forceinline__ float wred64(float v) {
    #pragma unroll
    for (int off = 32; off; off >>= 1) v += __shfl_xor(v, off);
    return v;
}
__device__ __forceinline__ void unpack8(uint4 r, float* f) {
    f[0] = bf2f(r.x & 0xffff); f[1] = bf2f(r.x >> 16);
    f[2] = bf2f(r.y & 0xffff); f[3] = bf2f(r.y >> 16);
    f[4] = bf2f(r.z & 0xffff); f[5] = bf2f(r.z >> 16);
    f[6] = bf2f(r.w & 0xffff); f[7] = bf2f(r.w >> 16);
}

// ---------------- projection GEMM (round-1, proven) ----------------
template<int IN_BF, int OUT_BF>
__global__ __launch_bounds__(256)
void gemm_xwT(const void* __restrict__ Xin, const float* __restrict__ W,
              const float* __restrict__ bias, void* __restrict__ Cout,
              const int K, const float outscale)
{
    __shared__ float Xs[32][68];
    __shared__ float Ws[32][68];
    const int m0 = blockIdx.x * 64, n0 = blockIdx.y * 64;
    const int tid = threadIdx.x;
    const int tx = tid & 15, ty = tid >> 4;
    float acc[4][4] = {};
    for (int k0 = 0; k0 < K; k0 += 32) {
        #pragma unroll
        for (int h = 0; h < 2; ++h) {
            const int f4 = tid + h * 256;
            const int r = f4 >> 3, c4 = f4 & 7;
            float v0, v1, v2, v3;
            if (IN_BF) {
                const u16* p = (const u16*)Xin + (size_t)(m0 + r) * K + k0 + c4 * 4;
                const uint2 raw = *(const uint2*)p;
                v0 = bf2f(raw.x & 0xffff); v1 = bf2f(raw.x >> 16);
                v2 = bf2f(raw.y & 0xffff); v3 = bf2f(raw.y >> 16);
            } else {
                const float4 raw = *(const float4*)((const float*)Xin + (size_t)(m0 + r) * K + k0 + c4 * 4);
                v0 = raw.x; v1 = raw.y; v2 = raw.z; v3 = raw.w;
            }
            Xs[c4 * 4 + 0][r] = v0; Xs[c4 * 4 + 1][r] = v1;
            Xs[c4 * 4 + 2][r] = v2; Xs[c4 * 4 + 3][r] = v3;
            const float4 wr = *(const float4*)(W + (size_t)(n0 + r) * K + k0 + c4 * 4);
            Ws[c4 * 4 + 0][r] = wr.x; Ws[c4 * 4 + 1][r] = wr.y;
            Ws[c4 * 4 + 2][r] = wr.z; Ws[c4 * 4 + 3][r] = wr.w;
        }
        __syncthreads();
        #pragma unroll
        for (int kk = 0; kk < 32; ++kk) {
            const float4 xa = *(const float4*)&Xs[kk][ty * 4];
            const float4 wb = *(const float4*)&Ws[kk][tx * 4];
            const float xv[4] = {xa.x, xa.y, xa.z, xa.w};
            const float wv[4] = {wb.x, wb.y, wb.z, wb.w};
            #pragma unroll
            for (int i = 0; i < 4; ++i)
                #pragma unroll
                for (int j = 0; j < 4; ++j)
                    acc[i][j] = fmaf(xv[i], wv[j], acc[i][j]);
        }
        __syncthreads();
    }
    #pragma unroll
    for (int i = 0; i < 4; ++i) {
        const int m = m0 + ty * 4 + i;
        #pragma unroll
        for (int j = 0; j < 4; ++j) {
            const int n = n0 + tx * 4 + j;
            const float val = (acc[i][j] + bias[n]) * outscale;
            if (OUT_BF) ((u16*)Cout)[(size_t)m * DD + n] = f2bf(val);
            else        ((float*)Cout)[(size_t)m * DD + n] = val;
        }
    }
}

__global__ __launch_bounds__(256)
void prep_kernel(const u16* __restrict__ Qb, const u16* __restrict__ Ub,
                 u16* __restrict__ Vb, float* __restrict__ sseq)
{
    const int lane = threadIdx.x & 63, wid = threadIdx.x >> 6;
    const int row = blockIdx.x * 4 + wid;
    const size_t base = (size_t)row * DD;
    const uint4 qr = *(const uint4*)(Qb + base + lane * 8);
    const uint4 ur = *(const uint4*)(Ub + base + lane * 8);
    const uint4 vr = *(const uint4*)(Vb + base + lane * 8);
    float q[8], u[8], v[8];
    unpack8(qr, q); unpack8(ur, u); unpack8(vr, v);
    float sd = 0.f, nv = 0.f;
    #pragma unroll
    for (int e = 0; e < 8; ++e) { sd = fmaf(q[e], u[e], sd); nv = fmaf(v[e], v[e], nv); }
    #pragma unroll
    for (int off = 32; off; off >>= 1) { sd += __shfl_xor(sd, off); nv += __shfl_xor(nv, off); }
    if (lane == 0) sseq[row] = sd * 22.627416997969522f;
    const float inv = 1.f / (sqrtf(nv) + 1e-6f);
    uint4 o;
    o.x = (u32)f2bf(v[0] * inv) | ((u32)f2bf(v[1] * inv) << 16);
    o.y = (u32)f2bf(v[2] * inv) | ((u32)f2bf(v[3] * inv) << 16);
    o.z = (u32)f2bf(v[4] * inv) | ((u32)f2bf(v[5] * inv) << 16);
    o.w = (u32)f2bf(v[6] * inv) | ((u32)f2bf(v[7] * inv) << 16);
    *(uint4*)(Vb + base + lane * 8) = o;
}

__global__ __launch_bounds__(256)
void init_kernel(float4* __restrict__ A4, float4* __restrict__ S4,
                 float* __restrict__ SnSq, float* __restrict__ AnAcc)
{
    const int gtid = blockIdx.x * 256 + threadIdx.x;
    const int N4 = BB * DD * DD / 4;
    for (int idx = gtid; idx < N4; idx += gridDim.x * 256) {
        const int e0 = idx << 2;
        const int r = (e0 >> 9) & 511;
        const int c = e0 & 511;
        float4 v;
        v.x = (c + 0 == r) ? 1.f : 0.f;
        v.y = (c + 1 == r) ? 1.f : 0.f;
        v.z = (c + 2 == r) ? 1.f : 0.f;
        v.w = (c + 3 == r) ? 1.f : 0.f;
        A4[idx] = v;
        S4[idx] = make_float4(0.f, 0.f, 0.f, 0.f);
    }
    if (gtid < BB) { SnSq[gtid] = 0.f; AnAcc[gtid] = 512.f; }
}

// ---------------- generic chunk GEMM ----------------
// A layouts: 0 f32 el(m,k)=p[m*lda+k]; 1 f32T el=p[k*lda+m]; 2 bf16 normal;
//            3 bf16T; 4 f32T causal-masked (el=0 if k>m)
// B layouts: 0 f32 el(k,n)=p[k*ldb+n]; 1 f32T el=p[n*ldb+k]; 2 bf16 normal;
//            3 bf16T; 5 mixed (n<128: bf16T from Bp; n>=128: f32 normal from Baux ld=128)
// epi: 0 C=acc (f32); 1 Cio=Cio-acc+diag(gdiag), accumulate ||.||^2 -> anacc;
//      2 Cio+=acc; 3 bf16 out = acc + OBSA[n*256+m]
struct GP {
    int alay, blay, epi;
    const void* Ap; const void* Bp; const void* Baux;
    void* Cp; float* Cio;
    const float* gdiag; float* anacc;
    int lda, ldb, ldc, K;
    long sA, sB, sBaux, sC, sCio;
};

__device__ __forceinline__ void gemm_body(const GP& p, const int bz) {
    __shared__ __align__(16) float As[32][68];
    __shared__ __align__(16) float Bs[32][68];
    const int m0 = blockIdx.x * 64, n0 = blockIdx.y * 64;
    const int tid = threadIdx.x, tx = tid & 15, ty = tid >> 4;
    float acc[4][4] = {};
    for (int k0 = 0; k0 < p.K; k0 += 32) {
        // ---- A tile ----
        if (p.alay == 0) {
            const float* A = (const float*)p.Ap + (size_t)bz * p.sA;
            #pragma unroll
            for (int h = 0; h < 2; ++h) {
                const int g = tid + h * 256, m = g >> 3, k4 = (g & 7) * 4;
                const float4 r = *(const float4*)(A + (size_t)(m0 + m) * p.lda + k0 + k4);
                As[k4][m] = r.x; As[k4+1][m] = r.y; As[k4+2][m] = r.z; As[k4+3][m] = r.w;
            }
        } else if (p.alay == 2) {
            const u16* A = (const u16*)p.Ap + (size_t)bz * p.sA;
            #pragma unroll
            for (int h = 0; h < 2; ++h) {
                const int g = tid + h * 256, m = g >> 3, k4 = (g & 7) * 4;
                const ushort4 r = *(const ushort4*)(A + (size_t)(m0 + m) * p.lda + k0 + k4);
                As[k4][m]=bf2f(r.x); As[k4+1][m]=bf2f(r.y); As[k4+2][m]=bf2f(r.z); As[k4+3][m]=bf2f(r.w);
            }
        } else if (p.alay == 1 || p.alay == 4) {
            const float* A = (const float*)p.Ap + (size_t)bz * p.sA;
            #pragma unroll
            for (int h = 0; h < 2; ++h) {
                const int g = tid + h * 256, k = g >> 4, m4 = (g & 15) * 4;
                float4 r = *(const float4*)(A + (size_t)(k0 + k) * p.lda + m0 + m4);
                if (p.alay == 4) {
                    const int kg = k0 + k, mg = m0 + m4;
                    if (kg > mg + 0) r.x = 0.f;
                    if (kg > mg + 1) r.y = 0.f;
                    if (kg > mg + 2) r.z = 0.f;
                    if (kg > mg + 3) r.w = 0.f;
                }
                As[k][m4] = r.x; As[k][m4+1] = r.y; As[k][m4+2] = r.z; As[k][m4+3] = r.w;
            }
        } else { // 3
            const u16* A = (const u16*)p.Ap + (size_t)bz * p.sA;
            #pragma unroll
            for (int h = 0; h < 2; ++h) {
                const int g = tid + h * 256, k = g >> 4, m4 = (g & 15) * 4;
                const ushort4 r = *(const ushort4*)(A + (size_t)(k0 + k) * p.lda + m0 + m4);
                As[k][m4]=bf2f(r.x); As[k][m4+1]=bf2f(r.y); As[k][m4+2]=bf2f(r.z); As[k][m4+3]=bf2f(r.w);
            }
        }
        // ---- B tile ----
        if (p.blay == 0) {
            const float* B = (const float*)p.Bp + (size_t)bz * p.sB;
            #pragma unroll
            for (int h = 0; h < 2; ++h) {
                const int g = tid + h * 256, k = g >> 4, n4 = (g & 15) * 4;
                const float4 r = *(const float4*)(B + (size_t)(k0 + k) * p.ldb + n0 + n4);
                Bs[k][n4] = r.x; Bs[k][n4+1] = r.y; Bs[k][n4+2] = r.z; Bs[k][n4+3] = r.w;
            }
        } else if (p.blay == 2) {
            const u16* B = (const u16*)p.Bp + (size_t)bz * p.sB;
            #pragma unroll
            for (int h = 0; h < 2; ++h) {
                const int g = tid + h * 256, k = g >> 4, n4 = (g & 15) * 4;
                const ushort4 r = *(const ushort4*)(B + (size_t)(k0 + k) * p.ldb + n0 + n4);
                Bs[k][n4]=bf2f(r.x); Bs[k][n4+1]=bf2f(r.y); Bs[k][n4+2]=bf2f(r.z); Bs[k][n4+3]=bf2f(r.w);
            }
        } else if (p.blay == 1) {
            const float* B = (const float*)p.Bp + (size_t)bz * p.sB;
            #pragma unroll
            for (int h = 0; h < 2; ++h) {
                const int g = tid + h * 256, n = g >> 3, k4 = (g & 7) * 4;
                const float4 r = *(const float4*)(B + (size_t)(n0 + n) * p.ldb + k0 + k4);
                Bs[k4][n] = r.x; Bs[k4+1][n] = r.y; Bs[k4+2][n] = r.z; Bs[k4+3][n] = r.w;
            }
        } else if (p.blay == 3) {
            const u16* B = (const u16*)p.Bp + (size_t)bz * p.sB;
            #pragma unroll
            for (int h = 0; h < 2; ++h) {
                const int g = tid + h * 256, n = g >> 3, k4 = (g & 7) * 4;
                const ushort4 r = *(const ushort4*)(B + (size_t)(n0 + n) * p.ldb + k0 + k4);
                Bs[k4][n]=bf2f(r.x); Bs[k4+1][n]=bf2f(r.y); Bs[k4+2][n]=bf2f(r.z); Bs[k4+3][n]=bf2f(r.w);
            }
        } else { // 5: mixed [Q | Alpha]
            if (n0 < 128) {
                const u16* B = (const u16*)p.Bp + (size_t)bz * p.sB;
                #pragma unroll
                for (int h = 0; h < 2; ++h) {
                    const int g = tid + h * 256, n = g >> 3, k4 = (g & 7) * 4;
                    const ushort4 r = *(const ushort4*)(B + (size_t)(n0 + n) * p.ldb + k0 + k4);
                    Bs[k4][n]=bf2f(r.x); Bs[k4+1][n]=bf2f(r.y); Bs[k4+2][n]=bf2f(r.z); Bs[k4+3][n]=bf2f(r.w);
                }
            } else {
                const float* B = (const float*)p.Baux + (size_t)bz * p.sBaux;
                #pragma unroll
                for (int h = 0; h < 2; ++h) {
                    const int g = tid + h * 256, k = g >> 4, n4 = (g & 15) * 4;
                    const float4 r = *(const float4*)(B + (size_t)(k0 + k) * 128 + (n0 - 128) + n4);
                    Bs[k][n4] = r.x; Bs[k][n4+1] = r.y; Bs[k][n4+2] = r.z; Bs[k][n4+3] = r.w;
                }
            }
        }
        __syncthreads();
        #pragma unroll
        for (int kk = 0; kk < 32; ++kk) {
            const float4 xa = *(const float4*)&As[kk][ty * 4];
            const float4 wb = *(const float4*)&Bs[kk][tx * 4];
            const float xv[4] = {xa.x, xa.y, xa.z, xa.w};
            const float wv[4] = {wb.x, wb.y, wb.z, wb.w};
            #pragma unroll
            for (int i = 0; i < 4; ++i)
                #pragma unroll
                for (int j = 0; j < 4; ++j)
                    acc[i][j] = fmaf(xv[i], wv[j], acc[i][j]);
        }
        __syncthreads();
    }
    const int mb = m0 + ty * 4, nb = n0 + tx * 4;
    if (p.epi == 0) {
        float* C = (float*)p.Cp + (size_t)bz * p.sC;
        #pragma unroll
        for (int i = 0; i < 4; ++i)
            #pragma unroll
            for (int j = 0; j < 4; ++j)
                C[(size_t)(mb + i) * p.ldc + nb + j] = acc[i][j];
    } else if (p.epi == 1) {
        float* C = p.Cio + (size_t)bz * p.sCio;
        const float gd = p.gdiag[bz];
        float v2 = 0.f;
        #pragma unroll
        for (int i = 0; i < 4; ++i)
            #pragma unroll
            for (int j = 0; j < 4; ++j) {
                const size_t idx = (size_t)(mb + i) * p.ldc + nb + j;
                float v = C[idx] - acc[i][j] + ((mb + i) == (nb + j) ? gd : 0.f);
                C[idx] = v;
                v2 = fmaf(v, v, v2);
            }
        v2 = wred64(v2);
        if ((tid & 63) == 0) atomicAdd(p.anacc + bz, v2);
    } else if (p.epi == 2) {
        float* C = p.Cio + (size_t)bz * p.sCio;
        #pragma unroll
        for (int i = 0; i < 4; ++i)
            #pragma unroll
            for (int j = 0; j < 4; ++j)
                C[(size_t)(mb + i) * p.ldc + nb + j] += acc[i][j];
    } else { // 3
        u16* O = (u16*)p.Cp + (size_t)bz * p.sC;
        const float* OB = p.Cio + (size_t)bz * p.sCio;
        #pragma unroll
        for (int i = 0; i < 4; ++i)
            #pragma unroll
            for (int j = 0; j < 4; ++j)
                O[(size_t)(mb + i) * p.ldc + nb + j] =
                    f2bf(acc[i][j] + OB[(size_t)(nb + j) * 256 + mb + i]);
    }
}

__global__ __launch_bounds__(256) void gemmx(GP p) { gemm_body(p, blockIdx.z); }

__global__ __launch_bounds__(256)
void gram3_kernel(const float* Alpha, const u16* Qt, const u16* Vnt,
                  float* P, float* Ga, float* Gv)
{
    const int z = blockIdx.z, b = z / 3, j = z - b * 3;
    GP p{};
    p.K = 512; p.epi = 0; p.ldc = 128; p.sC = 16384;
    if (j == 0) {
        p.alay = 1; p.Ap = Alpha; p.lda = 128; p.sA = 65536;
        p.blay = 3; p.Bp = Qt; p.ldb = 512; p.sB = 1048576;
        p.Cp = P;
    } else if (j == 1) {
        p.alay = 1; p.Ap = Alpha; p.lda = 128; p.sA = 65536;
        p.blay = 0; p.Bp = Alpha; p.ldb = 128; p.sB = 65536;
        p.Cp = Ga;
    } else {
        p.alay = 2; p.Ap = Vnt; p.lda = 512; p.sA = 1048576;
        p.blay = 3; p.Bp = Vnt; p.ldb = 512; p.sB = 1048576;
        p.Cp = Gv;
    }
    gemm_body(p, b);
}

// ---------------- small sequential kernels ----------------
// Y-elimination on G (LDS), produces Cm (strictly upper, rows scaled 1/delta),
// invd, ca = s/delta, cb (periodic term, last column only)
__global__ __launch_bounds__(256)
void elim_kernel(const float* __restrict__ G, float* __restrict__ Cm,
                 const float* __restrict__ sseq, float* __restrict__ invd,
                 float* __restrict__ ca, float* __restrict__ cb, const int t0)
{
    const int b = blockIdx.x, tid = threadIdx.x;
    __shared__ __align__(16) float E[128][128];
    __shared__ float del[128];
    __shared__ float dsh;
    const float4* Gb = (const float4*)(G + (size_t)b * 16384);
    float4* E4 = (float4*)E;
    for (int i = tid; i < 4096; i += 256) E4[i] = Gb[i];
    const int rg = tid >> 5, ln = tid & 31;
    for (int t = 0; t < 128; ++t) {
        __syncthreads();
        if (tid == 0) {
            const float d = fmaxf(1.f + E[t][t], 1e-6f);
            del[t] = d; dsh = d;
        }
        __syncthreads();
        const float inv = 1.f / dsh;
        const float4 y = ((const float4*)&E[t][0])[ln];
        for (int r = t + 1 + rg; r < 128; r += 8) {
            const float cc = E[t][r] * inv;
            float4* Er = (float4*)&E[r][0];
            float4 e = Er[ln];
            e.x = fmaf(-cc, y.x, e.x);
            e.y = fmaf(-cc, y.y, e.y);
            e.z = fmaf(-cc, y.z, e.z);
            e.w = fmaf(-cc, y.w, e.w);
            Er[ln] = e;
        }
    }
    __syncthreads();
    for (int idx = tid; idx < 16384; idx += 256) {
        const int r = idx >> 7, cc = idx & 127;
        Cm[(size_t)b * 16384 + idx] = (cc > r) ? E[r][cc] * (1.f / del[r]) : 0.f;
    }
    if (tid < 128) {
        const float d = del[tid];
        const float s = sseq[(size_t)b * TT + t0 + tid];
        invd[b * 128 + tid] = 1.f / d;
        ca[b * 128 + tid] = s / d;
        cb[b * 128 + tid] = (tid == 127) ? s * 1e-6f : 0.f;
    }
}

// forward substitution: Z = W (I+C)^-1 ; Zs = Z diag(1/delta) ; Alpha = Z diag(s/delta) (+periodic u term)
__global__ __launch_bounds__(128)
void fsub_kernel(const float* __restrict__ W, const float* __restrict__ Cm,
                 const float* __restrict__ invd, const float* __restrict__ ca,
                 const float* __restrict__ cb, const u16* __restrict__ Ulast,
                 float* __restrict__ Z, float* __restrict__ Zs, float* __restrict__ Alpha)
{
    const int b = blockIdx.z, slab = blockIdx.x, tid = threadIdx.x;
    __shared__ __align__(16) float zl[128][129];
    __shared__ float Cp[128][32];
    const float* Wb = W + (size_t)b * 65536 + (size_t)slab * 16384;
    const float* Cb = Cm + (size_t)b * 16384;
    for (int r = 0; r < 128; ++r) zl[r][tid] = Wb[(size_t)r * 128 + tid];
    __syncthreads();
    float zreg[32];
    for (int J = 0; J < 4; ++J) {
        const int nrows = (J + 1) * 32;
        for (int idx = tid; idx < nrows * 32; idx += 128) {
            const int i = idx >> 5, cc = idx & 31;
            Cp[i][cc] = Cb[i * 128 + J * 32 + cc];
        }
        __syncthreads();
        float tmp[32];
        #pragma unroll
        for (int cc = 0; cc < 32; ++cc) tmp[cc] = zl[tid][J * 32 + cc];
        for (int i = 0; i < J * 32; ++i) {
            const float zi = zl[tid][i];
            #pragma unroll
            for (int cc = 0; cc < 32; ++cc) tmp[cc] = fmaf(-zi, Cp[i][cc], tmp[cc]);
        }
        #pragma unroll
        for (int t = 0; t < 32; ++t) {
            float v = tmp[t];
            for (int i = 0; i < t; ++i) v = fmaf(-Cp[J * 32 + i][t], zreg[i], v);
            zreg[t] = v;
        }
        #pragma unroll
        for (int cc = 0; cc < 32; ++cc) zl[tid][J * 32 + cc] = zreg[cc];
        __syncthreads();
    }
    const float iv = invd[b * 128 + tid];
    const float cav = ca[b * 128 + tid];
    const float cbv = cb[b * 128 + tid];
    const u16* Ub_l = Ulast + (size_t)b * 1048576;
    for (int r = 0; r < 128; ++r) {
        const int grow = slab * 128 + r;
        const float v = zl[r][tid];
        const size_t o = (size_t)b * 65536 + (size_t)grow * 128 + tid;
        Z[o] = v;
        Zs[o] = v * iv;
        float a = v * cav;
        if (cbv != 0.f) a = fmaf(cbv, bf2f(Ub_l[grow]), a);
        Alpha[o] = a;
    }
}

// per-step Frobenius prefix + explosion-guard count -> gdiag; resets AnAcc
__global__ __launch_bounds__(256)
void guard_kernel(const float* __restrict__ OBSA, const u16* __restrict__ Vnt,
                  const float* __restrict__ Ga, const float* __restrict__ Gv,
                  float* __restrict__ SnSq, float* __restrict__ AnAcc,
                  float* __restrict__ gdiag)
{
    const int b = blockIdx.x, tid = threadIdx.x;
    __shared__ float dpart[256];
    __shared__ float dsum[128], rsum[128], mdia[128];
    const int i = tid & 127, half = tid >> 7;
    const float* SA = OBSA + (size_t)b * 131072;
    const u16* Vn = Vnt + (size_t)b * 1048576;
    float s = 0.f;
    for (int r = half * 256; r < half * 256 + 256; ++r)
        s = fmaf(bf2f(Vn[(size_t)i * 512 + r]), SA[(size_t)r * 256 + 128 + i], s);
    dpart[tid] = s;
    __syncthreads();
    if (tid < 128) {
        dsum[tid] = dpart[tid] + dpart[tid + 128];
        const float* gv = Gv + (size_t)b * 16384 + tid * 128;
        const float* ga = Ga + (size_t)b * 16384 + tid * 128;
        float rs = 0.f;
        for (int j = 0; j < tid; ++j) rs = fmaf(gv[j], ga[j], rs);
        rsum[tid] = rs;
        mdia[tid] = gv[tid] * ga[tid];
    }
    __syncthreads();
    if (tid == 0) {
        const float An2 = AnAcc[b];
        float Sn2 = SnSq[b], D = 0.f, T = 0.f;
        int ng = 0;
        for (int t = 0; t < 128; ++t) {
            D += dsum[t];
            T += mdia[t] + 2.f * rsum[t];
            const float sn2 = Sn2 + 2.f * D + T;
            if (sn2 > 1e6f || An2 > 1e6f) ++ng;
        }
        SnSq[b] = Sn2 + 2.f * D + T;
        gdiag[b] = 1e-6f + (float)ng * 1e-5f;
        AnAcc[b] = 0.f;
    }
}

extern "C" void kernel_launch(void* const* d_in, const int* in_sizes, int n_in,
                              void* d_out, int out_size, void* d_ws, size_t ws_size,
                              hipStream_t stream)
{
    const float* x  = (const float*)d_in[0];
    const float* Wq = (const float*)d_in[1];
    const float* bq = (const float*)d_in[2];
    const float* Wk = (const float*)d_in[3];
    const float* bk = (const float*)d_in[4];
    const float* Wv = (const float*)d_in[5];
    const float* bv = (const float*)d_in[6];
    const float* Wo = (const float*)d_in[7];
    const float* bo = (const float*)d_in[8];

    char* ws = (char*)d_ws;
    u16* Qb    = (u16*)(ws);
    u16* Ub    = (u16*)(ws + (16ull << 20));
    u16* Vnb   = (u16*)(ws + (32ull << 20));
    u16* Ob    = (u16*)(ws + (48ull << 20));
    float* A    = (float*)(ws + (64ull << 20));
    float* S    = (float*)(ws + (72ull << 20));
    float* Wm   = (float*)(ws + (80ull << 20));
    float* Z    = (float*)(ws + (82ull << 20));
    float* Zs   = (float*)(ws + (84ull << 20));
    float* Alpha= (float*)(ws + (86ull << 20));
    float* OBSA = (float*)(ws + (88ull << 20));
    float* G    = (float*)(ws + (92ull << 20));
    float* Cm   = (float*)(ws + (92ull << 20) + (512ull << 10));
    float* P    = (float*)(ws + (93ull << 20));
    float* Ga   = (float*)(ws + (93ull << 20) + (512ull << 10));
    float* Gv   = (float*)(ws + (94ull << 20));
    float* invd = (float*)(ws + (94ull << 20) + (512ull << 10));
    float* ca   = (float*)(ws + (94ull << 20) + (516ull << 10));
    float* cb   = (float*)(ws + (94ull << 20) + (520ull << 10));
    float* sseq = (float*)(ws + (94ull << 20) + (528ull << 10));
    float* SnSq = (float*)(ws + (94ull << 20) + (600ull << 10));
    float* AnAcc= (float*)(ws + (94ull << 20) + (600ull << 10) + 64);
    float* gdiag= (float*)(ws + (94ull << 20) + (600ull << 10) + 128);

    dim3 gg(16384 / 64, 512 / 64);
    gemm_xwT<0, 1><<<gg, 256, 0, stream>>>(x, Wq, bq, Qb, 512, 1.f);
    gemm_xwT<0, 1><<<gg, 256, 0, stream>>>(x, Wk, bk, Ub, 512, 0.04419417382415922f);
    gemm_xwT<0, 1><<<gg, 256, 0, stream>>>(x, Wv, bv, Vnb, 512, 1.f);
    prep_kernel<<<4096, 256, 0, stream>>>(Qb, Ub, Vnb, sseq);
    init_kernel<<<2048, 256, 0, stream>>>((float4*)A, (float4*)S, SnSq, AnAcc);

    for (int c = 0; c < NC; ++c) {
        const int t0 = c * LL;
        const u16* Ut = Ub + (size_t)t0 * 512;
        const u16* Qt = Qb + (size_t)t0 * 512;
        const u16* Vt = Vnb + (size_t)t0 * 512;
        // K1: W = A x U_cols
        GP p1{}; p1.alay = 0; p1.Ap = A; p1.lda = 512; p1.sA = 262144;
        p1.blay = 3; p1.Bp = Ut; p1.ldb = 512; p1.sB = 1048576;
        p1.epi = 0; p1.Cp = Wm; p1.ldc = 128; p1.sC = 65536; p1.K = 512;
        gemmx<<<dim3(8, 2, 8), 256, 0, stream>>>(p1);
        // K2: G = U^T W
        GP p2{}; p2.alay = 2; p2.Ap = Ut; p2.lda = 512; p2.sA = 1048576;
        p2.blay = 0; p2.Bp = Wm; p2.ldb = 128; p2.sB = 65536;
        p2.epi = 0; p2.Cp = G; p2.ldc = 128; p2.sC = 16384; p2.K = 512;
        gemmx<<<dim3(2, 2, 8), 256, 0, stream>>>(p2);
        elim_kernel<<<8, 256, 0, stream>>>(G, Cm, sseq, invd, ca, cb, t0);
        fsub_kernel<<<dim3(4, 1, 8), 128, 0, stream>>>(Wm, Cm, invd, ca, cb,
            Ub + (size_t)(t0 + 127) * 512, Z, Zs, Alpha);
        gram3_kernel<<<dim3(2, 2, 24), 256, 0, stream>>>(Alpha, Qt, Vt, P, Ga, Gv);
        // K6: [OB | SA] = S x [Q | Alpha]
        GP p6{}; p6.alay = 0; p6.Ap = S; p6.lda = 512; p6.sA = 262144;
        p6.blay = 5; p6.Bp = Qt; p6.ldb = 512; p6.sB = 1048576;
        p6.Baux = Alpha; p6.sBaux = 65536;
        p6.epi = 0; p6.Cp = OBSA; p6.ldc = 256; p6.sC = 131072; p6.K = 512;
        gemmx<<<dim3(8, 4, 8), 256, 0, stream>>>(p6);
        guard_kernel<<<8, 256, 0, stream>>>(OBSA, Vt, Ga, Gv, SnSq, AnAcc, gdiag);
        // K8: O^T = maskedP^T x Vn_rows + OB^T -> Ob (bf16)
        GP p8{}; p8.alay = 4; p8.Ap = P; p8.lda = 128; p8.sA = 16384;
        p8.blay = 2; p8.Bp = Vt; p8.ldb = 512; p8.sB = 1048576;
        p8.epi = 3; p8.Cp = Ob + (size_t)t0 * 512; p8.ldc = 512; p8.sC = 1048576;
        p8.Cio = OBSA; p8.sCio = 131072; p8.K = 128;
        gemmx<<<dim3(2, 8, 8), 256, 0, stream>>>(p8);
        // K9: S += Vn_cols x Alpha^T
        GP p9{}; p9.alay = 3; p9.Ap = Vt; p9.lda = 512; p9.sA = 1048576;
        p9.blay = 1; p9.Bp = Alpha; p9.ldb = 128; p9.sB = 65536;
        p9.epi = 2; p9.Cio = S; p9.sCio = 262144; p9.ldc = 512; p9.K = 128;
        gemmx<<<dim3(8, 8, 8), 256, 0, stream>>>(p9);
        // K10: A = A - Zs Z^T + gdiag*I ; accumulate ||A||^2 -> AnAcc
        GP p10{}; p10.alay = 0; p10.Ap = Zs; p10.lda = 128; p10.sA = 65536;
        p10.blay = 1; p10.Bp = Z; p10.ldb = 128; p10.sB = 65536;
        p10.epi = 1; p10.Cio = A; p10.sCio = 262144; p10.ldc = 512;
        p10.gdiag = gdiag; p10.anacc = AnAcc; p10.K = 128;
        gemmx<<<dim3(8, 8, 8), 256, 0, stream>>>(p10);
    }
    gemm_xwT<1, 0><<<gg, 256, 0, stream>>>(Ob, Wo, bo, d_out, 512, 1.f);
}

// Round 5
// 6186.168 us; speedup vs baseline: 5.7814x; 1.2310x over previous
//
#include <hip/hip_runtime.h>
#include <hip/hip_bf16.h>

#define BB 8
#define TT 2048
#define DD 512
#define LL 128
#define NC 16

typedef unsigned short u16;
typedef unsigned int u32;
typedef __attribute__((ext_vector_type(8))) short bf16x8v;
typedef __attribute__((ext_vector_type(4))) float f32x4v;

__device__ __forceinline__ float bf2f(u32 h) { return __uint_as_float(h << 16); }
__device__ __forceinline__ u16 f2bf(float f) {
    u32 u = __float_as_uint(f);
    u += 0x7fffu + ((u >> 16) & 1u);
    return (u16)(u >> 16);
}
__device__ __forceinline__ float wred64(float v) {
    #pragma unroll
    for (int off = 32; off; off >>= 1) v += __shfl_xor(v, off);
    return v;
}
__device__ __forceinline__ void unpack8(uint4 r, float* f) {
    f[0] = bf2f(r.x & 0xffff); f[1] = bf2f(r.x >> 16);
    f[2] = bf2f(r.y & 0xffff); f[3] = bf2f(r.y >> 16);
    f[4] = bf2f(r.z & 0xffff); f[5] = bf2f(r.z >> 16);
    f[6] = bf2f(r.w & 0xffff); f[7] = bf2f(r.w >> 16);
}

// ---------------- f32 -> bf16 convert ----------------
__global__ __launch_bounds__(256)
void f2bf_kernel(const float4* __restrict__ in, ushort4* __restrict__ out, const int n4)
{
    int i = blockIdx.x * 256 + threadIdx.x;
    const int stride = gridDim.x * 256;
    for (; i < n4; i += stride) {
        const float4 v = in[i];
        ushort4 o;
        o.x = f2bf(v.x); o.y = f2bf(v.y); o.z = f2bf(v.z); o.w = f2bf(v.w);
        out[i] = o;
    }
}

// ---------------- MFMA bf16 GEMM: C[m][n] = (sum_k A[m][k]B[n][k] + bias[n])*scale ----------------
// A: [M][512] bf16, B: [512][512] bf16 (row n = output col). Tile 128x128, BK=64,
// 4 waves in 2x2, each wave 64x64 via 4x4 frags of 16x16x32. global_load_lds w=16,
// chunk-XOR swizzle applied on global source + ds_read (LDS dest linear, rule #21).
template<int OUT_BF>
__global__ __launch_bounds__(256)
void mfma_gemm(const u16* __restrict__ Abf, const u16* __restrict__ Bbf,
               const float* __restrict__ bias, void* __restrict__ Cout,
               const float outscale)
{
    __shared__ u16 Asm[128 * 64];
    __shared__ u16 Bsm[128 * 64];
    const int tid = threadIdx.x;
    const int wave = tid >> 6, lane = tid & 63;
    const int wm = wave >> 1, wn = wave & 1;
    const int m0 = blockIdx.x * 128, n0 = blockIdx.y * 128;

    f32x4v acc[4][4];
    #pragma unroll
    for (int i = 0; i < 4; ++i)
        #pragma unroll
        for (int j = 0; j < 4; ++j)
            acc[i][j] = (f32x4v){0.f, 0.f, 0.f, 0.f};

    // staging source: chunk idx = i*256+tid ; row = idx>>3, c = idx&7, logical kb = c ^ (row&7)
    const u16* gsrcA[4];
    const u16* gsrcB[4];
    #pragma unroll
    for (int i = 0; i < 4; ++i) {
        const int idx = i * 256 + tid;
        const int row = idx >> 3, c = idx & 7;
        const int kb = c ^ (row & 7);
        gsrcA[i] = Abf + (size_t)(m0 + row) * 512 + kb * 8;
        gsrcB[i] = Bbf + (size_t)(n0 + row) * 512 + kb * 8;
    }

    for (int k0 = 0; k0 < 512; k0 += 64) {
        __syncthreads();
        #pragma unroll
        for (int i = 0; i < 4; ++i) {
            __builtin_amdgcn_global_load_lds(
                (__attribute__((address_space(1))) void*)(gsrcA[i] + k0),
                (__attribute__((address_space(3))) void*)(Asm + (size_t)(i * 256 + wave * 64) * 8),
                16, 0, 0);
            __builtin_amdgcn_global_load_lds(
                (__attribute__((address_space(1))) void*)(gsrcB[i] + k0),
                (__attribute__((address_space(3))) void*)(Bsm + (size_t)(i * 256 + wave * 64) * 8),
                16, 0, 0);
        }
        asm volatile("s_waitcnt vmcnt(0)" ::: "memory");
        __syncthreads();

        const int l15 = lane & 15, lhi = lane >> 4;
        bf16x8v af[4][2], bfr[4][2];
        #pragma unroll
        for (int mf = 0; mf < 4; ++mf) {
            const int row = wm * 64 + mf * 16 + l15;
            const int sw = (row & 7) << 4;
            #pragma unroll
            for (int ks = 0; ks < 2; ++ks) {
                const int kbyte = ks * 64 + lhi * 16;
                af[mf][ks] = *(const bf16x8v*)((const char*)Asm + row * 128 + (kbyte ^ sw));
            }
        }
        #pragma unroll
        for (int nf = 0; nf < 4; ++nf) {
            const int row = wn * 64 + nf * 16 + l15;
            const int sw = (row & 7) << 4;
            #pragma unroll
            for (int ks = 0; ks < 2; ++ks) {
                const int kbyte = ks * 64 + lhi * 16;
                bfr[nf][ks] = *(const bf16x8v*)((const char*)Bsm + row * 128 + (kbyte ^ sw));
            }
        }
        #pragma unroll
        for (int ks = 0; ks < 2; ++ks)
            #pragma unroll
            for (int mf = 0; mf < 4; ++mf)
                #pragma unroll
                for (int nf = 0; nf < 4; ++nf)
                    acc[mf][nf] = __builtin_amdgcn_mfma_f32_16x16x32_bf16(
                        af[mf][ks], bfr[nf][ks], acc[mf][nf], 0, 0, 0);
    }
    const int l15 = lane & 15, lhi = lane >> 4;
    #pragma unroll
    for (int mf = 0; mf < 4; ++mf) {
        #pragma unroll
        for (int nf = 0; nf < 4; ++nf) {
            const int n = n0 + wn * 64 + nf * 16 + l15;
            const float bsv = bias[n];
            #pragma unroll
            for (int r = 0; r < 4; ++r) {
                const int m = m0 + wm * 64 + mf * 16 + lhi * 4 + r;
                const float val = (acc[mf][nf][r] + bsv) * outscale;
                if (OUT_BF) ((u16*)Cout)[(size_t)m * 512 + n] = f2bf(val);
                else        ((float*)Cout)[(size_t)m * 512 + n] = val;
            }
        }
    }
}

// ---------------- prep: s_seq, Vn normalize ----------------
__global__ __launch_bounds__(256)
void prep_kernel(const u16* __restrict__ Qb, const u16* __restrict__ Ub,
                 u16* __restrict__ Vb, float* __restrict__ sseq)
{
    const int lane = threadIdx.x & 63, wid = threadIdx.x >> 6;
    const int row = blockIdx.x * 4 + wid;
    const size_t base = (size_t)row * DD;
    const uint4 qr = *(const uint4*)(Qb + base + lane * 8);
    const uint4 ur = *(const uint4*)(Ub + base + lane * 8);
    const uint4 vr = *(const uint4*)(Vb + base + lane * 8);
    float q[8], u[8], v[8];
    unpack8(qr, q); unpack8(ur, u); unpack8(vr, v);
    float sd = 0.f, nv = 0.f;
    #pragma unroll
    for (int e = 0; e < 8; ++e) { sd = fmaf(q[e], u[e], sd); nv = fmaf(v[e], v[e], nv); }
    #pragma unroll
    for (int off = 32; off; off >>= 1) { sd += __shfl_xor(sd, off); nv += __shfl_xor(nv, off); }
    if (lane == 0) sseq[row] = sd * 22.627416997969522f;
    const float inv = 1.f / (sqrtf(nv) + 1e-6f);
    uint4 o;
    o.x = (u32)f2bf(v[0] * inv) | ((u32)f2bf(v[1] * inv) << 16);
    o.y = (u32)f2bf(v[2] * inv) | ((u32)f2bf(v[3] * inv) << 16);
    o.z = (u32)f2bf(v[4] * inv) | ((u32)f2bf(v[5] * inv) << 16);
    o.w = (u32)f2bf(v[6] * inv) | ((u32)f2bf(v[7] * inv) << 16);
    *(uint4*)(Vb + base + lane * 8) = o;
}

__global__ __launch_bounds__(256)
void init_kernel(float4* __restrict__ A4, float4* __restrict__ S4,
                 float* __restrict__ SnSq, float* __restrict__ AnAcc)
{
    const int gtid = blockIdx.x * 256 + threadIdx.x;
    const int N4 = BB * DD * DD / 4;
    for (int idx = gtid; idx < N4; idx += gridDim.x * 256) {
        const int e0 = idx << 2;
        const int r = (e0 >> 9) & 511;
        const int c = e0 & 511;
        float4 v;
        v.x = (c + 0 == r) ? 1.f : 0.f;
        v.y = (c + 1 == r) ? 1.f : 0.f;
        v.z = (c + 2 == r) ? 1.f : 0.f;
        v.w = (c + 3 == r) ? 1.f : 0.f;
        A4[idx] = v;
        S4[idx] = make_float4(0.f, 0.f, 0.f, 0.f);
    }
    if (gtid < BB) { SnSq[gtid] = 0.f; AnAcc[gtid] = 512.f; }
}

// ---------------- generic chunk GEMM (f32 vector; round-3 proven) ----------------
struct GP {
    int alay, blay, epi;
    const void* Ap; const void* Bp; const void* Baux;
    void* Cp; float* Cio;
    const float* gdiag; float* anacc;
    int lda, ldb, ldc, K;
    long sA, sB, sBaux, sC, sCio;
};

__device__ __forceinline__ void gemm_body(const GP& p, const int bz) {
    __shared__ __align__(16) float As[32][68];
    __shared__ __align__(16) float Bs[32][68];
    const int m0 = blockIdx.x * 64, n0 = blockIdx.y * 64;
    const int tid = threadIdx.x, tx = tid & 15, ty = tid >> 4;
    float acc[4][4] = {};
    for (int k0 = 0; k0 < p.K; k0 += 32) {
        if (p.alay == 0) {
            const float* A = (const float*)p.Ap + (size_t)bz * p.sA;
            #pragma unroll
            for (int h = 0; h < 2; ++h) {
                const int g = tid + h * 256, m = g >> 3, k4 = (g & 7) * 4;
                const float4 r = *(const float4*)(A + (size_t)(m0 + m) * p.lda + k0 + k4);
                As[k4][m] = r.x; As[k4+1][m] = r.y; As[k4+2][m] = r.z; As[k4+3][m] = r.w;
            }
        } else if (p.alay == 2) {
            const u16* A = (const u16*)p.Ap + (size_t)bz * p.sA;
            #pragma unroll
            for (int h = 0; h < 2; ++h) {
                const int g = tid + h * 256, m = g >> 3, k4 = (g & 7) * 4;
                const ushort4 r = *(const ushort4*)(A + (size_t)(m0 + m) * p.lda + k0 + k4);
                As[k4][m]=bf2f(r.x); As[k4+1][m]=bf2f(r.y); As[k4+2][m]=bf2f(r.z); As[k4+3][m]=bf2f(r.w);
            }
        } else if (p.alay == 1 || p.alay == 4) {
            const float* A = (const float*)p.Ap + (size_t)bz * p.sA;
            #pragma unroll
            for (int h = 0; h < 2; ++h) {
                const int g = tid + h * 256, k = g >> 4, m4 = (g & 15) * 4;
                float4 r = *(const float4*)(A + (size_t)(k0 + k) * p.lda + m0 + m4);
                if (p.alay == 4) {
                    const int kg = k0 + k, mg = m0 + m4;
                    if (kg > mg + 0) r.x = 0.f;
                    if (kg > mg + 1) r.y = 0.f;
                    if (kg > mg + 2) r.z = 0.f;
                    if (kg > mg + 3) r.w = 0.f;
                }
                As[k][m4] = r.x; As[k][m4+1] = r.y; As[k][m4+2] = r.z; As[k][m4+3] = r.w;
            }
        } else { // 3
            const u16* A = (const u16*)p.Ap + (size_t)bz * p.sA;
            #pragma unroll
            for (int h = 0; h < 2; ++h) {
                const int g = tid + h * 256, k = g >> 4, m4 = (g & 15) * 4;
                const ushort4 r = *(const ushort4*)(A + (size_t)(k0 + k) * p.lda + m0 + m4);
                As[k][m4]=bf2f(r.x); As[k][m4+1]=bf2f(r.y); As[k][m4+2]=bf2f(r.z); As[k][m4+3]=bf2f(r.w);
            }
        }
        if (p.blay == 0) {
            const float* B = (const float*)p.Bp + (size_t)bz * p.sB;
            #pragma unroll
            for (int h = 0; h < 2; ++h) {
                const int g = tid + h * 256, k = g >> 4, n4 = (g & 15) * 4;
                const float4 r = *(const float4*)(B + (size_t)(k0 + k) * p.ldb + n0 + n4);
                Bs[k][n4] = r.x; Bs[k][n4+1] = r.y; Bs[k][n4+2] = r.z; Bs[k][n4+3] = r.w;
            }
        } else if (p.blay == 2) {
            const u16* B = (const u16*)p.Bp + (size_t)bz * p.sB;
            #pragma unroll
            for (int h = 0; h < 2; ++h) {
                const int g = tid + h * 256, k = g >> 4, n4 = (g & 15) * 4;
                const ushort4 r = *(const ushort4*)(B + (size_t)(k0 + k) * p.ldb + n0 + n4);
                Bs[k][n4]=bf2f(r.x); Bs[k][n4+1]=bf2f(r.y); Bs[k][n4+2]=bf2f(r.z); Bs[k][n4+3]=bf2f(r.w);
            }
        } else if (p.blay == 1) {
            const float* B = (const float*)p.Bp + (size_t)bz * p.sB;
            #pragma unroll
            for (int h = 0; h < 2; ++h) {
                const int g = tid + h * 256, n = g >> 3, k4 = (g & 7) * 4;
                const float4 r = *(const float4*)(B + (size_t)(n0 + n) * p.ldb + k0 + k4);
                Bs[k4][n] = r.x; Bs[k4+1][n] = r.y; Bs[k4+2][n] = r.z; Bs[k4+3][n] = r.w;
            }
        } else if (p.blay == 3) {
            const u16* B = (const u16*)p.Bp + (size_t)bz * p.sB;
            #pragma unroll
            for (int h = 0; h < 2; ++h) {
                const int g = tid + h * 256, n = g >> 3, k4 = (g & 7) * 4;
                const ushort4 r = *(const ushort4*)(B + (size_t)(n0 + n) * p.ldb + k0 + k4);
                Bs[k4][n]=bf2f(r.x); Bs[k4+1][n]=bf2f(r.y); Bs[k4+2][n]=bf2f(r.z); Bs[k4+3][n]=bf2f(r.w);
            }
        } else { // 5: mixed [Q | Alpha]
            if (n0 < 128) {
                const u16* B = (const u16*)p.Bp + (size_t)bz * p.sB;
                #pragma unroll
                for (int h = 0; h < 2; ++h) {
                    const int g = tid + h * 256, n = g >> 3, k4 = (g & 7) * 4;
                    const ushort4 r = *(const ushort4*)(B + (size_t)(n0 + n) * p.ldb + k0 + k4);
                    Bs[k4][n]=bf2f(r.x); Bs[k4+1][n]=bf2f(r.y); Bs[k4+2][n]=bf2f(r.z); Bs[k4+3][n]=bf2f(r.w);
                }
            } else {
                const float* B = (const float*)p.Baux + (size_t)bz * p.sBaux;
                #pragma unroll
                for (int h = 0; h < 2; ++h) {
                    const int g = tid + h * 256, k = g >> 4, n4 = (g & 15) * 4;
                    const float4 r = *(const float4*)(B + (size_t)(k0 + k) * 128 + (n0 - 128) + n4);
                    Bs[k][n4] = r.x; Bs[k][n4+1] = r.y; Bs[k][n4+2] = r.z; Bs[k][n4+3] = r.w;
                }
            }
        }
        __syncthreads();
        #pragma unroll
        for (int kk = 0; kk < 32; ++kk) {
            const float4 xa = *(const float4*)&As[kk][ty * 4];
            const float4 wb = *(const float4*)&Bs[kk][tx * 4];
            const float xv[4] = {xa.x, xa.y, xa.z, xa.w};
            const float wv[4] = {wb.x, wb.y, wb.z, wb.w};
            #pragma unroll
            for (int i = 0; i < 4; ++i)
                #pragma unroll
                for (int j = 0; j < 4; ++j)
                    acc[i][j] = fmaf(xv[i], wv[j], acc[i][j]);
        }
        __syncthreads();
    }
    const int mb = m0 + ty * 4, nb = n0 + tx * 4;
    if (p.epi == 0) {
        float* C = (float*)p.Cp + (size_t)bz * p.sC;
        #pragma unroll
        for (int i = 0; i < 4; ++i)
            #pragma unroll
            for (int j = 0; j < 4; ++j)
                C[(size_t)(mb + i) * p.ldc + nb + j] = acc[i][j];
    } else if (p.epi == 1) {
        float* C = p.Cio + (size_t)bz * p.sCio;
        const float gd = p.gdiag[bz];
        float v2 = 0.f;
        #pragma unroll
        for (int i = 0; i < 4; ++i)
            #pragma unroll
            for (int j = 0; j < 4; ++j) {
                const size_t idx = (size_t)(mb + i) * p.ldc + nb + j;
                float v = C[idx] - acc[i][j] + ((mb + i) == (nb + j) ? gd : 0.f);
                C[idx] = v;
                v2 = fmaf(v, v, v2);
            }
        v2 = wred64(v2);
        if ((tid & 63) == 0) atomicAdd(p.anacc + bz, v2);
    } else if (p.epi == 2) {
        float* C = p.Cio + (size_t)bz * p.sCio;
        #pragma unroll
        for (int i = 0; i < 4; ++i)
            #pragma unroll
            for (int j = 0; j < 4; ++j)
                C[(size_t)(mb + i) * p.ldc + nb + j] += acc[i][j];
    } else { // 3
        u16* O = (u16*)p.Cp + (size_t)bz * p.sC;
        const float* OB = p.Cio + (size_t)bz * p.sCio;
        #pragma unroll
        for (int i = 0; i < 4; ++i)
            #pragma unroll
            for (int j = 0; j < 4; ++j)
                O[(size_t)(mb + i) * p.ldc + nb + j] =
                    f2bf(acc[i][j] + OB[(size_t)(nb + j) * 256 + mb + i]);
    }
}

__global__ __launch_bounds__(256) void gemmx(GP p) { gemm_body(p, blockIdx.z); }

// ---------------- merged level-5: gram3 (P, Ga, Gv) + K6 (OBSA) ----------------
__global__ __launch_bounds__(256)
void lvl5_kernel(const float* Alpha, const u16* Qt, const u16* Vnt, const float* S,
                 float* P, float* Ga, float* Gv, float* OBSA)
{
    const int z = blockIdx.z;
    GP p{};
    if (z < 8) {
        p.alay = 0; p.Ap = S; p.lda = 512; p.sA = 262144;
        p.blay = 5; p.Bp = Qt; p.ldb = 512; p.sB = 1048576;
        p.Baux = Alpha; p.sBaux = 65536;
        p.epi = 0; p.Cp = OBSA; p.ldc = 256; p.sC = 131072; p.K = 512;
        gemm_body(p, z);
    } else {
        if (blockIdx.x >= 2 || blockIdx.y >= 2) return;
        const int zz = z - 8, b = zz / 3, j = zz - b * 3;
        p.K = 512; p.epi = 0; p.ldc = 128; p.sC = 16384;
        if (j == 0) {
            p.alay = 1; p.Ap = Alpha; p.lda = 128; p.sA = 65536;
            p.blay = 3; p.Bp = Qt; p.ldb = 512; p.sB = 1048576; p.Cp = P;
        } else if (j == 1) {
            p.alay = 1; p.Ap = Alpha; p.lda = 128; p.sA = 65536;
            p.blay = 0; p.Bp = Alpha; p.ldb = 128; p.sB = 65536; p.Cp = Ga;
        } else {
            p.alay = 2; p.Ap = Vnt; p.lda = 512; p.sA = 1048576;
            p.blay = 3; p.Bp = Vnt; p.ldb = 512; p.sB = 1048576; p.Cp = Gv;
        }
        gemm_body(p, b);
    }
}

// ---------------- merged level-7: K8 (O out) + K9 (S update) + K10 (A update) ----------------
__global__ __launch_bounds__(256)
void lvl7_kernel(const float* P, const u16* Vnt, u16* Obt, const float* OBSA,
                 const float* Alpha, const float* Zs, const float* Z,
                 float* S, float* A, const float* gdiag, float* AnAcc)
{
    const int z = blockIdx.z;
    GP p{};
    if (z < 8) {
        p.alay = 0; p.Ap = Zs; p.lda = 128; p.sA = 65536;
        p.blay = 1; p.Bp = Z; p.ldb = 128; p.sB = 65536;
        p.epi = 1; p.Cio = A; p.sCio = 262144; p.ldc = 512;
        p.gdiag = gdiag; p.anacc = AnAcc; p.K = 128;
        gemm_body(p, z);
    } else if (z < 16) {
        p.alay = 3; p.Ap = Vnt; p.lda = 512; p.sA = 1048576;
        p.blay = 1; p.Bp = Alpha; p.ldb = 128; p.sB = 65536;
        p.epi = 2; p.Cio = S; p.sCio = 262144; p.ldc = 512; p.K = 128;
        gemm_body(p, z - 8);
    } else {
        if (blockIdx.x >= 2) return;
        p.alay = 4; p.Ap = P; p.lda = 128; p.sA = 16384;
        p.blay = 2; p.Bp = Vnt; p.ldb = 512; p.sB = 1048576;
        p.epi = 3; p.Cp = Obt; p.ldc = 512; p.sC = 1048576;
        p.Cio = (float*)OBSA; p.sCio = 131072; p.K = 128;
        gemm_body(p, z - 16);
    }
}

// ---------------- blocked wave-synchronous elimination ----------------
__global__ __launch_bounds__(256)
void elim_kernel(const float* __restrict__ G, float* __restrict__ Cm,
                 const float* __restrict__ sseq, float* __restrict__ invd,
                 float* __restrict__ ca, float* __restrict__ cb, const int t0)
{
    const int b = blockIdx.x, tid = threadIdx.x, lane = tid & 63, wave = tid >> 6;
    __shared__ __align__(16) float E[128][128];
    __shared__ float del[128];
    __shared__ float Lp[128][8];
    const float4* Gb = (const float4*)(G + (size_t)b * 16384);
    float4* E4 = (float4*)E;
    for (int i = tid; i < 4096; i += 256) E4[i] = Gb[i];
    __syncthreads();

    for (int p = 0; p < 16; ++p) {
        const int pc0 = p * 8;
        if (wave == 0) {
            float pr[2][8];
            #pragma unroll
            for (int j = 0; j < 8; ++j) {
                pr[0][j] = E[2 * lane][pc0 + j];
                pr[1][j] = E[2 * lane + 1][pc0 + j];
            }
            float dl[8];
            #pragma unroll
            for (int j = 0; j < 8; ++j) {
                const int t = pc0 + j;
                const float Ett = __shfl(pr[j & 1][j], t >> 1);
                const float d = fmaxf(1.f + Ett, 1e-6f);
                dl[j] = d;
                const float inv = 1.f / d;
                float prow[8];
                #pragma unroll
                for (int c = 0; c < 8; ++c) prow[c] = __shfl(pr[j & 1][c], t >> 1);
                #pragma unroll
                for (int rr = 0; rr < 2; ++rr) {
                    const int r = 2 * lane + rr;
                    if (r > t) {
                        const float coef = pr[rr][j] * inv;
                        #pragma unroll
                        for (int c = j + 1; c < 8; ++c)
                            pr[rr][c] = fmaf(-coef, prow[c], pr[rr][c]);
                    }
                }
            }
            #pragma unroll
            for (int rr = 0; rr < 2; ++rr) {
                const int r = 2 * lane + rr;
                #pragma unroll
                for (int j = 0; j < 8; ++j) {
                    Lp[r][j] = pr[rr][j] / dl[j];
                    E[r][pc0 + j] = pr[rr][j];
                }
            }
            if (lane < 8) del[pc0 + lane] = dl[lane];
            #pragma unroll
            for (int rr = 1; rr < 8; ++rr) {
                const int r = pc0 + rr;
                for (int c = pc0 + 8 + lane; c < 128; c += 64) {
                    float e = E[r][c];
                    #pragma unroll
                    for (int j = 0; j < 8; ++j)
                        if (j < rr) e = fmaf(-Lp[r][j], E[pc0 + j][c], e);
                    E[r][c] = e;
                }
            }
        }
        __syncthreads();
        const int r0b = pc0 + 8;
        const int nrows = 128 - r0b;
        if (nrows > 0) {
            const int c40 = r0b >> 2, nc4 = 32 - c40;
            for (int idx = tid; idx < nrows * nc4; idx += 256) {
                const int rr = idx / nc4, cc = idx - rr * nc4;
                const int r = r0b + rr, c4 = c40 + cc;
                float4 e = ((float4*)&E[r][0])[c4];
                #pragma unroll
                for (int j = 0; j < 8; ++j) {
                    const float lv = Lp[r][j];
                    const float4 pv = ((const float4*)&E[pc0 + j][0])[c4];
                    e.x = fmaf(-lv, pv.x, e.x);
                    e.y = fmaf(-lv, pv.y, e.y);
                    e.z = fmaf(-lv, pv.z, e.z);
                    e.w = fmaf(-lv, pv.w, e.w);
                }
                ((float4*)&E[r][0])[c4] = e;
            }
        }
        __syncthreads();
    }

    for (int idx = tid; idx < 16384; idx += 256) {
        const int r = idx >> 7, cc = idx & 127;
        Cm[(size_t)b * 16384 + idx] = (cc > r) ? E[r][cc] * (1.f / del[r]) : 0.f;
    }
    if (tid < 128) {
        const float d = del[tid];
        const float s = sseq[(size_t)b * TT + t0 + tid];
        invd[b * 128 + tid] = 1.f / d;
        ca[b * 128 + tid] = s / d;
        cb[b * 128 + tid] = (tid == 127) ? s * 1e-6f : 0.f;
    }
}

// ---------------- forward substitution ----------------
__global__ __launch_bounds__(128)
void fsub_kernel(const float* __restrict__ W, const float* __restrict__ Cm,
                 const float* __restrict__ invd, const float* __restrict__ ca,
                 const float* __restrict__ cb, const u16* __restrict__ Ulast,
                 float* __restrict__ Z, float* __restrict__ Zs, float* __restrict__ Alpha)
{
    const int b = blockIdx.z, slab = blockIdx.x, tid = threadIdx.x;
    __shared__ __align__(16) float zl[128][129];
    __shared__ float Cp[128][32];
    const float* Wb = W + (size_t)b * 65536 + (size_t)slab * 16384;
    const float* Cb = Cm + (size_t)b * 16384;
    for (int r = 0; r < 128; ++r) zl[r][tid] = Wb[(size_t)r * 128 + tid];
    __syncthreads();
    float zreg[32];
    for (int J = 0; J < 4; ++J) {
        const int nrows = (J + 1) * 32;
        for (int idx = tid; idx < nrows * 32; idx += 128) {
            const int i = idx >> 5, cc = idx & 31;
            Cp[i][cc] = Cb[i * 128 + J * 32 + cc];
        }
        __syncthreads();
        float tmp[32];
        #pragma unroll
        for (int cc = 0; cc < 32; ++cc) tmp[cc] = zl[tid][J * 32 + cc];
        for (int i = 0; i < J * 32; ++i) {
            const float zi = zl[tid][i];
            #pragma unroll
            for (int cc = 0; cc < 32; ++cc) tmp[cc] = fmaf(-zi, Cp[i][cc], tmp[cc]);
        }
        #pragma unroll
        for (int t = 0; t < 32; ++t) {
            float v = tmp[t];
            for (int i = 0; i < t; ++i) v = fmaf(-Cp[J * 32 + i][t], zreg[i], v);
            zreg[t] = v;
        }
        #pragma unroll
        for (int cc = 0; cc < 32; ++cc) zl[tid][J * 32 + cc] = zreg[cc];
        __syncthreads();
    }
    const float iv = invd[b * 128 + tid];
    const float cav = ca[b * 128 + tid];
    const float cbv = cb[b * 128 + tid];
    const u16* Ub_l = Ulast + (size_t)b * 1048576;
    for (int r = 0; r < 128; ++r) {
        const int grow = slab * 128 + r;
        const float v = zl[r][tid];
        const size_t o = (size_t)b * 65536 + (size_t)grow * 128 + tid;
        Z[o] = v;
        Zs[o] = v * iv;
        float a = v * cav;
        if (cbv != 0.f) a = fmaf(cbv, bf2f(Ub_l[grow]), a);
        Alpha[o] = a;
    }
}

// ---------------- guard: per-step Frobenius prefix + explosion count ----------------
__global__ __launch_bounds__(256)
void guard_kernel(const float* __restrict__ OBSA, const u16* __restrict__ Vnt,
                  const float* __restrict__ Ga, const float* __restrict__ Gv,
                  float* __restrict__ SnSq, float* __restrict__ AnAcc,
                  float* __restrict__ gdiag)
{
    const int b = blockIdx.x, tid = threadIdx.x;
    __shared__ float dpart[256];
    __shared__ float dsum[128], rsum[128], mdia[128];
    const int i = tid & 127, half = tid >> 7;
    const float* SA = OBSA + (size_t)b * 131072;
    const u16* Vn = Vnt + (size_t)b * 1048576;
    float s = 0.f;
    for (int r = half * 256; r < half * 256 + 256; ++r)
        s = fmaf(bf2f(Vn[(size_t)i * 512 + r]), SA[(size_t)r * 256 + 128 + i], s);
    dpart[tid] = s;
    __syncthreads();
    if (tid < 128) {
        dsum[tid] = dpart[tid] + dpart[tid + 128];
        const float* gv = Gv + (size_t)b * 16384 + tid * 128;
        const float* ga = Ga + (size_t)b * 16384 + tid * 128;
        float rs = 0.f;
        for (int j = 0; j < tid; ++j) rs = fmaf(gv[j], ga[j], rs);
        rsum[tid] = rs;
        mdia[tid] = gv[tid] * ga[tid];
    }
    __syncthreads();
    if (tid == 0) {
        const float An2 = AnAcc[b];
        float Sn2 = SnSq[b], D = 0.f, T = 0.f;
        int ng = 0;
        for (int t = 0; t < 128; ++t) {
            D += dsum[t];
            T += mdia[t] + 2.f * rsum[t];
            const float sn2 = Sn2 + 2.f * D + T;
            if (sn2 > 1e6f || An2 > 1e6f) ++ng;
        }
        SnSq[b] = Sn2 + 2.f * D + T;
        gdiag[b] = 1e-6f + (float)ng * 1e-5f;
        AnAcc[b] = 0.f;
    }
}

extern "C" void kernel_launch(void* const* d_in, const int* in_sizes, int n_in,
                              void* d_out, int out_size, void* d_ws, size_t ws_size,
                              hipStream_t stream)
{
    const float* x  = (const float*)d_in[0];
    const float* Wq = (const float*)d_in[1];
    const float* bq = (const float*)d_in[2];
    const float* Wk = (const float*)d_in[3];
    const float* bk = (const float*)d_in[4];
    const float* Wv = (const float*)d_in[5];
    const float* bv = (const float*)d_in[6];
    const float* Wo = (const float*)d_in[7];
    const float* bo = (const float*)d_in[8];

    char* ws = (char*)d_ws;
    u16* Qb    = (u16*)(ws);
    u16* Ub    = (u16*)(ws + (16ull << 20));
    u16* Vnb   = (u16*)(ws + (32ull << 20));
    u16* Ob    = (u16*)(ws + (48ull << 20));   // also x_bf before chunk loop
    u16* x_bf  = Ob;
    float* A    = (float*)(ws + (64ull << 20));
    float* S    = (float*)(ws + (72ull << 20));
    float* Wm   = (float*)(ws + (80ull << 20));
    float* Z    = (float*)(ws + (82ull << 20));
    float* Zs   = (float*)(ws + (84ull << 20));
    float* Alpha= (float*)(ws + (86ull << 20));
    float* OBSA = (float*)(ws + (88ull << 20));
    float* G    = (float*)(ws + (92ull << 20));
    float* Cm   = (float*)(ws + (92ull << 20) + (512ull << 10));
    float* P    = (float*)(ws + (93ull << 20));
    float* Ga   = (float*)(ws + (93ull << 20) + (512ull << 10));
    float* Gv   = (float*)(ws + (94ull << 20));
    float* invd = (float*)(ws + (94ull << 20) + (512ull << 10));
    float* ca   = (float*)(ws + (94ull << 20) + (516ull << 10));
    float* cb   = (float*)(ws + (94ull << 20) + (520ull << 10));
    float* sseq = (float*)(ws + (94ull << 20) + (528ull << 10));
    float* SnSq = (float*)(ws + (94ull << 20) + (600ull << 10));
    float* AnAcc= (float*)(ws + (94ull << 20) + (600ull << 10) + 64);
    float* gdiag= (float*)(ws + (94ull << 20) + (600ull << 10) + 128);
    u16* Wq_bf = (u16*)(ws + (95ull << 20));
    u16* Wk_bf = (u16*)(ws + (95ull << 20) + (512ull << 10));
    u16* Wv_bf = (u16*)(ws + (96ull << 20));
    u16* Wo_bf = (u16*)(ws + (96ull << 20) + (512ull << 10));

    // bf16 conversions
    f2bf_kernel<<<2048, 256, 0, stream>>>((const float4*)x, (ushort4*)x_bf, 2097152);
    f2bf_kernel<<<256, 256, 0, stream>>>((const float4*)Wq, (ushort4*)Wq_bf, 65536);
    f2bf_kernel<<<256, 256, 0, stream>>>((const float4*)Wk, (ushort4*)Wk_bf, 65536);
    f2bf_kernel<<<256, 256, 0, stream>>>((const float4*)Wv, (ushort4*)Wv_bf, 65536);
    f2bf_kernel<<<256, 256, 0, stream>>>((const float4*)Wo, (ushort4*)Wo_bf, 65536);

    // projections via MFMA
    mfma_gemm<1><<<dim3(128, 4), 256, 0, stream>>>(x_bf, Wq_bf, bq, Qb, 1.f);
    mfma_gemm<1><<<dim3(128, 4), 256, 0, stream>>>(x_bf, Wk_bf, bk, Ub, 0.04419417382415922f);
    mfma_gemm<1><<<dim3(128, 4), 256, 0, stream>>>(x_bf, Wv_bf, bv, Vnb, 1.f);
    prep_kernel<<<4096, 256, 0, stream>>>(Qb, Ub, Vnb, sseq);
    init_kernel<<<2048, 256, 0, stream>>>((float4*)A, (float4*)S, SnSq, AnAcc);

    for (int c = 0; c < NC; ++c) {
        const int t0 = c * LL;
        const u16* Ut = Ub + (size_t)t0 * 512;
        const u16* Qt = Qb + (size_t)t0 * 512;
        const u16* Vt = Vnb + (size_t)t0 * 512;
        // K1: W = A x U_cols
        GP p1{}; p1.alay = 0; p1.Ap = A; p1.lda = 512; p1.sA = 262144;
        p1.blay = 3; p1.Bp = Ut; p1.ldb = 512; p1.sB = 1048576;
        p1.epi = 0; p1.Cp = Wm; p1.ldc = 128; p1.sC = 65536; p1.K = 512;
        gemmx<<<dim3(8, 2, 8), 256, 0, stream>>>(p1);
        // K2: G = U^T W
        GP p2{}; p2.alay = 2; p2.Ap = Ut; p2.lda = 512; p2.sA = 1048576;
        p2.blay = 0; p2.Bp = Wm; p2.ldb = 128; p2.sB = 65536;
        p2.epi = 0; p2.Cp = G; p2.ldc = 128; p2.sC = 16384; p2.K = 512;
        gemmx<<<dim3(2, 2, 8), 256, 0, stream>>>(p2);
        elim_kernel<<<8, 256, 0, stream>>>(G, Cm, sseq, invd, ca, cb, t0);
        fsub_kernel<<<dim3(4, 1, 8), 128, 0, stream>>>(Wm, Cm, invd, ca, cb,
            Ub + (size_t)(t0 + 127) * 512, Z, Zs, Alpha);
        lvl5_kernel<<<dim3(8, 4, 32), 256, 0, stream>>>(Alpha, Qt, Vt, S, P, Ga, Gv, OBSA);
        guard_kernel<<<8, 256, 0, stream>>>(OBSA, Vt, Ga, Gv, SnSq, AnAcc, gdiag);
        lvl7_kernel<<<dim3(8, 8, 24), 256, 0, stream>>>(P, Vt, Ob + (size_t)t0 * 512, OBSA,
            Alpha, Zs, Z, S, A, gdiag, AnAcc);
    }
    // output projection via MFMA (f32 out)
    mfma_gemm<0><<<dim3(128, 4), 256, 0, stream>>>(Ob, Wo_bf, bo, d_out, 1.f);
}

// Round 6
// 4787.376 us; speedup vs baseline: 7.4707x; 1.2922x over previous
//
#include <hip/hip_runtime.h>
#include <hip/hip_bf16.h>

#define BB 8
#define TT 2048
#define DD 512
#define LL 128
#define NC 16

typedef unsigned short u16;
typedef unsigned int u32;
typedef __attribute__((ext_vector_type(8))) short bf16x8v;
typedef __attribute__((ext_vector_type(4))) float f32x4v;

__device__ __forceinline__ float bf2f(u32 h) { return __uint_as_float(h << 16); }
__device__ __forceinline__ u16 f2bf(float f) {
    u32 u = __float_as_uint(f);
    u += 0x7fffu + ((u >> 16) & 1u);
    return (u16)(u >> 16);
}
__device__ __forceinline__ float wred64(float v) {
    #pragma unroll
    for (int off = 32; off; off >>= 1) v += __shfl_xor(v, off);
    return v;
}
__device__ __forceinline__ void unpack8(uint4 r, float* f) {
    f[0] = bf2f(r.x & 0xffff); f[1] = bf2f(r.x >> 16);
    f[2] = bf2f(r.y & 0xffff); f[3] = bf2f(r.y >> 16);
    f[4] = bf2f(r.z & 0xffff); f[5] = bf2f(r.z >> 16);
    f[6] = bf2f(r.w & 0xffff); f[7] = bf2f(r.w >> 16);
}

// ---------------- f32 -> bf16 convert ----------------
__global__ __launch_bounds__(256)
void f2bf_kernel(const float4* __restrict__ in, ushort4* __restrict__ out, const int n4)
{
    int i = blockIdx.x * 256 + threadIdx.x;
    const int stride = gridDim.x * 256;
    for (; i < n4; i += stride) {
        const float4 v = in[i];
        ushort4 o;
        o.x = f2bf(v.x); o.y = f2bf(v.y); o.z = f2bf(v.z); o.w = f2bf(v.w);
        out[i] = o;
    }
}

// ---------------- MFMA bf16 GEMM (round-5 proven) ----------------
template<int OUT_BF>
__global__ __launch_bounds__(256)
void mfma_gemm(const u16* __restrict__ Abf, const u16* __restrict__ Bbf,
               const float* __restrict__ bias, void* __restrict__ Cout,
               const float outscale)
{
    __shared__ u16 Asm[128 * 64];
    __shared__ u16 Bsm[128 * 64];
    const int tid = threadIdx.x;
    const int wave = tid >> 6, lane = tid & 63;
    const int wm = wave >> 1, wn = wave & 1;
    const int m0 = blockIdx.x * 128, n0 = blockIdx.y * 128;

    f32x4v acc[4][4];
    #pragma unroll
    for (int i = 0; i < 4; ++i)
        #pragma unroll
        for (int j = 0; j < 4; ++j)
            acc[i][j] = (f32x4v){0.f, 0.f, 0.f, 0.f};

    const u16* gsrcA[4];
    const u16* gsrcB[4];
    #pragma unroll
    for (int i = 0; i < 4; ++i) {
        const int idx = i * 256 + tid;
        const int row = idx >> 3, c = idx & 7;
        const int kb = c ^ (row & 7);
        gsrcA[i] = Abf + (size_t)(m0 + row) * 512 + kb * 8;
        gsrcB[i] = Bbf + (size_t)(n0 + row) * 512 + kb * 8;
    }

    for (int k0 = 0; k0 < 512; k0 += 64) {
        __syncthreads();
        #pragma unroll
        for (int i = 0; i < 4; ++i) {
            __builtin_amdgcn_global_load_lds(
                (__attribute__((address_space(1))) void*)(gsrcA[i] + k0),
                (__attribute__((address_space(3))) void*)(Asm + (size_t)(i * 256 + wave * 64) * 8),
                16, 0, 0);
            __builtin_amdgcn_global_load_lds(
                (__attribute__((address_space(1))) void*)(gsrcB[i] + k0),
                (__attribute__((address_space(3))) void*)(Bsm + (size_t)(i * 256 + wave * 64) * 8),
                16, 0, 0);
        }
        asm volatile("s_waitcnt vmcnt(0)" ::: "memory");
        __syncthreads();

        const int l15 = lane & 15, lhi = lane >> 4;
        bf16x8v af[4][2], bfr[4][2];
        #pragma unroll
        for (int mf = 0; mf < 4; ++mf) {
            const int row = wm * 64 + mf * 16 + l15;
            const int sw = (row & 7) << 4;
            #pragma unroll
            for (int ks = 0; ks < 2; ++ks) {
                const int kbyte = ks * 64 + lhi * 16;
                af[mf][ks] = *(const bf16x8v*)((const char*)Asm + row * 128 + (kbyte ^ sw));
            }
        }
        #pragma unroll
        for (int nf = 0; nf < 4; ++nf) {
            const int row = wn * 64 + nf * 16 + l15;
            const int sw = (row & 7) << 4;
            #pragma unroll
            for (int ks = 0; ks < 2; ++ks) {
                const int kbyte = ks * 64 + lhi * 16;
                bfr[nf][ks] = *(const bf16x8v*)((const char*)Bsm + row * 128 + (kbyte ^ sw));
            }
        }
        #pragma unroll
        for (int ks = 0; ks < 2; ++ks)
            #pragma unroll
            for (int mf = 0; mf < 4; ++mf)
                #pragma unroll
                for (int nf = 0; nf < 4; ++nf)
                    acc[mf][nf] = __builtin_amdgcn_mfma_f32_16x16x32_bf16(
                        af[mf][ks], bfr[nf][ks], acc[mf][nf], 0, 0, 0);
    }
    const int l15 = lane & 15, lhi = lane >> 4;
    #pragma unroll
    for (int mf = 0; mf < 4; ++mf) {
        #pragma unroll
        for (int nf = 0; nf < 4; ++nf) {
            const int n = n0 + wn * 64 + nf * 16 + l15;
            const float bsv = bias[n];
            #pragma unroll
            for (int r = 0; r < 4; ++r) {
                const int m = m0 + wm * 64 + mf * 16 + lhi * 4 + r;
                const float val = (acc[mf][nf][r] + bsv) * outscale;
                if (OUT_BF) ((u16*)Cout)[(size_t)m * 512 + n] = f2bf(val);
                else        ((float*)Cout)[(size_t)m * 512 + n] = val;
            }
        }
    }
}

// ---------------- prep: s_seq, Vn normalize ----------------
__global__ __launch_bounds__(256)
void prep_kernel(const u16* __restrict__ Qb, const u16* __restrict__ Ub,
                 u16* __restrict__ Vb, float* __restrict__ sseq)
{
    const int lane = threadIdx.x & 63, wid = threadIdx.x >> 6;
    const int row = blockIdx.x * 4 + wid;
    const size_t base = (size_t)row * DD;
    const uint4 qr = *(const uint4*)(Qb + base + lane * 8);
    const uint4 ur = *(const uint4*)(Ub + base + lane * 8);
    const uint4 vr = *(const uint4*)(Vb + base + lane * 8);
    float q[8], u[8], v[8];
    unpack8(qr, q); unpack8(ur, u); unpack8(vr, v);
    float sd = 0.f, nv = 0.f;
    #pragma unroll
    for (int e = 0; e < 8; ++e) { sd = fmaf(q[e], u[e], sd); nv = fmaf(v[e], v[e], nv); }
    #pragma unroll
    for (int off = 32; off; off >>= 1) { sd += __shfl_xor(sd, off); nv += __shfl_xor(nv, off); }
    if (lane == 0) sseq[row] = sd * 22.627416997969522f;
    const float inv = 1.f / (sqrtf(nv) + 1e-6f);
    uint4 o;
    o.x = (u32)f2bf(v[0] * inv) | ((u32)f2bf(v[1] * inv) << 16);
    o.y = (u32)f2bf(v[2] * inv) | ((u32)f2bf(v[3] * inv) << 16);
    o.z = (u32)f2bf(v[4] * inv) | ((u32)f2bf(v[5] * inv) << 16);
    o.w = (u32)f2bf(v[6] * inv) | ((u32)f2bf(v[7] * inv) << 16);
    *(uint4*)(Vb + base + lane * 8) = o;
}

__global__ __launch_bounds__(256)
void init_kernel(float4* __restrict__ A4, float4* __restrict__ S4,
                 float* __restrict__ SnSq, float* __restrict__ AnAcc)
{
    const int gtid = blockIdx.x * 256 + threadIdx.x;
    const int N4 = BB * DD * DD / 4;
    for (int idx = gtid; idx < N4; idx += gridDim.x * 256) {
        const int e0 = idx << 2;
        const int r = (e0 >> 9) & 511;
        const int c = e0 & 511;
        float4 v;
        v.x = (c + 0 == r) ? 1.f : 0.f;
        v.y = (c + 1 == r) ? 1.f : 0.f;
        v.z = (c + 2 == r) ? 1.f : 0.f;
        v.w = (c + 3 == r) ? 1.f : 0.f;
        A4[idx] = v;
        S4[idx] = make_float4(0.f, 0.f, 0.f, 0.f);
    }
    if (gtid < BB) { SnSq[gtid] = 0.f; AnAcc[gtid] = 512.f; }
}

// ---------------- generic chunk GEMM ----------------
// epi: 0 C=acc; 1 A-update(+norm); 2 C+=acc; 3 bf16 out+OB; 4 Z/Zs/Alpha epilogue;
//      5 C=acc + diag(Vn^T SA) atomics for n>=128
struct GP {
    int alay, blay, epi;
    const void* Ap; const void* Bp; const void* Baux;
    void* Cp; float* Cio;
    const float* gdiag; float* anacc;
    const float* invdp; const float* cap; const float* cbp;
    const u16* Ulastp; float* Zsp; float* Alphap;
    const u16* Vnp; float* dsump;
    int lda, ldb, ldc, K;
    long sA, sB, sBaux, sC, sCio;
};

__device__ __forceinline__ void gemm_body(const GP& p, const int bz) {
    __shared__ __align__(16) float As[32][68];
    __shared__ __align__(16) float Bs[32][68];
    const int m0 = blockIdx.x * 64, n0 = blockIdx.y * 64;
    const int tid = threadIdx.x, tx = tid & 15, ty = tid >> 4;
    float acc[4][4] = {};
    for (int k0 = 0; k0 < p.K; k0 += 32) {
        if (p.alay == 0) {
            const float* A = (const float*)p.Ap + (size_t)bz * p.sA;
            #pragma unroll
            for (int h = 0; h < 2; ++h) {
                const int g = tid + h * 256, m = g >> 3, k4 = (g & 7) * 4;
                const float4 r = *(const float4*)(A + (size_t)(m0 + m) * p.lda + k0 + k4);
                As[k4][m] = r.x; As[k4+1][m] = r.y; As[k4+2][m] = r.z; As[k4+3][m] = r.w;
            }
        } else if (p.alay == 2) {
            const u16* A = (const u16*)p.Ap + (size_t)bz * p.sA;
            #pragma unroll
            for (int h = 0; h < 2; ++h) {
                const int g = tid + h * 256, m = g >> 3, k4 = (g & 7) * 4;
                const ushort4 r = *(const ushort4*)(A + (size_t)(m0 + m) * p.lda + k0 + k4);
                As[k4][m]=bf2f(r.x); As[k4+1][m]=bf2f(r.y); As[k4+2][m]=bf2f(r.z); As[k4+3][m]=bf2f(r.w);
            }
        } else if (p.alay == 1 || p.alay == 4) {
            const float* A = (const float*)p.Ap + (size_t)bz * p.sA;
            #pragma unroll
            for (int h = 0; h < 2; ++h) {
                const int g = tid + h * 256, k = g >> 4, m4 = (g & 15) * 4;
                float4 r = *(const float4*)(A + (size_t)(k0 + k) * p.lda + m0 + m4);
                if (p.alay == 4) {
                    const int kg = k0 + k, mg = m0 + m4;
                    if (kg > mg + 0) r.x = 0.f;
                    if (kg > mg + 1) r.y = 0.f;
                    if (kg > mg + 2) r.z = 0.f;
                    if (kg > mg + 3) r.w = 0.f;
                }
                As[k][m4] = r.x; As[k][m4+1] = r.y; As[k][m4+2] = r.z; As[k][m4+3] = r.w;
            }
        } else { // 3
            const u16* A = (const u16*)p.Ap + (size_t)bz * p.sA;
            #pragma unroll
            for (int h = 0; h < 2; ++h) {
                const int g = tid + h * 256, k = g >> 4, m4 = (g & 15) * 4;
                const ushort4 r = *(const ushort4*)(A + (size_t)(k0 + k) * p.lda + m0 + m4);
                As[k][m4]=bf2f(r.x); As[k][m4+1]=bf2f(r.y); As[k][m4+2]=bf2f(r.z); As[k][m4+3]=bf2f(r.w);
            }
        }
        if (p.blay == 0) {
            const float* B = (const float*)p.Bp + (size_t)bz * p.sB;
            #pragma unroll
            for (int h = 0; h < 2; ++h) {
                const int g = tid + h * 256, k = g >> 4, n4 = (g & 15) * 4;
                const float4 r = *(const float4*)(B + (size_t)(k0 + k) * p.ldb + n0 + n4);
                Bs[k][n4] = r.x; Bs[k][n4+1] = r.y; Bs[k][n4+2] = r.z; Bs[k][n4+3] = r.w;
            }
        } else if (p.blay == 2) {
            const u16* B = (const u16*)p.Bp + (size_t)bz * p.sB;
            #pragma unroll
            for (int h = 0; h < 2; ++h) {
                const int g = tid + h * 256, k = g >> 4, n4 = (g & 15) * 4;
                const ushort4 r = *(const ushort4*)(B + (size_t)(k0 + k) * p.ldb + n0 + n4);
                Bs[k][n4]=bf2f(r.x); Bs[k][n4+1]=bf2f(r.y); Bs[k][n4+2]=bf2f(r.z); Bs[k][n4+3]=bf2f(r.w);
            }
        } else if (p.blay == 1) {
            const float* B = (const float*)p.Bp + (size_t)bz * p.sB;
            #pragma unroll
            for (int h = 0; h < 2; ++h) {
                const int g = tid + h * 256, n = g >> 3, k4 = (g & 7) * 4;
                const float4 r = *(const float4*)(B + (size_t)(n0 + n) * p.ldb + k0 + k4);
                Bs[k4][n] = r.x; Bs[k4+1][n] = r.y; Bs[k4+2][n] = r.z; Bs[k4+3][n] = r.w;
            }
        } else if (p.blay == 3) {
            const u16* B = (const u16*)p.Bp + (size_t)bz * p.sB;
            #pragma unroll
            for (int h = 0; h < 2; ++h) {
                const int g = tid + h * 256, n = g >> 3, k4 = (g & 7) * 4;
                const ushort4 r = *(const ushort4*)(B + (size_t)(n0 + n) * p.ldb + k0 + k4);
                Bs[k4][n]=bf2f(r.x); Bs[k4+1][n]=bf2f(r.y); Bs[k4+2][n]=bf2f(r.z); Bs[k4+3][n]=bf2f(r.w);
            }
        } else { // 5: mixed [Q | Alpha]
            if (n0 < 128) {
                const u16* B = (const u16*)p.Bp + (size_t)bz * p.sB;
                #pragma unroll
                for (int h = 0; h < 2; ++h) {
                    const int g = tid + h * 256, n = g >> 3, k4 = (g & 7) * 4;
                    const ushort4 r = *(const ushort4*)(B + (size_t)(n0 + n) * p.ldb + k0 + k4);
                    Bs[k4][n]=bf2f(r.x); Bs[k4+1][n]=bf2f(r.y); Bs[k4+2][n]=bf2f(r.z); Bs[k4+3][n]=bf2f(r.w);
                }
            } else {
                const float* B = (const float*)p.Baux + (size_t)bz * p.sBaux;
                #pragma unroll
                for (int h = 0; h < 2; ++h) {
                    const int g = tid + h * 256, k = g >> 4, n4 = (g & 15) * 4;
                    const float4 r = *(const float4*)(B + (size_t)(k0 + k) * 128 + (n0 - 128) + n4);
                    Bs[k][n4] = r.x; Bs[k][n4+1] = r.y; Bs[k][n4+2] = r.z; Bs[k][n4+3] = r.w;
                }
            }
        }
        __syncthreads();
        #pragma unroll
        for (int kk = 0; kk < 32; ++kk) {
            const float4 xa = *(const float4*)&As[kk][ty * 4];
            const float4 wb = *(const float4*)&Bs[kk][tx * 4];
            const float xv[4] = {xa.x, xa.y, xa.z, xa.w};
            const float wv[4] = {wb.x, wb.y, wb.z, wb.w};
            #pragma unroll
            for (int i = 0; i < 4; ++i)
                #pragma unroll
                for (int j = 0; j < 4; ++j)
                    acc[i][j] = fmaf(xv[i], wv[j], acc[i][j]);
        }
        __syncthreads();
    }
    const int mb = m0 + ty * 4, nb = n0 + tx * 4;
    if (p.epi == 0) {
        float* C = (float*)p.Cp + (size_t)bz * p.sC;
        #pragma unroll
        for (int i = 0; i < 4; ++i)
            #pragma unroll
            for (int j = 0; j < 4; ++j)
                C[(size_t)(mb + i) * p.ldc + nb + j] = acc[i][j];
    } else if (p.epi == 1) {
        float* C = p.Cio + (size_t)bz * p.sCio;
        const float gd = p.gdiag[bz];
        float v2 = 0.f;
        #pragma unroll
        for (int i = 0; i < 4; ++i)
            #pragma unroll
            for (int j = 0; j < 4; ++j) {
                const size_t idx = (size_t)(mb + i) * p.ldc + nb + j;
                float v = C[idx] - acc[i][j] + ((mb + i) == (nb + j) ? gd : 0.f);
                C[idx] = v;
                v2 = fmaf(v, v, v2);
            }
        v2 = wred64(v2);
        if ((tid & 63) == 0) atomicAdd(p.anacc + bz, v2);
    } else if (p.epi == 2) {
        float* C = p.Cio + (size_t)bz * p.sCio;
        #pragma unroll
        for (int i = 0; i < 4; ++i)
            #pragma unroll
            for (int j = 0; j < 4; ++j)
                C[(size_t)(mb + i) * p.ldc + nb + j] += acc[i][j];
    } else if (p.epi == 3) {
        u16* O = (u16*)p.Cp + (size_t)bz * p.sC;
        const float* OB = p.Cio + (size_t)bz * p.sCio;
        #pragma unroll
        for (int i = 0; i < 4; ++i)
            #pragma unroll
            for (int j = 0; j < 4; ++j)
                O[(size_t)(mb + i) * p.ldc + nb + j] =
                    f2bf(acc[i][j] + OB[(size_t)(nb + j) * 256 + mb + i]);
    } else if (p.epi == 4) {
        float* Zb  = (float*)p.Cp + (size_t)bz * 65536;
        float* Zsb = p.Zsp + (size_t)bz * 65536;
        float* Apb = p.Alphap + (size_t)bz * 65536;
        #pragma unroll
        for (int j = 0; j < 4; ++j) {
            const int n = nb + j;
            const float iv = p.invdp[bz * 128 + n];
            const float cav = p.cap[bz * 128 + n];
            const float cbv = p.cbp[bz * 128 + n];
            #pragma unroll
            for (int i = 0; i < 4; ++i) {
                const int m = mb + i;
                const float z = acc[i][j];
                const size_t o = (size_t)m * 128 + n;
                Zb[o] = z;
                Zsb[o] = z * iv;
                float a = z * cav;
                if (cbv != 0.f) a = fmaf(cbv, bf2f(p.Ulastp[(size_t)bz * 1048576 + m]), a);
                Apb[o] = a;
            }
        }
    } else { // 5
        float* C = (float*)p.Cp + (size_t)bz * p.sC;
        #pragma unroll
        for (int i = 0; i < 4; ++i)
            #pragma unroll
            for (int j = 0; j < 4; ++j)
                C[(size_t)(mb + i) * p.ldc + nb + j] = acc[i][j];
        if (nb >= 128) {
            const u16* Vn = p.Vnp + (size_t)bz * 1048576;
            #pragma unroll
            for (int j = 0; j < 4; ++j) {
                const int iidx = nb + j - 128;
                const ushort4 vr = *(const ushort4*)(Vn + (size_t)iidx * 512 + mb);
                const float part = bf2f(vr.x) * acc[0][j] + bf2f(vr.y) * acc[1][j]
                                 + bf2f(vr.z) * acc[2][j] + bf2f(vr.w) * acc[3][j];
                atomicAdd(p.dsump + bz * 128 + iidx, part);
            }
        }
    }
}

__global__ __launch_bounds__(256) void gemmx(GP p) { gemm_body(p, blockIdx.z); }

// ---------------- merged level-5: gram3 (P, Ga, Gv) + K6 (OBSA + diag atomics) ----------------
__global__ __launch_bounds__(256)
void lvl5_kernel(const float* Alpha, const u16* Qt, const u16* Vnt, const float* S,
                 float* P, float* Ga, float* Gv, float* OBSA, float* dsum)
{
    const int z = blockIdx.z;
    GP p{};
    if (z < 8) {
        p.alay = 0; p.Ap = S; p.lda = 512; p.sA = 262144;
        p.blay = 5; p.Bp = Qt; p.ldb = 512; p.sB = 1048576;
        p.Baux = Alpha; p.sBaux = 65536;
        p.epi = 5; p.Cp = OBSA; p.ldc = 256; p.sC = 131072; p.K = 512;
        p.Vnp = Vnt; p.dsump = dsum;
        gemm_body(p, z);
    } else {
        if (blockIdx.x >= 2 || blockIdx.y >= 2) return;
        const int zz = z - 8, b = zz / 3, j = zz - b * 3;
        p.K = 512; p.epi = 0; p.ldc = 128; p.sC = 16384;
        if (j == 0) {
            p.alay = 1; p.Ap = Alpha; p.lda = 128; p.sA = 65536;
            p.blay = 3; p.Bp = Qt; p.ldb = 512; p.sB = 1048576; p.Cp = P;
        } else if (j == 1) {
            p.alay = 1; p.Ap = Alpha; p.lda = 128; p.sA = 65536;
            p.blay = 0; p.Bp = Alpha; p.ldb = 128; p.sB = 65536; p.Cp = Ga;
        } else {
            p.alay = 2; p.Ap = Vnt; p.lda = 512; p.sA = 1048576;
            p.blay = 3; p.Bp = Vnt; p.ldb = 512; p.sB = 1048576; p.Cp = Gv;
        }
        gemm_body(p, b);
    }
}

// ---------------- merged level-7: K8 + K9 + K10 ----------------
__global__ __launch_bounds__(256)
void lvl7_kernel(const float* P, const u16* Vnt, u16* Obt, const float* OBSA,
                 const float* Alpha, const float* Zs, const float* Z,
                 float* S, float* A, const float* gdiag, float* AnAcc)
{
    const int z = blockIdx.z;
    GP p{};
    if (z < 8) {
        p.alay = 0; p.Ap = Zs; p.lda = 128; p.sA = 65536;
        p.blay = 1; p.Bp = Z; p.ldb = 128; p.sB = 65536;
        p.epi = 1; p.Cio = A; p.sCio = 262144; p.ldc = 512;
        p.gdiag = gdiag; p.anacc = AnAcc; p.K = 128;
        gemm_body(p, z);
    } else if (z < 16) {
        p.alay = 3; p.Ap = Vnt; p.lda = 512; p.sA = 1048576;
        p.blay = 1; p.Bp = Alpha; p.ldb = 128; p.sB = 65536;
        p.epi = 2; p.Cio = S; p.sCio = 262144; p.ldc = 512; p.K = 128;
        gemm_body(p, z - 8);
    } else {
        if (blockIdx.x >= 2) return;
        p.alay = 4; p.Ap = P; p.lda = 128; p.sA = 16384;
        p.blay = 2; p.Bp = Vnt; p.ldb = 512; p.sB = 1048576;
        p.epi = 3; p.Cp = Obt; p.ldc = 512; p.sC = 1048576;
        p.Cio = (float*)OBSA; p.sCio = 131072; p.K = 128;
        gemm_body(p, z - 16);
    }
}

// ---------------- elimination + triangular inverse ----------------
// Factor G (pivot d_t = max(1+E[t][t],1e-6)), then T = (I+C)^-1 in LDS:
// phase A: 16 diagonal 8x8 unit-upper inverses (parallel across waves)
// phase B: per-wave independent column-block descent via 8x8 lane matmuls.
// Writes T (for Z = W x T GEMM), invd/ca/cb, and zeroes dsum.
__global__ __launch_bounds__(256)
void elim_kernel(const float* __restrict__ G, float* __restrict__ Tg,
                 const float* __restrict__ sseq, float* __restrict__ invd,
                 float* __restrict__ ca, float* __restrict__ cb,
                 float* __restrict__ dsum_g, const int t0)
{
    const int b = blockIdx.x, tid = threadIdx.x, lane = tid & 63, wave = tid >> 6;
    __shared__ __align__(16) float E[128][128];
    __shared__ __align__(16) float Tm[128][128];
    __shared__ float del[128];
    __shared__ float Lp[128][8];
    __shared__ float Msc[4][8][8];
    const float4* Gb = (const float4*)(G + (size_t)b * 16384);
    float4* E4 = (float4*)E;
    for (int i = tid; i < 4096; i += 256) E4[i] = Gb[i];
    if (tid < 128) dsum_g[b * 128 + tid] = 0.f;
    __syncthreads();

    for (int p = 0; p < 16; ++p) {
        const int pc0 = p * 8;
        if (wave == 0) {
            float pr[2][8];
            #pragma unroll
            for (int j = 0; j < 8; ++j) {
                pr[0][j] = E[2 * lane][pc0 + j];
                pr[1][j] = E[2 * lane + 1][pc0 + j];
            }
            float dl[8];
            #pragma unroll
            for (int j = 0; j < 8; ++j) {
                const int t = pc0 + j;
                const float Ett = __shfl(pr[j & 1][j], t >> 1);
                const float d = fmaxf(1.f + Ett, 1e-6f);
                dl[j] = d;
                const float inv = 1.f / d;
                float prow[8];
                #pragma unroll
                for (int c = 0; c < 8; ++c) prow[c] = __shfl(pr[j & 1][c], t >> 1);
                #pragma unroll
                for (int rr = 0; rr < 2; ++rr) {
                    const int r = 2 * lane + rr;
                    if (r > t) {
                        const float coef = pr[rr][j] * inv;
                        #pragma unroll
                        for (int c = j + 1; c < 8; ++c)
                            pr[rr][c] = fmaf(-coef, prow[c], pr[rr][c]);
                    }
                }
            }
            #pragma unroll
            for (int rr = 0; rr < 2; ++rr) {
                const int r = 2 * lane + rr;
                #pragma unroll
                for (int j = 0; j < 8; ++j) {
                    Lp[r][j] = pr[rr][j] / dl[j];
                    E[r][pc0 + j] = pr[rr][j];
                }
            }
            if (lane < 8) del[pc0 + lane] = dl[lane];
            #pragma unroll
            for (int rr = 1; rr < 8; ++rr) {
                const int r = pc0 + rr;
                for (int c = pc0 + 8 + lane; c < 128; c += 64) {
                    float e = E[r][c];
                    #pragma unroll
                    for (int j = 0; j < 8; ++j)
                        if (j < rr) e = fmaf(-Lp[r][j], E[pc0 + j][c], e);
                    E[r][c] = e;
                }
            }
        }
        __syncthreads();
        const int r0b = pc0 + 8;
        const int nrows = 128 - r0b;
        if (nrows > 0) {
            const int c40 = r0b >> 2, nc4 = 32 - c40;
            for (int idx = tid; idx < nrows * nc4; idx += 256) {
                const int rr = idx / nc4, cc = idx - rr * nc4;
                const int r = r0b + rr, c4 = c40 + cc;
                float4 e = ((float4*)&E[r][0])[c4];
                #pragma unroll
                for (int j = 0; j < 8; ++j) {
                    const float lv = Lp[r][j];
                    const float4 pv = ((const float4*)&E[pc0 + j][0])[c4];
                    e.x = fmaf(-lv, pv.x, e.x);
                    e.y = fmaf(-lv, pv.y, e.y);
                    e.z = fmaf(-lv, pv.z, e.z);
                    e.w = fmaf(-lv, pv.w, e.w);
                }
                ((float4*)&E[r][0])[c4] = e;
            }
        }
        __syncthreads();
    }

    // scale E rows -> C (strictly upper, unit-diag implicit); init Tm = I
    for (int idx = tid; idx < 16384; idx += 256) {
        const int r = idx >> 7, c = idx & 127;
        if (c > r) E[r][c] = E[r][c] / del[r];
        Tm[r][c] = (r == c) ? 1.f : 0.f;
    }
    __syncthreads();
    // phase A: diagonal 8x8 unit-upper inverses
    #pragma unroll
    for (int k = 0; k < 4; ++k) {
        const int d = wave + 4 * k;
        if (lane < 8) {
            const int c = lane;
            for (int r = c - 1; r >= 0; --r) {
                float s = 0.f;
                for (int kk = r + 1; kk <= c; ++kk)
                    s = fmaf(E[8 * d + r][8 * d + kk], Tm[8 * d + kk][8 * d + c], s);
                Tm[8 * d + r][8 * d + c] = -s;
            }
        }
    }
    __syncthreads();
    // phase B: column-block descents (wave-independent)
    const int rr8 = lane >> 3, cc8 = lane & 7;
    for (int k = 0; k < 4; ++k) {
        const int j = wave + 4 * k;
        for (int i = j - 1; i >= 0; --i) {
            float m = 0.f;
            for (int l = i + 1; l <= j; ++l) {
                #pragma unroll
                for (int kk = 0; kk < 8; ++kk)
                    m = fmaf(E[8 * i + rr8][8 * l + kk], Tm[8 * l + kk][8 * j + cc8], m);
            }
            Msc[wave][rr8][cc8] = m;
            float s = 0.f;
            #pragma unroll
            for (int kk = 0; kk < 8; ++kk)
                s = fmaf(Tm[8 * i + rr8][8 * i + kk], Msc[wave][kk][cc8], s);
            Tm[8 * i + rr8][8 * j + cc8] = -s;
        }
    }
    __syncthreads();
    float4* Tgb = (float4*)(Tg + (size_t)b * 16384);
    const float4* Tm4 = (const float4*)Tm;
    for (int i = tid; i < 4096; i += 256) Tgb[i] = Tm4[i];
    if (tid < 128) {
        const float d = del[tid];
        const float s = sseq[(size_t)b * TT + t0 + tid];
        invd[b * 128 + tid] = 1.f / d;
        ca[b * 128 + tid] = s / d;
        cb[b * 128 + tid] = (tid == 127) ? s * 1e-6f : 0.f;
    }
}

// ---------------- guard: wave-parallel rsum/mdia + serial prefix ----------------
__global__ __launch_bounds__(256)
void guard_kernel(const float* __restrict__ dsum_g, const float* __restrict__ Ga,
                  const float* __restrict__ Gv, float* __restrict__ SnSq,
                  float* __restrict__ AnAcc, float* __restrict__ gdiag)
{
    const int b = blockIdx.x, tid = threadIdx.x;
    __shared__ float rpart[256], dsh[128], mdia[128];
    const int t = tid & 127, half = tid >> 7;
    const float* gv = Gv + (size_t)b * 16384 + t * 128;
    const float* ga = Ga + (size_t)b * 16384 + t * 128;
    float rs = 0.f;
    for (int j = half; j < t; j += 2) rs = fmaf(gv[j], ga[j], rs);
    rpart[tid] = rs;
    if (half == 0) { dsh[t] = dsum_g[b * 128 + t]; mdia[t] = gv[t] * ga[t]; }
    __syncthreads();
    if (tid == 0) {
        const float An2 = AnAcc[b];
        float Sn2 = SnSq[b], D = 0.f, T = 0.f;
        int ng = 0;
        for (int t2 = 0; t2 < 128; ++t2) {
            D += dsh[t2];
            T += mdia[t2] + 2.f * (rpart[t2] + rpart[t2 + 128]);
            const float sn2 = Sn2 + 2.f * D + T;
            if (sn2 > 1e6f || An2 > 1e6f) ++ng;
        }
        SnSq[b] = Sn2 + 2.f * D + T;
        gdiag[b] = 1e-6f + (float)ng * 1e-5f;
        AnAcc[b] = 0.f;
    }
}

extern "C" void kernel_launch(void* const* d_in, const int* in_sizes, int n_in,
                              void* d_out, int out_size, void* d_ws, size_t ws_size,
                              hipStream_t stream)
{
    const float* x  = (const float*)d_in[0];
    const float* Wq = (const float*)d_in[1];
    const float* bq = (const float*)d_in[2];
    const float* Wk = (const float*)d_in[3];
    const float* bk = (const float*)d_in[4];
    const float* Wv = (const float*)d_in[5];
    const float* bv = (const float*)d_in[6];
    const float* Wo = (const float*)d_in[7];
    const float* bo = (const float*)d_in[8];

    char* ws = (char*)d_ws;
    u16* Qb    = (u16*)(ws);
    u16* Ub    = (u16*)(ws + (16ull << 20));
    u16* Vnb   = (u16*)(ws + (32ull << 20));
    u16* Ob    = (u16*)(ws + (48ull << 20));   // also x_bf before chunk loop
    u16* x_bf  = Ob;
    float* A    = (float*)(ws + (64ull << 20));
    float* S    = (float*)(ws + (72ull << 20));
    float* Wm   = (float*)(ws + (80ull << 20));
    float* Z    = (float*)(ws + (82ull << 20));
    float* Zs   = (float*)(ws + (84ull << 20));
    float* Alpha= (float*)(ws + (86ull << 20));
    float* OBSA = (float*)(ws + (88ull << 20));
    float* G    = (float*)(ws + (92ull << 20));
    float* Tg   = (float*)(ws + (92ull << 20) + (512ull << 10));
    float* P    = (float*)(ws + (93ull << 20));
    float* Ga   = (float*)(ws + (93ull << 20) + (512ull << 10));
    float* Gv   = (float*)(ws + (94ull << 20));
    float* invd = (float*)(ws + (94ull << 20) + (512ull << 10));
    float* ca   = (float*)(ws + (94ull << 20) + (516ull << 10));
    float* cb   = (float*)(ws + (94ull << 20) + (520ull << 10));
    float* sseq = (float*)(ws + (94ull << 20) + (528ull << 10));
    float* SnSq = (float*)(ws + (94ull << 20) + (600ull << 10));
    float* AnAcc= (float*)(ws + (94ull << 20) + (600ull << 10) + 64);
    float* gdiag= (float*)(ws + (94ull << 20) + (600ull << 10) + 128);
    float* dsum = (float*)(ws + (94ull << 20) + (604ull << 10));
    u16* Wq_bf = (u16*)(ws + (95ull << 20));
    u16* Wk_bf = (u16*)(ws + (95ull << 20) + (512ull << 10));
    u16* Wv_bf = (u16*)(ws + (96ull << 20));
    u16* Wo_bf = (u16*)(ws + (96ull << 20) + (512ull << 10));

    // bf16 conversions
    f2bf_kernel<<<2048, 256, 0, stream>>>((const float4*)x, (ushort4*)x_bf, 2097152);
    f2bf_kernel<<<256, 256, 0, stream>>>((const float4*)Wq, (ushort4*)Wq_bf, 65536);
    f2bf_kernel<<<256, 256, 0, stream>>>((const float4*)Wk, (ushort4*)Wk_bf, 65536);
    f2bf_kernel<<<256, 256, 0, stream>>>((const float4*)Wv, (ushort4*)Wv_bf, 65536);
    f2bf_kernel<<<256, 256, 0, stream>>>((const float4*)Wo, (ushort4*)Wo_bf, 65536);

    // projections via MFMA
    mfma_gemm<1><<<dim3(128, 4), 256, 0, stream>>>(x_bf, Wq_bf, bq, Qb, 1.f);
    mfma_gemm<1><<<dim3(128, 4), 256, 0, stream>>>(x_bf, Wk_bf, bk, Ub, 0.04419417382415922f);
    mfma_gemm<1><<<dim3(128, 4), 256, 0, stream>>>(x_bf, Wv_bf, bv, Vnb, 1.f);
    prep_kernel<<<4096, 256, 0, stream>>>(Qb, Ub, Vnb, sseq);
    init_kernel<<<2048, 256, 0, stream>>>((float4*)A, (float4*)S, SnSq, AnAcc);

    for (int c = 0; c < NC; ++c) {
        const int t0 = c * LL;
        const u16* Ut = Ub + (size_t)t0 * 512;
        const u16* Qt = Qb + (size_t)t0 * 512;
        const u16* Vt = Vnb + (size_t)t0 * 512;
        // K1: W = A x U_cols
        GP p1{}; p1.alay = 0; p1.Ap = A; p1.lda = 512; p1.sA = 262144;
        p1.blay = 3; p1.Bp = Ut; p1.ldb = 512; p1.sB = 1048576;
        p1.epi = 0; p1.Cp = Wm; p1.ldc = 128; p1.sC = 65536; p1.K = 512;
        gemmx<<<dim3(8, 2, 8), 256, 0, stream>>>(p1);
        // K2: G = U^T W
        GP p2{}; p2.alay = 2; p2.Ap = Ut; p2.lda = 512; p2.sA = 1048576;
        p2.blay = 0; p2.Bp = Wm; p2.ldb = 128; p2.sB = 65536;
        p2.epi = 0; p2.Cp = G; p2.ldc = 128; p2.sC = 16384; p2.K = 512;
        gemmx<<<dim3(2, 2, 8), 256, 0, stream>>>(p2);
        elim_kernel<<<8, 256, 0, stream>>>(G, Tg, sseq, invd, ca, cb, dsum, t0);
        // Z/Zs/Alpha = W x T with scale epilogue (replaces fsub)
        GP p4{}; p4.alay = 0; p4.Ap = Wm; p4.lda = 128; p4.sA = 65536;
        p4.blay = 0; p4.Bp = Tg; p4.ldb = 128; p4.sB = 16384;
        p4.epi = 4; p4.Cp = Z; p4.Zsp = Zs; p4.Alphap = Alpha;
        p4.invdp = invd; p4.cap = ca; p4.cbp = cb;
        p4.Ulastp = Ub + (size_t)(t0 + 127) * 512;
        p4.K = 128; p4.ldc = 128; p4.sC = 65536;
        gemmx<<<dim3(8, 2, 8), 256, 0, stream>>>(p4);
        lvl5_kernel<<<dim3(8, 4, 32), 256, 0, stream>>>(Alpha, Qt, Vt, S, P, Ga, Gv, OBSA, dsum);
        guard_kernel<<<8, 256, 0, stream>>>(dsum, Ga, Gv, SnSq, AnAcc, gdiag);
        lvl7_kernel<<<dim3(8, 8, 24), 256, 0, stream>>>(P, Vt, Ob + (size_t)t0 * 512, OBSA,
            Alpha, Zs, Z, S, A, gdiag, AnAcc);
    }
    // output projection via MFMA (f32 out)
    mfma_gemm<0><<<dim3(128, 4), 256, 0, stream>>>(Ob, Wo_bf, bo, d_out, 1.f);
}

// Round 7
// 4512.887 us; speedup vs baseline: 7.9251x; 1.0608x over previous
//
#include <hip/hip_runtime.h>
#include <hip/hip_bf16.h>

#define BB 8
#define TT 2048
#define DD 512
#define LL 128
#define NC 16
#define ETH 512

typedef unsigned short u16;
typedef unsigned int u32;
typedef __attribute__((ext_vector_type(8))) short bf16x8v;
typedef __attribute__((ext_vector_type(4))) float f32x4v;

__device__ __forceinline__ float bf2f(u32 h) { return __uint_as_float(h << 16); }
__device__ __forceinline__ u16 f2bf(float f) {
    u32 u = __float_as_uint(f);
    u += 0x7fffu + ((u >> 16) & 1u);
    return (u16)(u >> 16);
}
__device__ __forceinline__ float wred64(float v) {
    #pragma unroll
    for (int off = 32; off; off >>= 1) v += __shfl_xor(v, off);
    return v;
}
__device__ __forceinline__ void unpack8(uint4 r, float* f) {
    f[0] = bf2f(r.x & 0xffff); f[1] = bf2f(r.x >> 16);
    f[2] = bf2f(r.y & 0xffff); f[3] = bf2f(r.y >> 16);
    f[4] = bf2f(r.z & 0xffff); f[5] = bf2f(r.z >> 16);
    f[6] = bf2f(r.w & 0xffff); f[7] = bf2f(r.w >> 16);
}

// ---------------- f32 -> bf16 convert ----------------
__global__ __launch_bounds__(256)
void f2bf_kernel(const float4* __restrict__ in, ushort4* __restrict__ out, const int n4)
{
    int i = blockIdx.x * 256 + threadIdx.x;
    const int stride = gridDim.x * 256;
    for (; i < n4; i += stride) {
        const float4 v = in[i];
        ushort4 o;
        o.x = f2bf(v.x); o.y = f2bf(v.y); o.z = f2bf(v.z); o.w = f2bf(v.w);
        out[i] = o;
    }
}

__global__ __launch_bounds__(256)
void wconv_kernel(const float4* __restrict__ Wq, const float4* __restrict__ Wk,
                  const float4* __restrict__ Wv, const float4* __restrict__ Wo,
                  ushort4* __restrict__ oq, ushort4* __restrict__ ok,
                  ushort4* __restrict__ ov, ushort4* __restrict__ oo)
{
    const int i = blockIdx.x * 256 + threadIdx.x;
    const int y = blockIdx.y;
    const float4* src = (y == 0) ? Wq : (y == 1) ? Wk : (y == 2) ? Wv : Wo;
    ushort4* dst = (y == 0) ? oq : (y == 1) ? ok : (y == 2) ? ov : oo;
    const float4 v = src[i];
    ushort4 o;
    o.x = f2bf(v.x); o.y = f2bf(v.y); o.z = f2bf(v.z); o.w = f2bf(v.w);
    dst[i] = o;
}

// ---------------- MFMA bf16 GEMM (round-5 proven) ----------------
template<int OUT_BF>
__global__ __launch_bounds__(256)
void mfma_gemm(const u16* __restrict__ Abf, const u16* __restrict__ Bbf,
               const float* __restrict__ bias, void* __restrict__ Cout,
               const float outscale)
{
    __shared__ u16 Asm[128 * 64];
    __shared__ u16 Bsm[128 * 64];
    const int tid = threadIdx.x;
    const int wave = tid >> 6, lane = tid & 63;
    const int wm = wave >> 1, wn = wave & 1;
    const int m0 = blockIdx.x * 128, n0 = blockIdx.y * 128;

    f32x4v acc[4][4];
    #pragma unroll
    for (int i = 0; i < 4; ++i)
        #pragma unroll
        for (int j = 0; j < 4; ++j)
            acc[i][j] = (f32x4v){0.f, 0.f, 0.f, 0.f};

    const u16* gsrcA[4];
    const u16* gsrcB[4];
    #pragma unroll
    for (int i = 0; i < 4; ++i) {
        const int idx = i * 256 + tid;
        const int row = idx >> 3, c = idx & 7;
        const int kb = c ^ (row & 7);
        gsrcA[i] = Abf + (size_t)(m0 + row) * 512 + kb * 8;
        gsrcB[i] = Bbf + (size_t)(n0 + row) * 512 + kb * 8;
    }

    for (int k0 = 0; k0 < 512; k0 += 64) {
        __syncthreads();
        #pragma unroll
        for (int i = 0; i < 4; ++i) {
            __builtin_amdgcn_global_load_lds(
                (__attribute__((address_space(1))) void*)(gsrcA[i] + k0),
                (__attribute__((address_space(3))) void*)(Asm + (size_t)(i * 256 + wave * 64) * 8),
                16, 0, 0);
            __builtin_amdgcn_global_load_lds(
                (__attribute__((address_space(1))) void*)(gsrcB[i] + k0),
                (__attribute__((address_space(3))) void*)(Bsm + (size_t)(i * 256 + wave * 64) * 8),
                16, 0, 0);
        }
        asm volatile("s_waitcnt vmcnt(0)" ::: "memory");
        __syncthreads();

        const int l15 = lane & 15, lhi = lane >> 4;
        bf16x8v af[4][2], bfr[4][2];
        #pragma unroll
        for (int mf = 0; mf < 4; ++mf) {
            const int row = wm * 64 + mf * 16 + l15;
            const int sw = (row & 7) << 4;
            #pragma unroll
            for (int ks = 0; ks < 2; ++ks) {
                const int kbyte = ks * 64 + lhi * 16;
                af[mf][ks] = *(const bf16x8v*)((const char*)Asm + row * 128 + (kbyte ^ sw));
            }
        }
        #pragma unroll
        for (int nf = 0; nf < 4; ++nf) {
            const int row = wn * 64 + nf * 16 + l15;
            const int sw = (row & 7) << 4;
            #pragma unroll
            for (int ks = 0; ks < 2; ++ks) {
                const int kbyte = ks * 64 + lhi * 16;
                bfr[nf][ks] = *(const bf16x8v*)((const char*)Bsm + row * 128 + (kbyte ^ sw));
            }
        }
        #pragma unroll
        for (int ks = 0; ks < 2; ++ks)
            #pragma unroll
            for (int mf = 0; mf < 4; ++mf)
                #pragma unroll
                for (int nf = 0; nf < 4; ++nf)
                    acc[mf][nf] = __builtin_amdgcn_mfma_f32_16x16x32_bf16(
                        af[mf][ks], bfr[nf][ks], acc[mf][nf], 0, 0, 0);
    }
    const int l15 = lane & 15, lhi = lane >> 4;
    #pragma unroll
    for (int mf = 0; mf < 4; ++mf) {
        #pragma unroll
        for (int nf = 0; nf < 4; ++nf) {
            const int n = n0 + wn * 64 + nf * 16 + l15;
            const float bsv = bias[n];
            #pragma unroll
            for (int r = 0; r < 4; ++r) {
                const int m = m0 + wm * 64 + mf * 16 + lhi * 4 + r;
                const float val = (acc[mf][nf][r] + bsv) * outscale;
                if (OUT_BF) ((u16*)Cout)[(size_t)m * 512 + n] = f2bf(val);
                else        ((float*)Cout)[(size_t)m * 512 + n] = val;
            }
        }
    }
}

// ---------------- prep: s_seq, Vn normalize ----------------
__global__ __launch_bounds__(256)
void prep_kernel(const u16* __restrict__ Qb, const u16* __restrict__ Ub,
                 u16* __restrict__ Vb, float* __restrict__ sseq)
{
    const int lane = threadIdx.x & 63, wid = threadIdx.x >> 6;
    const int row = blockIdx.x * 4 + wid;
    const size_t base = (size_t)row * DD;
    const uint4 qr = *(const uint4*)(Qb + base + lane * 8);
    const uint4 ur = *(const uint4*)(Ub + base + lane * 8);
    const uint4 vr = *(const uint4*)(Vb + base + lane * 8);
    float q[8], u[8], v[8];
    unpack8(qr, q); unpack8(ur, u); unpack8(vr, v);
    float sd = 0.f, nv = 0.f;
    #pragma unroll
    for (int e = 0; e < 8; ++e) { sd = fmaf(q[e], u[e], sd); nv = fmaf(v[e], v[e], nv); }
    #pragma unroll
    for (int off = 32; off; off >>= 1) { sd += __shfl_xor(sd, off); nv += __shfl_xor(nv, off); }
    if (lane == 0) sseq[row] = sd * 22.627416997969522f;
    const float inv = 1.f / (sqrtf(nv) + 1e-6f);
    uint4 o;
    o.x = (u32)f2bf(v[0] * inv) | ((u32)f2bf(v[1] * inv) << 16);
    o.y = (u32)f2bf(v[2] * inv) | ((u32)f2bf(v[3] * inv) << 16);
    o.z = (u32)f2bf(v[4] * inv) | ((u32)f2bf(v[5] * inv) << 16);
    o.w = (u32)f2bf(v[6] * inv) | ((u32)f2bf(v[7] * inv) << 16);
    *(uint4*)(Vb + base + lane * 8) = o;
}

__global__ __launch_bounds__(256)
void init_kernel(float4* __restrict__ A4, float4* __restrict__ S4,
                 float* __restrict__ SnSq, float* __restrict__ AnAcc)
{
    const int gtid = blockIdx.x * 256 + threadIdx.x;
    const int N4 = BB * DD * DD / 4;
    for (int idx = gtid; idx < N4; idx += gridDim.x * 256) {
        const int e0 = idx << 2;
        const int r = (e0 >> 9) & 511;
        const int c = e0 & 511;
        float4 v;
        v.x = (c + 0 == r) ? 1.f : 0.f;
        v.y = (c + 1 == r) ? 1.f : 0.f;
        v.z = (c + 2 == r) ? 1.f : 0.f;
        v.w = (c + 3 == r) ? 1.f : 0.f;
        A4[idx] = v;
        S4[idx] = make_float4(0.f, 0.f, 0.f, 0.f);
    }
    if (gtid < BB) { SnSq[gtid] = 0.f; AnAcc[gtid] = 512.f; }
}

// ---------------- generic chunk GEMM ----------------
struct GP {
    int alay, blay, epi;
    const void* Ap; const void* Bp; const void* Baux;
    void* Cp; float* Cio;
    const float* gdiag; float* anacc;
    const float* invdp; const float* cap; const float* cbp;
    const u16* Ulastp; float* Zsp; float* Alphap;
    const u16* Vnp; float* dsump;
    int lda, ldb, ldc, K;
    long sA, sB, sBaux, sC, sCio;
};

__device__ __forceinline__ void gemm_body(const GP& p, const int bz) {
    __shared__ __align__(16) float As[32][68];
    __shared__ __align__(16) float Bs[32][68];
    const int m0 = blockIdx.x * 64, n0 = blockIdx.y * 64;
    const int tid = threadIdx.x, tx = tid & 15, ty = tid >> 4;
    float acc[4][4] = {};
    for (int k0 = 0; k0 < p.K; k0 += 32) {
        if (p.alay == 0) {
            const float* A = (const float*)p.Ap + (size_t)bz * p.sA;
            #pragma unroll
            for (int h = 0; h < 2; ++h) {
                const int g = tid + h * 256, m = g >> 3, k4 = (g & 7) * 4;
                const float4 r = *(const float4*)(A + (size_t)(m0 + m) * p.lda + k0 + k4);
                As[k4][m] = r.x; As[k4+1][m] = r.y; As[k4+2][m] = r.z; As[k4+3][m] = r.w;
            }
        } else if (p.alay == 2) {
            const u16* A = (const u16*)p.Ap + (size_t)bz * p.sA;
            #pragma unroll
            for (int h = 0; h < 2; ++h) {
                const int g = tid + h * 256, m = g >> 3, k4 = (g & 7) * 4;
                const ushort4 r = *(const ushort4*)(A + (size_t)(m0 + m) * p.lda + k0 + k4);
                As[k4][m]=bf2f(r.x); As[k4+1][m]=bf2f(r.y); As[k4+2][m]=bf2f(r.z); As[k4+3][m]=bf2f(r.w);
            }
        } else if (p.alay == 1 || p.alay == 4) {
            const float* A = (const float*)p.Ap + (size_t)bz * p.sA;
            #pragma unroll
            for (int h = 0; h < 2; ++h) {
                const int g = tid + h * 256, k = g >> 4, m4 = (g & 15) * 4;
                float4 r = *(const float4*)(A + (size_t)(k0 + k) * p.lda + m0 + m4);
                if (p.alay == 4) {
                    const int kg = k0 + k, mg = m0 + m4;
                    if (kg > mg + 0) r.x = 0.f;
                    if (kg > mg + 1) r.y = 0.f;
                    if (kg > mg + 2) r.z = 0.f;
                    if (kg > mg + 3) r.w = 0.f;
                }
                As[k][m4] = r.x; As[k][m4+1] = r.y; As[k][m4+2] = r.z; As[k][m4+3] = r.w;
            }
        } else { // 3
            const u16* A = (const u16*)p.Ap + (size_t)bz * p.sA;
            #pragma unroll
            for (int h = 0; h < 2; ++h) {
                const int g = tid + h * 256, k = g >> 4, m4 = (g & 15) * 4;
                const ushort4 r = *(const ushort4*)(A + (size_t)(k0 + k) * p.lda + m0 + m4);
                As[k][m4]=bf2f(r.x); As[k][m4+1]=bf2f(r.y); As[k][m4+2]=bf2f(r.z); As[k][m4+3]=bf2f(r.w);
            }
        }
        if (p.blay == 0) {
            const float* B = (const float*)p.Bp + (size_t)bz * p.sB;
            #pragma unroll
            for (int h = 0; h < 2; ++h) {
                const int g = tid + h * 256, k = g >> 4, n4 = (g & 15) * 4;
                const float4 r = *(const float4*)(B + (size_t)(k0 + k) * p.ldb + n0 + n4);
                Bs[k][n4] = r.x; Bs[k][n4+1] = r.y; Bs[k][n4+2] = r.z; Bs[k][n4+3] = r.w;
            }
        } else if (p.blay == 2) {
            const u16* B = (const u16*)p.Bp + (size_t)bz * p.sB;
            #pragma unroll
            for (int h = 0; h < 2; ++h) {
                const int g = tid + h * 256, k = g >> 4, n4 = (g & 15) * 4;
                const ushort4 r = *(const ushort4*)(B + (size_t)(k0 + k) * p.ldb + n0 + n4);
                Bs[k][n4]=bf2f(r.x); Bs[k][n4+1]=bf2f(r.y); Bs[k][n4+2]=bf2f(r.z); Bs[k][n4+3]=bf2f(r.w);
            }
        } else if (p.blay == 1) {
            const float* B = (const float*)p.Bp + (size_t)bz * p.sB;
            #pragma unroll
            for (int h = 0; h < 2; ++h) {
                const int g = tid + h * 256, n = g >> 3, k4 = (g & 7) * 4;
                const float4 r = *(const float4*)(B + (size_t)(n0 + n) * p.ldb + k0 + k4);
                Bs[k4][n] = r.x; Bs[k4+1][n] = r.y; Bs[k4+2][n] = r.z; Bs[k4+3][n] = r.w;
            }
        } else if (p.blay == 3) {
            const u16* B = (const u16*)p.Bp + (size_t)bz * p.sB;
            #pragma unroll
            for (int h = 0; h < 2; ++h) {
                const int g = tid + h * 256, n = g >> 3, k4 = (g & 7) * 4;
                const ushort4 r = *(const ushort4*)(B + (size_t)(n0 + n) * p.ldb + k0 + k4);
                Bs[k4][n]=bf2f(r.x); Bs[k4+1][n]=bf2f(r.y); Bs[k4+2][n]=bf2f(r.z); Bs[k4+3][n]=bf2f(r.w);
            }
        } else { // 5: mixed [Q | Alpha]
            if (n0 < 128) {
                const u16* B = (const u16*)p.Bp + (size_t)bz * p.sB;
                #pragma unroll
                for (int h = 0; h < 2; ++h) {
                    const int g = tid + h * 256, n = g >> 3, k4 = (g & 7) * 4;
                    const ushort4 r = *(const ushort4*)(B + (size_t)(n0 + n) * p.ldb + k0 + k4);
                    Bs[k4][n]=bf2f(r.x); Bs[k4+1][n]=bf2f(r.y); Bs[k4+2][n]=bf2f(r.z); Bs[k4+3][n]=bf2f(r.w);
                }
            } else {
                const float* B = (const float*)p.Baux + (size_t)bz * p.sBaux;
                #pragma unroll
                for (int h = 0; h < 2; ++h) {
                    const int g = tid + h * 256, k = g >> 4, n4 = (g & 15) * 4;
                    const float4 r = *(const float4*)(B + (size_t)(k0 + k) * 128 + (n0 - 128) + n4);
                    Bs[k][n4] = r.x; Bs[k][n4+1] = r.y; Bs[k][n4+2] = r.z; Bs[k][n4+3] = r.w;
                }
            }
        }
        __syncthreads();
        #pragma unroll
        for (int kk = 0; kk < 32; ++kk) {
            const float4 xa = *(const float4*)&As[kk][ty * 4];
            const float4 wb = *(const float4*)&Bs[kk][tx * 4];
            const float xv[4] = {xa.x, xa.y, xa.z, xa.w};
            const float wv[4] = {wb.x, wb.y, wb.z, wb.w};
            #pragma unroll
            for (int i = 0; i < 4; ++i)
                #pragma unroll
                for (int j = 0; j < 4; ++j)
                    acc[i][j] = fmaf(xv[i], wv[j], acc[i][j]);
        }
        __syncthreads();
    }
    const int mb = m0 + ty * 4, nb = n0 + tx * 4;
    if (p.epi == 0) {
        float* C = (float*)p.Cp + (size_t)bz * p.sC;
        #pragma unroll
        for (int i = 0; i < 4; ++i)
            #pragma unroll
            for (int j = 0; j < 4; ++j)
                C[(size_t)(mb + i) * p.ldc + nb + j] = acc[i][j];
    } else if (p.epi == 1) {
        float* C = p.Cio + (size_t)bz * p.sCio;
        const float gd = p.gdiag[bz];
        float v2 = 0.f;
        #pragma unroll
        for (int i = 0; i < 4; ++i)
            #pragma unroll
            for (int j = 0; j < 4; ++j) {
                const size_t idx = (size_t)(mb + i) * p.ldc + nb + j;
                float v = C[idx] - acc[i][j] + ((mb + i) == (nb + j) ? gd : 0.f);
                C[idx] = v;
                v2 = fmaf(v, v, v2);
            }
        v2 = wred64(v2);
        if ((tid & 63) == 0) atomicAdd(p.anacc + bz, v2);
    } else if (p.epi == 2) {
        float* C = p.Cio + (size_t)bz * p.sCio;
        #pragma unroll
        for (int i = 0; i < 4; ++i)
            #pragma unroll
            for (int j = 0; j < 4; ++j)
                C[(size_t)(mb + i) * p.ldc + nb + j] += acc[i][j];
    } else if (p.epi == 3) {
        u16* O = (u16*)p.Cp + (size_t)bz * p.sC;
        const float* OB = p.Cio + (size_t)bz * p.sCio;
        #pragma unroll
        for (int i = 0; i < 4; ++i)
            #pragma unroll
            for (int j = 0; j < 4; ++j)
                O[(size_t)(mb + i) * p.ldc + nb + j] =
                    f2bf(acc[i][j] + OB[(size_t)(nb + j) * 256 + mb + i]);
    } else if (p.epi == 4) {
        float* Zb  = (float*)p.Cp + (size_t)bz * 65536;
        float* Zsb = p.Zsp + (size_t)bz * 65536;
        float* Apb = p.Alphap + (size_t)bz * 65536;
        #pragma unroll
        for (int j = 0; j < 4; ++j) {
            const int n = nb + j;
            const float iv = p.invdp[bz * 128 + n];
            const float cav = p.cap[bz * 128 + n];
            const float cbv = p.cbp[bz * 128 + n];
            #pragma unroll
            for (int i = 0; i < 4; ++i) {
                const int m = mb + i;
                const float z = acc[i][j];
                const size_t o = (size_t)m * 128 + n;
                Zb[o] = z;
                Zsb[o] = z * iv;
                float a = z * cav;
                if (cbv != 0.f) a = fmaf(cbv, bf2f(p.Ulastp[(size_t)bz * 1048576 + m]), a);
                Apb[o] = a;
            }
        }
    } else { // 5
        float* C = (float*)p.Cp + (size_t)bz * p.sC;
        #pragma unroll
        for (int i = 0; i < 4; ++i)
            #pragma unroll
            for (int j = 0; j < 4; ++j)
                C[(size_t)(mb + i) * p.ldc + nb + j] = acc[i][j];
        if (nb >= 128) {
            const u16* Vn = p.Vnp + (size_t)bz * 1048576;
            #pragma unroll
            for (int j = 0; j < 4; ++j) {
                const int iidx = nb + j - 128;
                const ushort4 vr = *(const ushort4*)(Vn + (size_t)iidx * 512 + mb);
                const float part = bf2f(vr.x) * acc[0][j] + bf2f(vr.y) * acc[1][j]
                                 + bf2f(vr.z) * acc[2][j] + bf2f(vr.w) * acc[3][j];
                atomicAdd(p.dsump + bz * 128 + iidx, part);
            }
        }
    }
}

__global__ __launch_bounds__(256) void gemmx(GP p) { gemm_body(p, blockIdx.z); }

// ---------------- merged level-5 ----------------
__global__ __launch_bounds__(256)
void lvl5_kernel(const float* Alpha, const u16* Qt, const u16* Vnt, const float* S,
                 float* P, float* Ga, float* Gv, float* OBSA, float* dsum)
{
    const int z = blockIdx.z;
    GP p{};
    if (z < 8) {
        p.alay = 0; p.Ap = S; p.lda = 512; p.sA = 262144;
        p.blay = 5; p.Bp = Qt; p.ldb = 512; p.sB = 1048576;
        p.Baux = Alpha; p.sBaux = 65536;
        p.epi = 5; p.Cp = OBSA; p.ldc = 256; p.sC = 131072; p.K = 512;
        p.Vnp = Vnt; p.dsump = dsum;
        gemm_body(p, z);
    } else {
        if (blockIdx.x >= 2 || blockIdx.y >= 2) return;
        const int zz = z - 8, b = zz / 3, j = zz - b * 3;
        p.K = 512; p.epi = 0; p.ldc = 128; p.sC = 16384;
        if (j == 0) {
            p.alay = 1; p.Ap = Alpha; p.lda = 128; p.sA = 65536;
            p.blay = 3; p.Bp = Qt; p.ldb = 512; p.sB = 1048576; p.Cp = P;
        } else if (j == 1) {
            p.alay = 1; p.Ap = Alpha; p.lda = 128; p.sA = 65536;
            p.blay = 0; p.Bp = Alpha; p.ldb = 128; p.sB = 65536; p.Cp = Ga;
        } else {
            p.alay = 2; p.Ap = Vnt; p.lda = 512; p.sA = 1048576;
            p.blay = 3; p.Bp = Vnt; p.ldb = 512; p.sB = 1048576; p.Cp = Gv;
        }
        gemm_body(p, b);
    }
}

// ---------------- merged level-7 ----------------
__global__ __launch_bounds__(256)
void lvl7_kernel(const float* P, const u16* Vnt, u16* Obt, const float* OBSA,
                 const float* Alpha, const float* Zs, const float* Z,
                 float* S, float* A, const float* gdiag, float* AnAcc)
{
    const int z = blockIdx.z;
    GP p{};
    if (z < 8) {
        p.alay = 0; p.Ap = Zs; p.lda = 128; p.sA = 65536;
        p.blay = 1; p.Bp = Z; p.ldb = 128; p.sB = 65536;
        p.epi = 1; p.Cio = A; p.sCio = 262144; p.ldc = 512;
        p.gdiag = gdiag; p.anacc = AnAcc; p.K = 128;
        gemm_body(p, z);
    } else if (z < 16) {
        p.alay = 3; p.Ap = Vnt; p.lda = 512; p.sA = 1048576;
        p.blay = 1; p.Bp = Alpha; p.ldb = 128; p.sB = 65536;
        p.epi = 2; p.Cio = S; p.sCio = 262144; p.ldc = 512; p.K = 128;
        gemm_body(p, z - 8);
    } else {
        if (blockIdx.x >= 2) return;
        p.alay = 4; p.Ap = P; p.lda = 128; p.sA = 16384;
        p.blay = 2; p.Bp = Vnt; p.ldb = 512; p.sB = 1048576;
        p.epi = 3; p.Cp = Obt; p.ldc = 512; p.sC = 1048576;
        p.Cio = (float*)OBSA; p.sCio = 131072; p.K = 128;
        gemm_body(p, z - 16);
    }
}

// ---------------- elimination + triangular inverse (bank-conflict-free, 512 thr) ----------------
// LDLt-style factorization of I+G (pivot d_t = max(1+E_tt,1e-6)) with padded LDS rows
// (132 floats -> bank offset 4/row), transposed panel staging (conflict-free wave-0
// factor), transposed multipliers LpT, then T = (I+C)^-1 via 8x8-block phase A
// (diag inverses) + snake-balanced per-wave column descents (phase B).
__global__ __launch_bounds__(512)
void elim_kernel(const float* __restrict__ G, float* __restrict__ Tg,
                 const float* __restrict__ sseq, float* __restrict__ invd,
                 float* __restrict__ ca, float* __restrict__ cb,
                 float* __restrict__ dsum_g, const int t0)
{
    const int b = blockIdx.x, tid = threadIdx.x, lane = tid & 63, wave = tid >> 6;
    __shared__ float E[128][132];
    __shared__ float Tm[128][132];
    __shared__ float Pst[8][132];
    __shared__ float LpT[8][132];
    __shared__ float Msc[8][8][9];
    __shared__ float del[128];

    const float* Gb = G + (size_t)b * 16384;
    for (int idx = tid; idx < 16384; idx += ETH)
        E[idx >> 7][idx & 127] = Gb[idx];
    if (tid < 128) dsum_g[b * 128 + tid] = 0.f;
    __syncthreads();

    for (int p = 0; p < 16; ++p) {
        const int pc0 = p * 8;
        // stage panel transposed (j fastest -> near-conflict-free)
        for (int idx = tid; idx < 1024; idx += ETH) {
            const int j = idx & 7, r = idx >> 3;
            Pst[j][r] = E[r][pc0 + j];
        }
        __syncthreads();
        if (wave == 0) {
            // lane owns global rows {lane, lane+64}; conflict-free Pst access
            float pr[2][8];
            #pragma unroll
            for (int j = 0; j < 8; ++j) {
                pr[0][j] = Pst[j][lane];
                pr[1][j] = Pst[j][64 + lane];
            }
            float dl[8];
            #pragma unroll
            for (int j = 0; j < 8; ++j) {
                const int t = pc0 + j;
                const int ph = t >> 6, pl = t & 63;
                const float Ett = __shfl(pr[ph][j], pl);
                const float d = fmaxf(1.f + Ett, 1e-6f);
                dl[j] = d;
                const float inv = 1.f / d;
                float prow[8];
                #pragma unroll
                for (int c = 0; c < 8; ++c) prow[c] = __shfl(pr[ph][c], pl);
                #pragma unroll
                for (int h = 0; h < 2; ++h) {
                    const int r = lane + 64 * h;
                    if (r > t) {
                        const float coef = pr[h][j] * inv;
                        #pragma unroll
                        for (int c = j + 1; c < 8; ++c)
                            pr[h][c] = fmaf(-coef, prow[c], pr[h][c]);
                    }
                }
            }
            #pragma unroll
            for (int h = 0; h < 2; ++h) {
                const int r = lane + 64 * h;
                #pragma unroll
                for (int j = 0; j < 8; ++j) {
                    LpT[j][r] = pr[h][j] / dl[j];
                    Pst[j][r] = pr[h][j];
                }
            }
            if (lane < 8) del[pc0 + lane] = dl[lane];
            // finalize pivot-row trailing cols (rows pc0+1..pc0+7), sequential in rr
            #pragma unroll
            for (int rr = 1; rr < 8; ++rr) {
                const int r = pc0 + rr;
                for (int c = pc0 + 8 + lane; c < 128; c += 64) {
                    float e = E[r][c];
                    #pragma unroll
                    for (int j = 0; j < 8; ++j)
                        if (j < rr) e = fmaf(-LpT[j][r], E[pc0 + j][c], e);
                    E[r][c] = e;
                }
            }
        }
        __syncthreads();
        // panel col writeback (cols pc0..pc0+7; disjoint from trailing cols)
        for (int idx = tid; idx < 1024; idx += ETH) {
            const int j = idx & 7, r = idx >> 3;
            E[r][pc0 + j] = Pst[j][r];
        }
        // rank-8 trailing update: rows >= pc0+8, cols >= pc0+8
        const int r0b = pc0 + 8;
        const int nrows = 128 - r0b;
        if (nrows > 0) {
            const int c40 = r0b >> 2, nc4 = 32 - c40;
            for (int idx = tid; idx < nrows * nc4; idx += ETH) {
                const int rr = idx / nc4, cc = idx - rr * nc4;
                const int r = r0b + rr, c4 = c40 + cc;
                float4 e = ((float4*)&E[r][0])[c4];
                #pragma unroll
                for (int j = 0; j < 8; ++j) {
                    const float lv = LpT[j][r];
                    const float4 pv = ((const float4*)&E[pc0 + j][0])[c4];
                    e.x = fmaf(-lv, pv.x, e.x);
                    e.y = fmaf(-lv, pv.y, e.y);
                    e.z = fmaf(-lv, pv.z, e.z);
                    e.w = fmaf(-lv, pv.w, e.w);
                }
                ((float4*)&E[r][0])[c4] = e;
            }
        }
        __syncthreads();
    }

    // scale E -> C (strictly upper); init Tm = I
    for (int idx = tid; idx < 16384; idx += ETH) {
        const int r = idx >> 7, c = idx & 127;
        if (c > r) E[r][c] *= (1.f / del[r]);
        Tm[r][c] = (r == c) ? 1.f : 0.f;
    }
    __syncthreads();
    // phase A: 16 diagonal 8x8 unit-upper inverses over 8 waves
    #pragma unroll
    for (int k = 0; k < 2; ++k) {
        const int d = wave + 8 * k;
        if (lane < 8) {
            const int c = lane;
            for (int r2 = c - 1; r2 >= 0; --r2) {
                float s = 0.f;
                for (int kk = r2 + 1; kk <= c; ++kk)
                    s = fmaf(E[8 * d + r2][8 * d + kk], Tm[8 * d + kk][8 * d + c], s);
                Tm[8 * d + r2][8 * d + c] = -s;
            }
        }
    }
    __syncthreads();
    // phase B: snake-balanced column-block descents (wave w -> cols {w, 15-w})
    const int rr8 = lane >> 3, cc8 = lane & 7;
    #pragma unroll
    for (int which = 0; which < 2; ++which) {
        const int j = which ? (15 - wave) : wave;
        for (int i = j - 1; i >= 0; --i) {
            float m = 0.f;
            for (int l = i + 1; l <= j; ++l) {
                #pragma unroll
                for (int kk = 0; kk < 8; ++kk)
                    m = fmaf(E[8 * i + rr8][8 * l + kk], Tm[8 * l + kk][8 * j + cc8], m);
            }
            Msc[wave][rr8][cc8] = m;
            float s = 0.f;
            #pragma unroll
            for (int kk = 0; kk < 8; ++kk)
                s = fmaf(Tm[8 * i + rr8][8 * i + kk], Msc[wave][kk][cc8], s);
            Tm[8 * i + rr8][8 * j + cc8] = -s;
        }
    }
    __syncthreads();
    float* Tgb = Tg + (size_t)b * 16384;
    for (int idx = tid; idx < 16384; idx += ETH)
        Tgb[idx] = Tm[idx >> 7][idx & 127];
    if (tid < 128) {
        const float d = del[tid];
        const float s = sseq[(size_t)b * TT + t0 + tid];
        invd[b * 128 + tid] = 1.f / d;
        ca[b * 128 + tid] = s / d;
        cb[b * 128 + tid] = (tid == 127) ? s * 1e-6f : 0.f;
    }
}

// ---------------- guard ----------------
__global__ __launch_bounds__(256)
void guard_kernel(const float* __restrict__ dsum_g, const float* __restrict__ Ga,
                  const float* __restrict__ Gv, float* __restrict__ SnSq,
                  float* __restrict__ AnAcc, float* __restrict__ gdiag)
{
    const int b = blockIdx.x, tid = threadIdx.x;
    __shared__ float rpart[256], dsh[128], mdia[128];
    const int t = tid & 127, half = tid >> 7;
    const float* gv = Gv + (size_t)b * 16384 + t * 128;
    const float* ga = Ga + (size_t)b * 16384 + t * 128;
    float rs = 0.f;
    for (int j = half; j < t; j += 2) rs = fmaf(gv[j], ga[j], rs);
    rpart[tid] = rs;
    if (half == 0) { dsh[t] = dsum_g[b * 128 + t]; mdia[t] = gv[t] * ga[t]; }
    __syncthreads();
    if (tid == 0) {
        const float An2 = AnAcc[b];
        float Sn2 = SnSq[b], D = 0.f, T = 0.f;
        int ng = 0;
        for (int t2 = 0; t2 < 128; ++t2) {
            D += dsh[t2];
            T += mdia[t2] + 2.f * (rpart[t2] + rpart[t2 + 128]);
            const float sn2 = Sn2 + 2.f * D + T;
            if (sn2 > 1e6f || An2 > 1e6f) ++ng;
        }
        SnSq[b] = Sn2 + 2.f * D + T;
        gdiag[b] = 1e-6f + (float)ng * 1e-5f;
        AnAcc[b] = 0.f;
    }
}

extern "C" void kernel_launch(void* const* d_in, const int* in_sizes, int n_in,
                              void* d_out, int out_size, void* d_ws, size_t ws_size,
                              hipStream_t stream)
{
    const float* x  = (const float*)d_in[0];
    const float* Wq = (const float*)d_in[1];
    const float* bq = (const float*)d_in[2];
    const float* Wk = (const float*)d_in[3];
    const float* bk = (const float*)d_in[4];
    const float* Wv = (const float*)d_in[5];
    const float* bv = (const float*)d_in[6];
    const float* Wo = (const float*)d_in[7];
    const float* bo = (const float*)d_in[8];

    char* ws = (char*)d_ws;
    u16* Qb    = (u16*)(ws);
    u16* Ub    = (u16*)(ws + (16ull << 20));
    u16* Vnb   = (u16*)(ws + (32ull << 20));
    u16* Ob    = (u16*)(ws + (48ull << 20));   // also x_bf before chunk loop
    u16* x_bf  = Ob;
    float* A    = (float*)(ws + (64ull << 20));
    float* S    = (float*)(ws + (72ull << 20));
    float* Wm   = (float*)(ws + (80ull << 20));
    float* Z    = (float*)(ws + (82ull << 20));
    float* Zs   = (float*)(ws + (84ull << 20));
    float* Alpha= (float*)(ws + (86ull << 20));
    float* OBSA = (float*)(ws + (88ull << 20));
    float* G    = (float*)(ws + (92ull << 20));
    float* Tg   = (float*)(ws + (92ull << 20) + (512ull << 10));
    float* P    = (float*)(ws + (93ull << 20));
    float* Ga   = (float*)(ws + (93ull << 20) + (512ull << 10));
    float* Gv   = (float*)(ws + (94ull << 20));
    float* invd = (float*)(ws + (94ull << 20) + (512ull << 10));
    float* ca   = (float*)(ws + (94ull << 20) + (516ull << 10));
    float* cb   = (float*)(ws + (94ull << 20) + (520ull << 10));
    float* sseq = (float*)(ws + (94ull << 20) + (528ull << 10));
    float* SnSq = (float*)(ws + (94ull << 20) + (600ull << 10));
    float* AnAcc= (float*)(ws + (94ull << 20) + (600ull << 10) + 64);
    float* gdiag= (float*)(ws + (94ull << 20) + (600ull << 10) + 128);
    float* dsum = (float*)(ws + (94ull << 20) + (604ull << 10));
    u16* Wq_bf = (u16*)(ws + (95ull << 20));
    u16* Wk_bf = (u16*)(ws + (95ull << 20) + (512ull << 10));
    u16* Wv_bf = (u16*)(ws + (96ull << 20));
    u16* Wo_bf = (u16*)(ws + (96ull << 20) + (512ull << 10));

    // bf16 conversions
    f2bf_kernel<<<2048, 256, 0, stream>>>((const float4*)x, (ushort4*)x_bf, 2097152);
    wconv_kernel<<<dim3(256, 4), 256, 0, stream>>>(
        (const float4*)Wq, (const float4*)Wk, (const float4*)Wv, (const float4*)Wo,
        (ushort4*)Wq_bf, (ushort4*)Wk_bf, (ushort4*)Wv_bf, (ushort4*)Wo_bf);

    // projections via MFMA
    mfma_gemm<1><<<dim3(128, 4), 256, 0, stream>>>(x_bf, Wq_bf, bq, Qb, 1.f);
    mfma_gemm<1><<<dim3(128, 4), 256, 0, stream>>>(x_bf, Wk_bf, bk, Ub, 0.04419417382415922f);
    mfma_gemm<1><<<dim3(128, 4), 256, 0, stream>>>(x_bf, Wv_bf, bv, Vnb, 1.f);
    prep_kernel<<<4096, 256, 0, stream>>>(Qb, Ub, Vnb, sseq);
    init_kernel<<<2048, 256, 0, stream>>>((float4*)A, (float4*)S, SnSq, AnAcc);

    for (int c = 0; c < NC; ++c) {
        const int t0 = c * LL;
        const u16* Ut = Ub + (size_t)t0 * 512;
        const u16* Qt = Qb + (size_t)t0 * 512;
        const u16* Vt = Vnb + (size_t)t0 * 512;
        // K1: W = A x U_cols
        GP p1{}; p1.alay = 0; p1.Ap = A; p1.lda = 512; p1.sA = 262144;
        p1.blay = 3; p1.Bp = Ut; p1.ldb = 512; p1.sB = 1048576;
        p1.epi = 0; p1.Cp = Wm; p1.ldc = 128; p1.sC = 65536; p1.K = 512;
        gemmx<<<dim3(8, 2, 8), 256, 0, stream>>>(p1);
        // K2: G = U^T W
        GP p2{}; p2.alay = 2; p2.Ap = Ut; p2.lda = 512; p2.sA = 1048576;
        p2.blay = 0; p2.Bp = Wm; p2.ldb = 128; p2.sB = 65536;
        p2.epi = 0; p2.Cp = G; p2.ldc = 128; p2.sC = 16384; p2.K = 512;
        gemmx<<<dim3(2, 2, 8), 256, 0, stream>>>(p2);
        elim_kernel<<<8, 512, 0, stream>>>(G, Tg, sseq, invd, ca, cb, dsum, t0);
        // Z/Zs/Alpha = W x T with scale epilogue
        GP p4{}; p4.alay = 0; p4.Ap = Wm; p4.lda = 128; p4.sA = 65536;
        p4.blay = 0; p4.Bp = Tg; p4.ldb = 128; p4.sB = 16384;
        p4.epi = 4; p4.Cp = Z; p4.Zsp = Zs; p4.Alphap = Alpha;
        p4.invdp = invd; p4.cap = ca; p4.cbp = cb;
        p4.Ulastp = Ub + (size_t)(t0 + 127) * 512;
        p4.K = 128; p4.ldc = 128; p4.sC = 65536;
        gemmx<<<dim3(8, 2, 8), 256, 0, stream>>>(p4);
        lvl5_kernel<<<dim3(8, 4, 32), 256, 0, stream>>>(Alpha, Qt, Vt, S, P, Ga, Gv, OBSA, dsum);
        guard_kernel<<<8, 256, 0, stream>>>(dsum, Ga, Gv, SnSq, AnAcc, gdiag);
        lvl7_kernel<<<dim3(8, 8, 24), 256, 0, stream>>>(P, Vt, Ob + (size_t)t0 * 512, OBSA,
            Alpha, Zs, Z, S, A, gdiag, AnAcc);
    }
    // output projection via MFMA (f32 out)
    mfma_gemm<0><<<dim3(128, 4), 256, 0, stream>>>(Ob, Wo_bf, bo, d_out, 1.f);
}

// Round 8
// 4031.614 us; speedup vs baseline: 8.8711x; 1.1194x over previous
//
#include <hip/hip_runtime.h>
#include <hip/hip_bf16.h>

#define BB 8
#define TT 2048
#define DD 512
#define LL 128
#define NC 16
#define ETH 512

typedef unsigned short u16;
typedef unsigned int u32;
typedef __attribute__((ext_vector_type(8))) short bf16x8v;
typedef __attribute__((ext_vector_type(4))) float f32x4v;

__device__ __forceinline__ float bf2f(u32 h) { return __uint_as_float(h << 16); }
__device__ __forceinline__ u16 f2bf(float f) {
    u32 u = __float_as_uint(f);
    u += 0x7fffu + ((u >> 16) & 1u);
    return (u16)(u >> 16);
}
__device__ __forceinline__ float wred64(float v) {
    #pragma unroll
    for (int off = 32; off; off >>= 1) v += __shfl_xor(v, off);
    return v;
}
__device__ __forceinline__ void unpack8(uint4 r, float* f) {
    f[0] = bf2f(r.x & 0xffff); f[1] = bf2f(r.x >> 16);
    f[2] = bf2f(r.y & 0xffff); f[3] = bf2f(r.y >> 16);
    f[4] = bf2f(r.z & 0xffff); f[5] = bf2f(r.z >> 16);
    f[6] = bf2f(r.w & 0xffff); f[7] = bf2f(r.w >> 16);
}

// ---------------- f32 -> bf16 convert ----------------
__global__ __launch_bounds__(256)
void f2bf_kernel(const float4* __restrict__ in, ushort4* __restrict__ out, const int n4)
{
    int i = blockIdx.x * 256 + threadIdx.x;
    const int stride = gridDim.x * 256;
    for (; i < n4; i += stride) {
        const float4 v = in[i];
        ushort4 o;
        o.x = f2bf(v.x); o.y = f2bf(v.y); o.z = f2bf(v.z); o.w = f2bf(v.w);
        out[i] = o;
    }
}

__global__ __launch_bounds__(256)
void wconv_kernel(const float4* __restrict__ Wq, const float4* __restrict__ Wk,
                  const float4* __restrict__ Wv, const float4* __restrict__ Wo,
                  ushort4* __restrict__ oq, ushort4* __restrict__ ok,
                  ushort4* __restrict__ ov, ushort4* __restrict__ oo)
{
    const int i = blockIdx.x * 256 + threadIdx.x;
    const int y = blockIdx.y;
    const float4* src = (y == 0) ? Wq : (y == 1) ? Wk : (y == 2) ? Wv : Wo;
    ushort4* dst = (y == 0) ? oq : (y == 1) ? ok : (y == 2) ? ov : oo;
    const float4 v = src[i];
    ushort4 o;
    o.x = f2bf(v.x); o.y = f2bf(v.y); o.z = f2bf(v.z); o.w = f2bf(v.w);
    dst[i] = o;
}

// ---------------- MFMA bf16 GEMM (round-5 proven) ----------------
template<int OUT_BF>
__global__ __launch_bounds__(256)
void mfma_gemm(const u16* __restrict__ Abf, const u16* __restrict__ Bbf,
               const float* __restrict__ bias, void* __restrict__ Cout,
               const float outscale)
{
    __shared__ u16 Asm[128 * 64];
    __shared__ u16 Bsm[128 * 64];
    const int tid = threadIdx.x;
    const int wave = tid >> 6, lane = tid & 63;
    const int wm = wave >> 1, wn = wave & 1;
    const int m0 = blockIdx.x * 128, n0 = blockIdx.y * 128;

    f32x4v acc[4][4];
    #pragma unroll
    for (int i = 0; i < 4; ++i)
        #pragma unroll
        for (int j = 0; j < 4; ++j)
            acc[i][j] = (f32x4v){0.f, 0.f, 0.f, 0.f};

    const u16* gsrcA[4];
    const u16* gsrcB[4];
    #pragma unroll
    for (int i = 0; i < 4; ++i) {
        const int idx = i * 256 + tid;
        const int row = idx >> 3, c = idx & 7;
        const int kb = c ^ (row & 7);
        gsrcA[i] = Abf + (size_t)(m0 + row) * 512 + kb * 8;
        gsrcB[i] = Bbf + (size_t)(n0 + row) * 512 + kb * 8;
    }

    for (int k0 = 0; k0 < 512; k0 += 64) {
        __syncthreads();
        #pragma unroll
        for (int i = 0; i < 4; ++i) {
            __builtin_amdgcn_global_load_lds(
                (__attribute__((address_space(1))) void*)(gsrcA[i] + k0),
                (__attribute__((address_space(3))) void*)(Asm + (size_t)(i * 256 + wave * 64) * 8),
                16, 0, 0);
            __builtin_amdgcn_global_load_lds(
                (__attribute__((address_space(1))) void*)(gsrcB[i] + k0),
                (__attribute__((address_space(3))) void*)(Bsm + (size_t)(i * 256 + wave * 64) * 8),
                16, 0, 0);
        }
        asm volatile("s_waitcnt vmcnt(0)" ::: "memory");
        __syncthreads();

        const int l15 = lane & 15, lhi = lane >> 4;
        bf16x8v af[4][2], bfr[4][2];
        #pragma unroll
        for (int mf = 0; mf < 4; ++mf) {
            const int row = wm * 64 + mf * 16 + l15;
            const int sw = (row & 7) << 4;
            #pragma unroll
            for (int ks = 0; ks < 2; ++ks) {
                const int kbyte = ks * 64 + lhi * 16;
                af[mf][ks] = *(const bf16x8v*)((const char*)Asm + row * 128 + (kbyte ^ sw));
            }
        }
        #pragma unroll
        for (int nf = 0; nf < 4; ++nf) {
            const int row = wn * 64 + nf * 16 + l15;
            const int sw = (row & 7) << 4;
            #pragma unroll
            for (int ks = 0; ks < 2; ++ks) {
                const int kbyte = ks * 64 + lhi * 16;
                bfr[nf][ks] = *(const bf16x8v*)((const char*)Bsm + row * 128 + (kbyte ^ sw));
            }
        }
        #pragma unroll
        for (int ks = 0; ks < 2; ++ks)
            #pragma unroll
            for (int mf = 0; mf < 4; ++mf)
                #pragma unroll
                for (int nf = 0; nf < 4; ++nf)
                    acc[mf][nf] = __builtin_amdgcn_mfma_f32_16x16x32_bf16(
                        af[mf][ks], bfr[nf][ks], acc[mf][nf], 0, 0, 0);
    }
    const int l15 = lane & 15, lhi = lane >> 4;
    #pragma unroll
    for (int mf = 0; mf < 4; ++mf) {
        #pragma unroll
        for (int nf = 0; nf < 4; ++nf) {
            const int n = n0 + wn * 64 + nf * 16 + l15;
            const float bsv = bias[n];
            #pragma unroll
            for (int r = 0; r < 4; ++r) {
                const int m = m0 + wm * 64 + mf * 16 + lhi * 4 + r;
                const float val = (acc[mf][nf][r] + bsv) * outscale;
                if (OUT_BF) ((u16*)Cout)[(size_t)m * 512 + n] = f2bf(val);
                else        ((float*)Cout)[(size_t)m * 512 + n] = val;
            }
        }
    }
}

// ---------------- prep: s_seq, Vn normalize ----------------
__global__ __launch_bounds__(256)
void prep_kernel(const u16* __restrict__ Qb, const u16* __restrict__ Ub,
                 u16* __restrict__ Vb, float* __restrict__ sseq)
{
    const int lane = threadIdx.x & 63, wid = threadIdx.x >> 6;
    const int row = blockIdx.x * 4 + wid;
    const size_t base = (size_t)row * DD;
    const uint4 qr = *(const uint4*)(Qb + base + lane * 8);
    const uint4 ur = *(const uint4*)(Ub + base + lane * 8);
    const uint4 vr = *(const uint4*)(Vb + base + lane * 8);
    float q[8], u[8], v[8];
    unpack8(qr, q); unpack8(ur, u); unpack8(vr, v);
    float sd = 0.f, nv = 0.f;
    #pragma unroll
    for (int e = 0; e < 8; ++e) { sd = fmaf(q[e], u[e], sd); nv = fmaf(v[e], v[e], nv); }
    #pragma unroll
    for (int off = 32; off; off >>= 1) { sd += __shfl_xor(sd, off); nv += __shfl_xor(nv, off); }
    if (lane == 0) sseq[row] = sd * 22.627416997969522f;
    const float inv = 1.f / (sqrtf(nv) + 1e-6f);
    uint4 o;
    o.x = (u32)f2bf(v[0] * inv) | ((u32)f2bf(v[1] * inv) << 16);
    o.y = (u32)f2bf(v[2] * inv) | ((u32)f2bf(v[3] * inv) << 16);
    o.z = (u32)f2bf(v[4] * inv) | ((u32)f2bf(v[5] * inv) << 16);
    o.w = (u32)f2bf(v[6] * inv) | ((u32)f2bf(v[7] * inv) << 16);
    *(uint4*)(Vb + base + lane * 8) = o;
}

__global__ __launch_bounds__(256)
void init_kernel(float4* __restrict__ A4, float4* __restrict__ S4,
                 float* __restrict__ SnSq, float* __restrict__ AnAcc)
{
    const int gtid = blockIdx.x * 256 + threadIdx.x;
    const int N4 = BB * DD * DD / 4;
    for (int idx = gtid; idx < N4; idx += gridDim.x * 256) {
        const int e0 = idx << 2;
        const int r = (e0 >> 9) & 511;
        const int c = e0 & 511;
        float4 v;
        v.x = (c + 0 == r) ? 1.f : 0.f;
        v.y = (c + 1 == r) ? 1.f : 0.f;
        v.z = (c + 2 == r) ? 1.f : 0.f;
        v.w = (c + 3 == r) ? 1.f : 0.f;
        A4[idx] = v;
        S4[idx] = make_float4(0.f, 0.f, 0.f, 0.f);
    }
    if (gtid < BB) { SnSq[gtid] = 0.f; AnAcc[gtid] = 512.f; }
}

// ---------------- generic chunk GEMM ----------------
struct GP {
    int alay, blay, epi;
    const void* Ap; const void* Bp; const void* Baux;
    void* Cp; float* Cio;
    const float* gdiag; float* anacc;
    const float* invdp; const float* cap; const float* cbp;
    const u16* Ulastp; float* Zsp; float* Alphap;
    const u16* Vnp; float* dsump;
    int lda, ldb, ldc, K;
    long sA, sB, sBaux, sC, sCio;
};

__device__ __forceinline__ void gemm_body(const GP& p, const int bz) {
    __shared__ __align__(16) float As[32][68];
    __shared__ __align__(16) float Bs[32][68];
    const int m0 = blockIdx.x * 64, n0 = blockIdx.y * 64;
    const int tid = threadIdx.x, tx = tid & 15, ty = tid >> 4;
    float acc[4][4] = {};
    for (int k0 = 0; k0 < p.K; k0 += 32) {
        if (p.alay == 0) {
            const float* A = (const float*)p.Ap + (size_t)bz * p.sA;
            #pragma unroll
            for (int h = 0; h < 2; ++h) {
                const int g = tid + h * 256, m = g >> 3, k4 = (g & 7) * 4;
                const float4 r = *(const float4*)(A + (size_t)(m0 + m) * p.lda + k0 + k4);
                As[k4][m] = r.x; As[k4+1][m] = r.y; As[k4+2][m] = r.z; As[k4+3][m] = r.w;
            }
        } else if (p.alay == 2) {
            const u16* A = (const u16*)p.Ap + (size_t)bz * p.sA;
            #pragma unroll
            for (int h = 0; h < 2; ++h) {
                const int g = tid + h * 256, m = g >> 3, k4 = (g & 7) * 4;
                const ushort4 r = *(const ushort4*)(A + (size_t)(m0 + m) * p.lda + k0 + k4);
                As[k4][m]=bf2f(r.x); As[k4+1][m]=bf2f(r.y); As[k4+2][m]=bf2f(r.z); As[k4+3][m]=bf2f(r.w);
            }
        } else if (p.alay == 1 || p.alay == 4) {
            const float* A = (const float*)p.Ap + (size_t)bz * p.sA;
            #pragma unroll
            for (int h = 0; h < 2; ++h) {
                const int g = tid + h * 256, k = g >> 4, m4 = (g & 15) * 4;
                float4 r = *(const float4*)(A + (size_t)(k0 + k) * p.lda + m0 + m4);
                if (p.alay == 4) {
                    const int kg = k0 + k, mg = m0 + m4;
                    if (kg > mg + 0) r.x = 0.f;
                    if (kg > mg + 1) r.y = 0.f;
                    if (kg > mg + 2) r.z = 0.f;
                    if (kg > mg + 3) r.w = 0.f;
                }
                As[k][m4] = r.x; As[k][m4+1] = r.y; As[k][m4+2] = r.z; As[k][m4+3] = r.w;
            }
        } else { // 3
            const u16* A = (const u16*)p.Ap + (size_t)bz * p.sA;
            #pragma unroll
            for (int h = 0; h < 2; ++h) {
                const int g = tid + h * 256, k = g >> 4, m4 = (g & 15) * 4;
                const ushort4 r = *(const ushort4*)(A + (size_t)(k0 + k) * p.lda + m0 + m4);
                As[k][m4]=bf2f(r.x); As[k][m4+1]=bf2f(r.y); As[k][m4+2]=bf2f(r.z); As[k][m4+3]=bf2f(r.w);
            }
        }
        if (p.blay == 0) {
            const float* B = (const float*)p.Bp + (size_t)bz * p.sB;
            #pragma unroll
            for (int h = 0; h < 2; ++h) {
                const int g = tid + h * 256, k = g >> 4, n4 = (g & 15) * 4;
                const float4 r = *(const float4*)(B + (size_t)(k0 + k) * p.ldb + n0 + n4);
                Bs[k][n4] = r.x; Bs[k][n4+1] = r.y; Bs[k][n4+2] = r.z; Bs[k][n4+3] = r.w;
            }
        } else if (p.blay == 2) {
            const u16* B = (const u16*)p.Bp + (size_t)bz * p.sB;
            #pragma unroll
            for (int h = 0; h < 2; ++h) {
                const int g = tid + h * 256, k = g >> 4, n4 = (g & 15) * 4;
                const ushort4 r = *(const ushort4*)(B + (size_t)(k0 + k) * p.ldb + n0 + n4);
                Bs[k][n4]=bf2f(r.x); Bs[k][n4+1]=bf2f(r.y); Bs[k][n4+2]=bf2f(r.z); Bs[k][n4+3]=bf2f(r.w);
            }
        } else if (p.blay == 1) {
            const float* B = (const float*)p.Bp + (size_t)bz * p.sB;
            #pragma unroll
            for (int h = 0; h < 2; ++h) {
                const int g = tid + h * 256, n = g >> 3, k4 = (g & 7) * 4;
                const float4 r = *(const float4*)(B + (size_t)(n0 + n) * p.ldb + k0 + k4);
                Bs[k4][n] = r.x; Bs[k4+1][n] = r.y; Bs[k4+2][n] = r.z; Bs[k4+3][n] = r.w;
            }
        } else if (p.blay == 3) {
            const u16* B = (const u16*)p.Bp + (size_t)bz * p.sB;
            #pragma unroll
            for (int h = 0; h < 2; ++h) {
                const int g = tid + h * 256, n = g >> 3, k4 = (g & 7) * 4;
                const ushort4 r = *(const ushort4*)(B + (size_t)(n0 + n) * p.ldb + k0 + k4);
                Bs[k4][n]=bf2f(r.x); Bs[k4+1][n]=bf2f(r.y); Bs[k4+2][n]=bf2f(r.z); Bs[k4+3][n]=bf2f(r.w);
            }
        } else { // 5: mixed [Q | Alpha]
            if (n0 < 128) {
                const u16* B = (const u16*)p.Bp + (size_t)bz * p.sB;
                #pragma unroll
                for (int h = 0; h < 2; ++h) {
                    const int g = tid + h * 256, n = g >> 3, k4 = (g & 7) * 4;
                    const ushort4 r = *(const ushort4*)(B + (size_t)(n0 + n) * p.ldb + k0 + k4);
                    Bs[k4][n]=bf2f(r.x); Bs[k4+1][n]=bf2f(r.y); Bs[k4+2][n]=bf2f(r.z); Bs[k4+3][n]=bf2f(r.w);
                }
            } else {
                const float* B = (const float*)p.Baux + (size_t)bz * p.sBaux;
                #pragma unroll
                for (int h = 0; h < 2; ++h) {
                    const int g = tid + h * 256, k = g >> 4, n4 = (g & 15) * 4;
                    const float4 r = *(const float4*)(B + (size_t)(k0 + k) * 128 + (n0 - 128) + n4);
                    Bs[k][n4] = r.x; Bs[k][n4+1] = r.y; Bs[k][n4+2] = r.z; Bs[k][n4+3] = r.w;
                }
            }
        }
        __syncthreads();
        #pragma unroll
        for (int kk = 0; kk < 32; ++kk) {
            const float4 xa = *(const float4*)&As[kk][ty * 4];
            const float4 wb = *(const float4*)&Bs[kk][tx * 4];
            const float xv[4] = {xa.x, xa.y, xa.z, xa.w};
            const float wv[4] = {wb.x, wb.y, wb.z, wb.w};
            #pragma unroll
            for (int i = 0; i < 4; ++i)
                #pragma unroll
                for (int j = 0; j < 4; ++j)
                    acc[i][j] = fmaf(xv[i], wv[j], acc[i][j]);
        }
        __syncthreads();
    }
    const int mb = m0 + ty * 4, nb = n0 + tx * 4;
    if (p.epi == 0) {
        float* C = (float*)p.Cp + (size_t)bz * p.sC;
        #pragma unroll
        for (int i = 0; i < 4; ++i)
            #pragma unroll
            for (int j = 0; j < 4; ++j)
                C[(size_t)(mb + i) * p.ldc + nb + j] = acc[i][j];
    } else if (p.epi == 1) {
        float* C = p.Cio + (size_t)bz * p.sCio;
        const float gd = p.gdiag[bz];
        float v2 = 0.f;
        #pragma unroll
        for (int i = 0; i < 4; ++i)
            #pragma unroll
            for (int j = 0; j < 4; ++j) {
                const size_t idx = (size_t)(mb + i) * p.ldc + nb + j;
                float v = C[idx] - acc[i][j] + ((mb + i) == (nb + j) ? gd : 0.f);
                C[idx] = v;
                v2 = fmaf(v, v, v2);
            }
        v2 = wred64(v2);
        if ((tid & 63) == 0) atomicAdd(p.anacc + bz, v2);
    } else if (p.epi == 2) {
        float* C = p.Cio + (size_t)bz * p.sCio;
        #pragma unroll
        for (int i = 0; i < 4; ++i)
            #pragma unroll
            for (int j = 0; j < 4; ++j)
                C[(size_t)(mb + i) * p.ldc + nb + j] += acc[i][j];
    } else if (p.epi == 3) {
        u16* O = (u16*)p.Cp + (size_t)bz * p.sC;
        const float* OB = p.Cio + (size_t)bz * p.sCio;
        #pragma unroll
        for (int i = 0; i < 4; ++i)
            #pragma unroll
            for (int j = 0; j < 4; ++j)
                O[(size_t)(mb + i) * p.ldc + nb + j] =
                    f2bf(acc[i][j] + OB[(size_t)(nb + j) * 256 + mb + i]);
    } else if (p.epi == 4) {
        float* Zb  = (float*)p.Cp + (size_t)bz * 65536;
        float* Zsb = p.Zsp + (size_t)bz * 65536;
        float* Apb = p.Alphap + (size_t)bz * 65536;
        #pragma unroll
        for (int j = 0; j < 4; ++j) {
            const int n = nb + j;
            const float iv = p.invdp[bz * 128 + n];
            const float cav = p.cap[bz * 128 + n];
            const float cbv = p.cbp[bz * 128 + n];
            #pragma unroll
            for (int i = 0; i < 4; ++i) {
                const int m = mb + i;
                const float z = acc[i][j];
                const size_t o = (size_t)m * 128 + n;
                Zb[o] = z;
                Zsb[o] = z * iv;
                float a = z * cav;
                if (cbv != 0.f) a = fmaf(cbv, bf2f(p.Ulastp[(size_t)bz * 1048576 + m]), a);
                Apb[o] = a;
            }
        }
    } else { // 5
        float* C = (float*)p.Cp + (size_t)bz * p.sC;
        #pragma unroll
        for (int i = 0; i < 4; ++i)
            #pragma unroll
            for (int j = 0; j < 4; ++j)
                C[(size_t)(mb + i) * p.ldc + nb + j] = acc[i][j];
        if (nb >= 128) {
            const u16* Vn = p.Vnp + (size_t)bz * 1048576;
            #pragma unroll
            for (int j = 0; j < 4; ++j) {
                const int iidx = nb + j - 128;
                const ushort4 vr = *(const ushort4*)(Vn + (size_t)iidx * 512 + mb);
                const float part = bf2f(vr.x) * acc[0][j] + bf2f(vr.y) * acc[1][j]
                                 + bf2f(vr.z) * acc[2][j] + bf2f(vr.w) * acc[3][j];
                atomicAdd(p.dsump + bz * 128 + iidx, part);
            }
        }
    }
}

__global__ __launch_bounds__(256) void gemmx(GP p) { gemm_body(p, blockIdx.z); }

// ---------------- merged level-5 ----------------
__global__ __launch_bounds__(256)
void lvl5_kernel(const float* Alpha, const u16* Qt, const u16* Vnt, const float* S,
                 float* P, float* Ga, float* Gv, float* OBSA, float* dsum)
{
    const int z = blockIdx.z;
    GP p{};
    if (z < 8) {
        p.alay = 0; p.Ap = S; p.lda = 512; p.sA = 262144;
        p.blay = 5; p.Bp = Qt; p.ldb = 512; p.sB = 1048576;
        p.Baux = Alpha; p.sBaux = 65536;
        p.epi = 5; p.Cp = OBSA; p.ldc = 256; p.sC = 131072; p.K = 512;
        p.Vnp = Vnt; p.dsump = dsum;
        gemm_body(p, z);
    } else {
        if (blockIdx.x >= 2 || blockIdx.y >= 2) return;
        const int zz = z - 8, b = zz / 3, j = zz - b * 3;
        p.K = 512; p.epi = 0; p.ldc = 128; p.sC = 16384;
        if (j == 0) {
            p.alay = 1; p.Ap = Alpha; p.lda = 128; p.sA = 65536;
            p.blay = 3; p.Bp = Qt; p.ldb = 512; p.sB = 1048576; p.Cp = P;
        } else if (j == 1) {
            p.alay = 1; p.Ap = Alpha; p.lda = 128; p.sA = 65536;
            p.blay = 0; p.Bp = Alpha; p.ldb = 128; p.sB = 65536; p.Cp = Ga;
        } else {
            p.alay = 2; p.Ap = Vnt; p.lda = 512; p.sA = 1048576;
            p.blay = 3; p.Bp = Vnt; p.ldb = 512; p.sB = 1048576; p.Cp = Gv;
        }
        gemm_body(p, b);
    }
}

// ---------------- merged level-7 ----------------
__global__ __launch_bounds__(256)
void lvl7_kernel(const float* P, const u16* Vnt, u16* Obt, const float* OBSA,
                 const float* Alpha, const float* Zs, const float* Z,
                 float* S, float* A, const float* gdiag, float* AnAcc)
{
    const int z = blockIdx.z;
    GP p{};
    if (z < 8) {
        p.alay = 0; p.Ap = Zs; p.lda = 128; p.sA = 65536;
        p.blay = 1; p.Bp = Z; p.ldb = 128; p.sB = 65536;
        p.epi = 1; p.Cio = A; p.sCio = 262144; p.ldc = 512;
        p.gdiag = gdiag; p.anacc = AnAcc; p.K = 128;
        gemm_body(p, z);
    } else if (z < 16) {
        p.alay = 3; p.Ap = Vnt; p.lda = 512; p.sA = 1048576;
        p.blay = 1; p.Bp = Alpha; p.ldb = 128; p.sB = 65536;
        p.epi = 2; p.Cio = S; p.sCio = 262144; p.ldc = 512; p.K = 128;
        gemm_body(p, z - 8);
    } else {
        if (blockIdx.x >= 2) return;
        p.alay = 4; p.Ap = P; p.lda = 128; p.sA = 16384;
        p.blay = 2; p.Bp = Vnt; p.ldb = 512; p.sB = 1048576;
        p.epi = 3; p.Cp = Obt; p.ldc = 512; p.sC = 1048576;
        p.Cio = (float*)OBSA; p.sCio = 131072; p.K = 128;
        gemm_body(p, z - 16);
    }
}

// ---------------- symmetric LDL^T elimination + triangular inverse ----------------
// M = I + G, G symmetric (G = U^T A U, A symmetric). Blocked right-looking LDL^T,
// 8-wide panels held entirely in wave-0 registers (static pr0/pr1 split - no dynamic
// register indexing). C = L^T assembled directly into Cs during factorization (no
// finalize pass, no writeback, no scaling pass). Trailing update: E -= L D L^T via
// LpT/SpT. T = (I+C)^-1 built in Tm (aliases E): phase A = 16 parallel 8x8 diag
// inverses; phase B = snake-balanced per-wave column-block descents.
__global__ __launch_bounds__(512)
void elim_kernel(const float* __restrict__ G, float* __restrict__ Tg,
                 const float* __restrict__ sseq, float* __restrict__ invd,
                 float* __restrict__ ca, float* __restrict__ cb,
                 float* __restrict__ dsum_g, const int t0)
{
    const int b = blockIdx.x, tid = threadIdx.x, lane = tid & 63, wave = tid >> 6;
    __shared__ __align__(16) float E[128][132];    // G/trailing; reused as Tm
    __shared__ __align__(16) float Cs[128][132];   // C = L^T (strictly-upper valid, 0 elsewhere)
    __shared__ __align__(16) float Pst[8][132];
    __shared__ __align__(16) float LpT[8][132];
    __shared__ __align__(16) float SpT[8][132];
    __shared__ float Msc[8][8][9];
    __shared__ float del[128];
    float (*Tm)[132] = E;

    {
        const float4* Gb = (const float4*)(G + (size_t)b * 16384);
        for (int idx = tid; idx < 4096; idx += ETH) {
            const int r = idx >> 5, c4 = idx & 31;
            ((float4*)&E[r][0])[c4] = Gb[idx];
        }
    }
    if (tid < 128) dsum_g[b * 128 + tid] = 0.f;
    __syncthreads();

    for (int p = 0; p < 16; ++p) {
        const int pc0 = p * 8;
        // stage panel via symmetric ROW reads (contiguous float4)
        for (int idx = tid; idx < 256; idx += ETH) {
            const int j = idx >> 5, c4 = idx & 31;
            ((float4*)&Pst[j][0])[c4] = ((const float4*)&E[pc0 + j][0])[c4];
        }
        __syncthreads();
        if (wave == 0) {
            // rows lane (pr0) and lane+64 (pr1) — static register arrays
            float pr0[8], pr1[8];
            #pragma unroll
            for (int j = 0; j < 8; ++j) { pr0[j] = Pst[j][lane]; pr1[j] = Pst[j][64 + lane]; }
            float dl[8];
            const bool hi = (pc0 >= 64);   // uniform per panel
            #pragma unroll
            for (int j = 0; j < 8; ++j) {
                const int t = pc0 + j;
                const int pl = t & 63;
                float prow[8];
                #pragma unroll
                for (int c = 0; c < 8; ++c) {
                    const float v0 = __shfl(pr0[c], pl);
                    const float v1 = __shfl(pr1[c], pl);
                    prow[c] = hi ? v1 : v0;
                }
                const float d = fmaxf(1.f + prow[j], 1e-6f);
                dl[j] = d;
                const float inv = 1.f / d;
                if (lane > t) {
                    const float coef = pr0[j] * inv;
                    #pragma unroll
                    for (int c = j + 1; c < 8; ++c) pr0[c] = fmaf(-coef, prow[c], pr0[c]);
                }
                if (lane + 64 > t) {
                    const float coef = pr1[j] * inv;
                    #pragma unroll
                    for (int c = j + 1; c < 8; ++c) pr1[c] = fmaf(-coef, prow[c], pr1[c]);
                }
            }
            #pragma unroll
            for (int j = 0; j < 8; ++j) {
                const float idj = 1.f / dl[j];
                const int t = pc0 + j;
                {
                    const bool below = (lane > t);
                    const float y = below ? pr0[j] : 0.f;
                    const float l = y * idj;
                    LpT[j][lane] = l; SpT[j][lane] = y; Cs[t][lane] = l;
                }
                {
                    const int r = lane + 64;
                    const bool below = (r > t);
                    const float y = below ? pr1[j] : 0.f;
                    const float l = y * idj;
                    LpT[j][r] = l; SpT[j][r] = y; Cs[t][r] = l;
                }
            }
            if (lane < 8) del[pc0 + lane] = dl[lane];
        }
        __syncthreads();
        // symmetric rank-8 trailing update: E -= L D L^T (full square, keeps E symmetric)
        const int r0b = pc0 + 8;
        if (r0b < 128) {
            const int nrows = 128 - r0b;
            const int c40 = r0b >> 2, nc4 = 32 - c40;
            for (int idx = tid; idx < nrows * nc4; idx += ETH) {
                const int rr = idx / nc4, cc = idx - rr * nc4;
                const int r = r0b + rr, c4 = c40 + cc;
                float4 e = ((float4*)&E[r][0])[c4];
                #pragma unroll
                for (int j = 0; j < 8; ++j) {
                    const float lv = LpT[j][r];
                    const float4 sv = ((const float4*)&SpT[j][0])[c4];
                    e.x = fmaf(-lv, sv.x, e.x);
                    e.y = fmaf(-lv, sv.y, e.y);
                    e.z = fmaf(-lv, sv.z, e.z);
                    e.w = fmaf(-lv, sv.w, e.w);
                }
                ((float4*)&E[r][0])[c4] = e;
            }
        }
        __syncthreads();
    }

    // ---- Tm = (I+C)^-1 (Tm aliases E; E no longer needed) ----
    for (int idx = tid; idx < 4224; idx += ETH)
        ((float4*)&Tm[0][0])[idx] = make_float4(0.f, 0.f, 0.f, 0.f);
    __syncthreads();
    if (tid < 128) Tm[tid][tid] = 1.f;
    __syncthreads();
    // phase A: 16 parallel 8x8 unit-upper diag inverses (group g = tid>>3)
    {
        const int g = tid >> 3, c = tid & 7;
        if (g < 16) {
            for (int r2 = c - 1; r2 >= 0; --r2) {
                float s = 0.f;
                for (int kk = r2 + 1; kk <= c; ++kk)
                    s = fmaf(Cs[8 * g + r2][8 * g + kk],
                             (kk == c) ? 1.f : Tm[8 * g + kk][8 * g + c], s);
                Tm[8 * g + r2][8 * g + c] = -s;
            }
        }
    }
    __syncthreads();
    // phase B: snake-balanced column-block descents (wave w -> cols {w, 15-w})
    const int rr8 = lane >> 3, cc8 = lane & 7;
    #pragma unroll
    for (int which = 0; which < 2; ++which) {
        const int j = which ? (15 - wave) : wave;
        for (int i = j - 1; i >= 0; --i) {
            float m = 0.f;
            for (int l = i + 1; l <= j; ++l) {
                #pragma unroll
                for (int kk = 0; kk < 8; ++kk)
                    m = fmaf(Cs[8 * i + rr8][8 * l + kk], Tm[8 * l + kk][8 * j + cc8], m);
            }
            Msc[wave][rr8][cc8] = m;
            float s = 0.f;
            #pragma unroll
            for (int kk = 0; kk < 8; ++kk)
                s = fmaf(Tm[8 * i + rr8][8 * i + kk], Msc[wave][kk][cc8], s);
            Tm[8 * i + rr8][8 * j + cc8] = -s;
        }
    }
    __syncthreads();
    {
        float4* Tgb = (float4*)(Tg + (size_t)b * 16384);
        for (int idx = tid; idx < 4096; idx += ETH) {
            const int r = idx >> 5, c4 = idx & 31;
            Tgb[idx] = ((const float4*)&Tm[r][0])[c4];
        }
    }
    if (tid < 128) {
        const float d = del[tid];
        const float s = sseq[(size_t)b * TT + t0 + tid];
        invd[b * 128 + tid] = 1.f / d;
        ca[b * 128 + tid] = s / d;
        cb[b * 128 + tid] = (tid == 127) ? s * 1e-6f : 0.f;
    }
}

// ---------------- guard ----------------
__global__ __launch_bounds__(256)
void guard_kernel(const float* __restrict__ dsum_g, const float* __restrict__ Ga,
                  const float* __restrict__ Gv, float* __restrict__ SnSq,
                  float* __restrict__ AnAcc, float* __restrict__ gdiag)
{
    const int b = blockIdx.x, tid = threadIdx.x;
    __shared__ float rpart[256], dsh[128], mdia[128];
    const int t = tid & 127, half = tid >> 7;
    const float* gv = Gv + (size_t)b * 16384 + t * 128;
    const float* ga = Ga + (size_t)b * 16384 + t * 128;
    float rs = 0.f;
    for (int j = half; j < t; j += 2) rs = fmaf(gv[j], ga[j], rs);
    rpart[tid] = rs;
    if (half == 0) { dsh[t] = dsum_g[b * 128 + t]; mdia[t] = gv[t] * ga[t]; }
    __syncthreads();
    if (tid == 0) {
        const float An2 = AnAcc[b];
        float Sn2 = SnSq[b], D = 0.f, T = 0.f;
        int ng = 0;
        for (int t2 = 0; t2 < 128; ++t2) {
            D += dsh[t2];
            T += mdia[t2] + 2.f * (rpart[t2] + rpart[t2 + 128]);
            const float sn2 = Sn2 + 2.f * D + T;
            if (sn2 > 1e6f || An2 > 1e6f) ++ng;
        }
        SnSq[b] = Sn2 + 2.f * D + T;
        gdiag[b] = 1e-6f + (float)ng * 1e-5f;
        AnAcc[b] = 0.f;
    }
}

extern "C" void kernel_launch(void* const* d_in, const int* in_sizes, int n_in,
                              void* d_out, int out_size, void* d_ws, size_t ws_size,
                              hipStream_t stream)
{
    const float* x  = (const float*)d_in[0];
    const float* Wq = (const float*)d_in[1];
    const float* bq = (const float*)d_in[2];
    const float* Wk = (const float*)d_in[3];
    const float* bk = (const float*)d_in[4];
    const float* Wv = (const float*)d_in[5];
    const float* bv = (const float*)d_in[6];
    const float* Wo = (const float*)d_in[7];
    const float* bo = (const float*)d_in[8];

    char* ws = (char*)d_ws;
    u16* Qb    = (u16*)(ws);
    u16* Ub    = (u16*)(ws + (16ull << 20));
    u16* Vnb   = (u16*)(ws + (32ull << 20));
    u16* Ob    = (u16*)(ws + (48ull << 20));   // also x_bf before chunk loop
    u16* x_bf  = Ob;
    float* A    = (float*)(ws + (64ull << 20));
    float* S    = (float*)(ws + (72ull << 20));
    float* Wm   = (float*)(ws + (80ull << 20));
    float* Z    = (float*)(ws + (82ull << 20));
    float* Zs   = (float*)(ws + (84ull << 20));
    float* Alpha= (float*)(ws + (86ull << 20));
    float* OBSA = (float*)(ws + (88ull << 20));
    float* G    = (float*)(ws + (92ull << 20));
    float* Tg   = (float*)(ws + (92ull << 20) + (512ull << 10));
    float* P    = (float*)(ws + (93ull << 20));
    float* Ga   = (float*)(ws + (93ull << 20) + (512ull << 10));
    float* Gv   = (float*)(ws + (94ull << 20));
    float* invd = (float*)(ws + (94ull << 20) + (512ull << 10));
    float* ca   = (float*)(ws + (94ull << 20) + (516ull << 10));
    float* cb   = (float*)(ws + (94ull << 20) + (520ull << 10));
    float* sseq = (float*)(ws + (94ull << 20) + (528ull << 10));
    float* SnSq = (float*)(ws + (94ull << 20) + (600ull << 10));
    float* AnAcc= (float*)(ws + (94ull << 20) + (600ull << 10) + 64);
    float* gdiag= (float*)(ws + (94ull << 20) + (600ull << 10) + 128);
    float* dsum = (float*)(ws + (94ull << 20) + (604ull << 10));
    u16* Wq_bf = (u16*)(ws + (95ull << 20));
    u16* Wk_bf = (u16*)(ws + (95ull << 20) + (512ull << 10));
    u16* Wv_bf = (u16*)(ws + (96ull << 20));
    u16* Wo_bf = (u16*)(ws + (96ull << 20) + (512ull << 10));

    // bf16 conversions
    f2bf_kernel<<<2048, 256, 0, stream>>>((const float4*)x, (ushort4*)x_bf, 2097152);
    wconv_kernel<<<dim3(256, 4), 256, 0, stream>>>(
        (const float4*)Wq, (const float4*)Wk, (const float4*)Wv, (const float4*)Wo,
        (ushort4*)Wq_bf, (ushort4*)Wk_bf, (ushort4*)Wv_bf, (ushort4*)Wo_bf);

    // projections via MFMA
    mfma_gemm<1><<<dim3(128, 4), 256, 0, stream>>>(x_bf, Wq_bf, bq, Qb, 1.f);
    mfma_gemm<1><<<dim3(128, 4), 256, 0, stream>>>(x_bf, Wk_bf, bk, Ub, 0.04419417382415922f);
    mfma_gemm<1><<<dim3(128, 4), 256, 0, stream>>>(x_bf, Wv_bf, bv, Vnb, 1.f);
    prep_kernel<<<4096, 256, 0, stream>>>(Qb, Ub, Vnb, sseq);
    init_kernel<<<2048, 256, 0, stream>>>((float4*)A, (float4*)S, SnSq, AnAcc);

    for (int c = 0; c < NC; ++c) {
        const int t0 = c * LL;
        const u16* Ut = Ub + (size_t)t0 * 512;
        const u16* Qt = Qb + (size_t)t0 * 512;
        const u16* Vt = Vnb + (size_t)t0 * 512;
        // K1: W = A x U_cols
        GP p1{}; p1.alay = 0; p1.Ap = A; p1.lda = 512; p1.sA = 262144;
        p1.blay = 3; p1.Bp = Ut; p1.ldb = 512; p1.sB = 1048576;
        p1.epi = 0; p1.Cp = Wm; p1.ldc = 128; p1.sC = 65536; p1.K = 512;
        gemmx<<<dim3(8, 2, 8), 256, 0, stream>>>(p1);
        // K2: G = U^T W
        GP p2{}; p2.alay = 2; p2.Ap = Ut; p2.lda = 512; p2.sA = 1048576;
        p2.blay = 0; p2.Bp = Wm; p2.ldb = 128; p2.sB = 65536;
        p2.epi = 0; p2.Cp = G; p2.ldc = 128; p2.sC = 16384; p2.K = 512;
        gemmx<<<dim3(2, 2, 8), 256, 0, stream>>>(p2);
        elim_kernel<<<8, 512, 0, stream>>>(G, Tg, sseq, invd, ca, cb, dsum, t0);
        // Z/Zs/Alpha = W x T with scale epilogue
        GP p4{}; p4.alay = 0; p4.Ap = Wm; p4.lda = 128; p4.sA = 65536;
        p4.blay = 0; p4.Bp = Tg; p4.ldb = 128; p4.sB = 16384;
        p4.epi = 4; p4.Cp = Z; p4.Zsp = Zs; p4.Alphap = Alpha;
        p4.invdp = invd; p4.cap = ca; p4.cbp = cb;
        p4.Ulastp = Ub + (size_t)(t0 + 127) * 512;
        p4.K = 128; p4.ldc = 128; p4.sC = 65536;
        gemmx<<<dim3(8, 2, 8), 256, 0, stream>>>(p4);
        lvl5_kernel<<<dim3(8, 4, 32), 256, 0, stream>>>(Alpha, Qt, Vt, S, P, Ga, Gv, OBSA, dsum);
        guard_kernel<<<8, 256, 0, stream>>>(dsum, Ga, Gv, SnSq, AnAcc, gdiag);
        lvl7_kernel<<<dim3(8, 8, 24), 256, 0, stream>>>(P, Vt, Ob + (size_t)t0 * 512, OBSA,
            Alpha, Zs, Z, S, A, gdiag, AnAcc);
    }
    // output projection via MFMA (f32 out)
    mfma_gemm<0><<<dim3(128, 4), 256, 0, stream>>>(Ob, Wo_bf, bo, d_out, 1.f);
}